// Round 5
// baseline (1078.372 us; speedup 1.0000x reference)
//
#include <hip/hip_runtime.h>
#include <math.h>

#define D_MODEL 1024
#define NHEAD 16
#define HEAD_DIM 64
#define BATCH 2
#define SEQ 1024
#define ROWS (BATCH * SEQ)        // 2048
#define RD (ROWS * D_MODEL)       // 2097152
#define WSZ (D_MODEL * D_MODEL)   // 1048576
#define CHUNK 64
#define NCHUNK (SEQ / CHUNK)      // 16

typedef __attribute__((ext_vector_type(8))) short bf16x8;
typedef __attribute__((ext_vector_type(8))) unsigned short ushort8;
typedef __attribute__((ext_vector_type(4))) unsigned short us4;
typedef __attribute__((ext_vector_type(4))) float f32x4;
typedef unsigned short ushort;

// ---------------------------------------------------------------------------
// helpers
// ---------------------------------------------------------------------------
__device__ __forceinline__ void load_lds_16u(const unsigned short* g, unsigned short* l) {
    __builtin_amdgcn_global_load_lds((const __attribute__((address_space(1))) void*)g,
                                     (__attribute__((address_space(3))) void*)l, 16, 0, 0);
}
// fp32 -> bf16 RNE, and back
__device__ __forceinline__ unsigned short f2bf(float x) {
    unsigned int u = __float_as_uint(x);
    unsigned int r = (u + 0x7FFFu + ((u >> 16) & 1u)) >> 16;
    return (unsigned short)r;
}
__device__ __forceinline__ float bf2f(unsigned short h) {
    return __uint_as_float(((unsigned int)h) << 16);
}
// fragment-order index into a 64x64 bf16 operand buffer (R4-validated layout):
// element (r,k) at subtile ((r>>4)*2 + (k>>5)) * 512 + (kg*16 + (r&15))*8 + (k&7)
__device__ __forceinline__ int fidx(int r, int k) {
    return (((r >> 4) * 2 + (k >> 5)) << 9) + ((((k & 31) >> 3) << 4) + (r & 15)) * 8 + (k & 7);
}

// ---------------------------------------------------------------------------
// split: fp32 -> (hi, lo) bf16 buffers. n4 = n/4 float4 groups.
// ---------------------------------------------------------------------------
__global__ __launch_bounds__(256) void split_kernel(const float* __restrict__ X,
                                                    unsigned short* __restrict__ H,
                                                    unsigned short* __restrict__ L,
                                                    int n4) {
    int i = blockIdx.x * 256 + threadIdx.x;
    if (i >= n4) return;
    float4 v = ((const float4*)X)[i];
    us4 h, l;
    h.x = f2bf(v.x); l.x = f2bf(v.x - bf2f(h.x));
    h.y = f2bf(v.y); l.y = f2bf(v.y - bf2f(h.y));
    h.z = f2bf(v.z); l.z = f2bf(v.z - bf2f(h.z));
    h.w = f2bf(v.w); l.w = f2bf(v.w - bf2f(h.w));
    ((us4*)H)[i] = h;
    ((us4*)L)[i] = l;
}

// ---------------------------------------------------------------------------
// Fast GEMM on pre-split inputs (unchanged from R4).
// ---------------------------------------------------------------------------
template <int ACT>
__global__ __launch_bounds__(256) void gemm_bf16s(const unsigned short* __restrict__ Ah,
                                                  const unsigned short* __restrict__ Al,
                                                  const unsigned short* __restrict__ Bh,
                                                  const unsigned short* __restrict__ Bl,
                                                  float* __restrict__ C,
                                                  int M, int N, int K) {
    __shared__ unsigned short LA[2][8 * 512];
    __shared__ unsigned short LB[2][4 * 512];

    const int t = threadIdx.x;
    const int wave = t >> 6, lane = t & 63;
    const int wm = wave >> 1, wn = wave & 1;
    const int m16 = lane & 15, kg = lane >> 4;
    const int row0 = blockIdx.y * 128, col0 = blockIdx.x * 64;

    f32x4 acc[4][2];
#pragma unroll
    for (int i = 0; i < 4; ++i)
#pragma unroll
        for (int j = 0; j < 2; ++j) acc[i][j] = (f32x4){0.f, 0.f, 0.f, 0.f};

    for (int k0 = 0; k0 < K; k0 += 32) {
#pragma unroll
        for (int ci = 0; ci < 6; ++ci) {
            const int c = wave * 6 + ci;
            const unsigned short* src;
            unsigned short* dst;
            int g16, rbase;
            if (c < 8)       { src = Ah; dst = &LA[0][c * 512];        g16 = c;      rbase = row0; }
            else if (c < 16) { src = Al; dst = &LA[1][(c - 8) * 512];  g16 = c - 8;  rbase = row0; }
            else if (c < 20) { src = Bh; dst = &LB[0][(c - 16) * 512]; g16 = c - 16; rbase = col0; }
            else             { src = Bl; dst = &LB[1][(c - 20) * 512]; g16 = c - 20; rbase = col0; }
            const unsigned short* gp = src + (size_t)(rbase + g16 * 16 + m16) * K + k0 + kg * 8;
            load_lds_16u(gp, dst);
        }
        __syncthreads();

        bf16x8 fah[4], fal[4], fbh[2], fbl[2];
#pragma unroll
        for (int mt = 0; mt < 4; ++mt) {
            const int off = (wm * 4 + mt) * 512 + lane * 8;
            fah[mt] = *(const bf16x8*)&LA[0][off];
            fal[mt] = *(const bf16x8*)&LA[1][off];
        }
#pragma unroll
        for (int nt = 0; nt < 2; ++nt) {
            const int off = (wn * 2 + nt) * 512 + lane * 8;
            fbh[nt] = *(const bf16x8*)&LB[0][off];
            fbl[nt] = *(const bf16x8*)&LB[1][off];
        }
#pragma unroll
        for (int mt = 0; mt < 4; ++mt)
#pragma unroll
            for (int nt = 0; nt < 2; ++nt) {
                acc[mt][nt] = __builtin_amdgcn_mfma_f32_16x16x32_bf16(fal[mt], fbh[nt], acc[mt][nt], 0, 0, 0);
                acc[mt][nt] = __builtin_amdgcn_mfma_f32_16x16x32_bf16(fah[mt], fbl[nt], acc[mt][nt], 0, 0, 0);
                acc[mt][nt] = __builtin_amdgcn_mfma_f32_16x16x32_bf16(fah[mt], fbh[nt], acc[mt][nt], 0, 0, 0);
            }
        __syncthreads();
    }

#pragma unroll
    for (int mt = 0; mt < 4; ++mt)
#pragma unroll
        for (int nt = 0; nt < 2; ++nt) {
            const int rowb = row0 + wm * 64 + mt * 16 + kg * 4;
            const int col  = col0 + wn * 32 + nt * 16 + m16;
#pragma unroll
            for (int rg = 0; rg < 4; ++rg) {
                float v = acc[mt][nt][rg];
                if (ACT == 1) v = v / (1.f + expf(-v));
                C[(size_t)(rowb + rg) * N + col] = v;
            }
        }
}

// ---------------------------------------------------------------------------
// Fallback GEMM (inline split) — only if ws_size too small (unchanged from R4).
// ---------------------------------------------------------------------------
#define LDST 40
template <int ACT>
__global__ __launch_bounds__(256) void gemm_mfma(const float* __restrict__ A,
                                                 const float* __restrict__ B,
                                                 float* __restrict__ C,
                                                 int M, int N, int K) {
    __shared__ unsigned short Ahi[128 * LDST], Alo[128 * LDST];
    __shared__ unsigned short Bhi[128 * LDST], Blo[128 * LDST];

    const int t = threadIdx.x;
    const int wave = t >> 6, lane = t & 63;
    const int wm = wave >> 1, wn = wave & 1;
    const int row0 = blockIdx.y * 128, col0 = blockIdx.x * 128;
    const int sr = t >> 1;
    const int sh = t & 1;
    const int m16 = lane & 15, kg = lane >> 4;

    f32x4 acc[4][4];
#pragma unroll
    for (int i = 0; i < 4; ++i)
#pragma unroll
        for (int j = 0; j < 4; ++j) acc[i][j] = (f32x4){0.f, 0.f, 0.f, 0.f};

    const float* ga = A + (size_t)(row0 + sr) * K + sh * 16;
    const float* gb = B + (size_t)(col0 + sr) * K + sh * 16;
    const int sbase = sr * LDST + sh * 16;

    for (int k0 = 0; k0 < K; k0 += 32) {
        float af[16], bf[16];
#pragma unroll
        for (int i = 0; i < 4; ++i) {
            float4 a4 = *(const float4*)(ga + k0 + i * 4);
            float4 b4 = *(const float4*)(gb + k0 + i * 4);
            af[i * 4 + 0] = a4.x; af[i * 4 + 1] = a4.y; af[i * 4 + 2] = a4.z; af[i * 4 + 3] = a4.w;
            bf[i * 4 + 0] = b4.x; bf[i * 4 + 1] = b4.y; bf[i * 4 + 2] = b4.z; bf[i * 4 + 3] = b4.w;
        }
        ushort8 ah0, ah1, al0, al1, bh0, bh1, bl0, bl1;
#pragma unroll
        for (int j = 0; j < 8; ++j) {
            unsigned short h = f2bf(af[j]);       ah0[j] = h; al0[j] = f2bf(af[j] - bf2f(h));
            h = f2bf(af[j + 8]);                  ah1[j] = h; al1[j] = f2bf(af[j + 8] - bf2f(h));
            h = f2bf(bf[j]);                      bh0[j] = h; bl0[j] = f2bf(bf[j] - bf2f(h));
            h = f2bf(bf[j + 8]);                  bh1[j] = h; bl1[j] = f2bf(bf[j + 8] - bf2f(h));
        }
        *(ushort8*)&Ahi[sbase] = ah0;  *(ushort8*)&Ahi[sbase + 8] = ah1;
        *(ushort8*)&Alo[sbase] = al0;  *(ushort8*)&Alo[sbase + 8] = al1;
        *(ushort8*)&Bhi[sbase] = bh0;  *(ushort8*)&Bhi[sbase + 8] = bh1;
        *(ushort8*)&Blo[sbase] = bl0;  *(ushort8*)&Blo[sbase + 8] = bl1;
        __syncthreads();

        bf16x8 fah[4], fal[4], fbh[4], fbl[4];
#pragma unroll
        for (int i = 0; i < 4; ++i) {
            const int ar = (wm * 64 + i * 16 + m16) * LDST + kg * 8;
            const int br = (wn * 64 + i * 16 + m16) * LDST + kg * 8;
            fah[i] = *(const bf16x8*)&Ahi[ar];
            fal[i] = *(const bf16x8*)&Alo[ar];
            fbh[i] = *(const bf16x8*)&Bhi[br];
            fbl[i] = *(const bf16x8*)&Blo[br];
        }
#pragma unroll
        for (int i = 0; i < 4; ++i)
#pragma unroll
            for (int j = 0; j < 4; ++j) {
                acc[i][j] = __builtin_amdgcn_mfma_f32_16x16x32_bf16(fal[i], fbh[j], acc[i][j], 0, 0, 0);
                acc[i][j] = __builtin_amdgcn_mfma_f32_16x16x32_bf16(fah[i], fbl[j], acc[i][j], 0, 0, 0);
                acc[i][j] = __builtin_amdgcn_mfma_f32_16x16x32_bf16(fah[i], fbh[j], acc[i][j], 0, 0, 0);
            }
        __syncthreads();
    }

#pragma unroll
    for (int i = 0; i < 4; ++i)
#pragma unroll
        for (int j = 0; j < 4; ++j) {
            const int col = col0 + wn * 64 + j * 16 + m16;
            const int rowb = row0 + wm * 64 + i * 16 + kg * 4;
#pragma unroll
            for (int rg = 0; rg < 4; ++rg) {
                float v = acc[i][j][rg];
                if (ACT == 1) v = v / (1.f + expf(-v));
                C[(size_t)(rowb + rg) * N + col] = v;
            }
        }
}

// ---------------------------------------------------------------------------
// beta = 2*sigmoid(x @ Wb^T)  : (ROWS, NHEAD). One wave per row.
// ---------------------------------------------------------------------------
__global__ __launch_bounds__(256) void beta_kernel(const float* __restrict__ x,
                                                   const float* __restrict__ Wb,
                                                   float* __restrict__ beta) {
    const int wave = blockIdx.x * 4 + (threadIdx.x >> 6);
    const int lane = threadIdx.x & 63;
    const float* xr = x + (size_t)wave * D_MODEL;
    float xv[16];
#pragma unroll
    for (int j = 0; j < 16; ++j) xv[j] = xr[lane + 64 * j];
    for (int n = 0; n < NHEAD; ++n) {
        const float* wr = Wb + (size_t)n * D_MODEL;
        float s = 0.f;
#pragma unroll
        for (int j = 0; j < 16; ++j) s += xv[j] * wr[lane + 64 * j];
#pragma unroll
        for (int off = 32; off; off >>= 1) s += __shfl_xor(s, off);
        if (lane == 0) beta[(size_t)wave * NHEAD + n] = 2.f / (1.f + expf(-s));
    }
}

// ---------------------------------------------------------------------------
// L2-normalize q and k per (row, head) over HEAD_DIM=64.
// ---------------------------------------------------------------------------
__global__ __launch_bounds__(256) void norm_qk(float* __restrict__ Q,
                                               float* __restrict__ Kp) {
    const int TOT = ROWS * NHEAD;
    int wave = blockIdx.x * 4 + (threadIdx.x >> 6);
    const int lane = threadIdx.x & 63;
    float* T = (wave < TOT) ? Q : Kp;
    int w = (wave < TOT) ? wave : wave - TOT;
    float* p = T + (size_t)(w >> 4) * D_MODEL + (size_t)(w & 15) * HEAD_DIM;
    float v = p[lane];
    float ss = v * v;
#pragma unroll
    for (int off = 32; off; off >>= 1) ss += __shfl_xor(ss, off);
    p[lane] = v / (sqrtf(ss) + 1e-6f);
}

// ---------------------------------------------------------------------------
// Chunked delta-rule scan. One block per (b,head); 4 waves; C = 64.
// Per chunk: split-bf16 MFMA products + one in-LDS fp32 triangular solve.
// Recurrence (verified vs reference in R1's sequential form):
//   r_t = M k_t ; delta_t = v_t - r_t ; M += beta_t * outer(k_t, delta_t)
//   y_t = M^T q_t (pre-update)
// Chunk math: V0 = V - K M0^T ; A = KK^T ; C0 = K V0^T
//   X[t,s] = C0[t,s] - sum_{u<s} A[t,u] beta_u X[s,u]   (strictly lower)
//   Delta  = V0 - (X beta) K
//   Y      = Q M0 + tril_(QK^T) (beta Delta)
//   M     += K^T (beta Delta)   (and transpose for MT)
// ---------------------------------------------------------------------------
#define SMEM_SCAN 149760

__global__ __launch_bounds__(256, 1) void scan_chunked(const float* __restrict__ Qg,
                                                       const float* __restrict__ Kg,
                                                       const float* __restrict__ Vg,
                                                       const float* __restrict__ Btg,
                                                       float* __restrict__ Yg) {
    extern __shared__ char smem[];
    // bf16 fragment-order buffers, 8192 B each
    ushort* Mh_  = (ushort*)(smem + 0);
    ushort* Ml_  = (ushort*)(smem + 8192);
    ushort* MTh_ = (ushort*)(smem + 16384);
    ushort* MTl_ = (ushort*)(smem + 24576);
    ushort* KTh_ = (ushort*)(smem + 32768);
    ushort* KTl_ = (ushort*)(smem + 40960);
    ushort* V0h_ = (ushort*)(smem + 49152);
    ushort* V0l_ = (ushort*)(smem + 57344);
    ushort* Gh_  = (ushort*)(smem + 65536);
    ushort* Gl_  = (ushort*)(smem + 73728);
    ushort* Kh_  = (ushort*)(smem + 81920);   // union1: K (stage..C0) / DT (Delta..end)
    ushort* Kl_  = (ushort*)(smem + 90112);
    ushort* DTh_ = Kh_;
    ushort* DTl_ = Kl_;
    ushort* Qh_  = (ushort*)(smem + 98304);   // union2: Q (stage..QK) / Xb (solve..Delta)
    ushort* Ql_  = (ushort*)(smem + 106496);
    ushort* Xbh_ = Qh_;
    ushort* Xbl_ = Ql_;
    float*  Vf32 = (float*)(smem + 114688);   // 64x68 fp32; reused as nothing else
    float*  C032 = Vf32;                      // NOTE: C0 written AFTER V consumed (P_R)
    float*  A32  = (float*)(smem + 132096);   // 64x68 fp32
    float*  bv   = (float*)(smem + 149504);   // 64 fp32

    const int b = blockIdx.x >> 4;
    const int n = blockIdx.x & 15;
    const int t = threadIdx.x;
    const int wave = t >> 6, lane = t & 63;
    const int m16 = lane & 15, kg = lane >> 4;
    const int bS = b * SEQ;
    const int nOff = n * HEAD_DIM;
    const int r = t >> 2, g = t & 3;   // staging: row r, col-quarter g

    // zero state M, MT (hi+lo): 4 arrays x 2048 uints
    for (int i = t; i < 2048; i += 256) {
        ((unsigned int*)Mh_)[i] = 0; ((unsigned int*)Ml_)[i] = 0;
        ((unsigned int*)MTh_)[i] = 0; ((unsigned int*)MTl_)[i] = 0;
    }
    __syncthreads();

    // product helper: 16-row band (= wave) x 64 cols, K=64, split operands
    auto prod_band = [&](const ushort* Ah, const ushort* Al,
                         const ushort* Bh, const ushort* Bl, f32x4 acc[4]) {
        const int lo8 = lane * 8;
#pragma unroll
        for (int half = 0; half < 2; ++half) {
            bf16x8 ah = *(const bf16x8*)&Ah[((wave * 2 + half) << 9) + lo8];
            bf16x8 al = *(const bf16x8*)&Al[((wave * 2 + half) << 9) + lo8];
#pragma unroll
            for (int j = 0; j < 4; ++j) {
                bf16x8 bh = *(const bf16x8*)&Bh[((j * 2 + half) << 9) + lo8];
                bf16x8 bl = *(const bf16x8*)&Bl[((j * 2 + half) << 9) + lo8];
                acc[j] = __builtin_amdgcn_mfma_f32_16x16x32_bf16(al, bh, acc[j], 0, 0, 0);
                acc[j] = __builtin_amdgcn_mfma_f32_16x16x32_bf16(ah, bl, acc[j], 0, 0, 0);
                acc[j] = __builtin_amdgcn_mfma_f32_16x16x32_bf16(ah, bh, acc[j], 0, 0, 0);
            }
        }
    };

    for (int c = 0; c < NCHUNK; ++c) {
        const int s0 = c * CHUNK;

        // ---- stage K (+transpose), Q, V, beta ----
        {
            const float* gK = Kg + (size_t)(bS + s0 + r) * D_MODEL + nOff + g * 16;
            const float* gQ = Qg + (size_t)(bS + s0 + r) * D_MODEL + nOff + g * 16;
            const float* gV = Vg + (size_t)(bS + s0 + r) * D_MODEL + nOff + g * 16;
#pragma unroll
            for (int j4 = 0; j4 < 4; ++j4) {
                float4 kv = ((const float4*)gK)[j4];
                float4 qv = ((const float4*)gQ)[j4];
                float4 vv = ((const float4*)gV)[j4];
                float kf[4] = {kv.x, kv.y, kv.z, kv.w};
                float qf[4] = {qv.x, qv.y, qv.z, qv.w};
#pragma unroll
                for (int e = 0; e < 4; ++e) {
                    const int cc = g * 16 + j4 * 4 + e;
                    ushort h = f2bf(kf[e]);
                    ushort l = f2bf(kf[e] - bf2f(h));
                    const int ia = fidx(r, cc), ib = fidx(cc, r);
                    Kh_[ia] = h; Kl_[ia] = l;
                    KTh_[ib] = h; KTl_[ib] = l;
                    h = f2bf(qf[e]); l = f2bf(qf[e] - bf2f(h));
                    Qh_[ia] = h; Ql_[ia] = l;
                }
                *(float4*)&Vf32[r * 68 + g * 16 + j4 * 4] = vv;
            }
            if (t < 64) bv[t] = Btg[(size_t)(bS + s0 + t) * NHEAD + n];
        }
        __syncthreads();   // B1

        f32x4 yacc[4];
        {
            // ---- P_R: R = K * M0^T ; V0 = V - R -> V0sp ----
            f32x4 acc[4];
#pragma unroll
            for (int j = 0; j < 4; ++j) acc[j] = (f32x4){0.f, 0.f, 0.f, 0.f};
            prod_band(Kh_, Kl_, Mh_, Ml_, acc);
#pragma unroll
            for (int j = 0; j < 4; ++j)
#pragma unroll
                for (int rg = 0; rg < 4; ++rg) {
                    const int row = wave * 16 + kg * 4 + rg, col = j * 16 + m16;
                    float v0 = Vf32[row * 68 + col] - acc[j][rg];
                    ushort h = f2bf(v0);
                    const int ii = fidx(row, col);
                    V0h_[ii] = h; V0l_[ii] = f2bf(v0 - bf2f(h));
                }
            // ---- P_YM: yacc = Q * M0 (via MT) ----
#pragma unroll
            for (int j = 0; j < 4; ++j) yacc[j] = (f32x4){0.f, 0.f, 0.f, 0.f};
            prod_band(Qh_, Ql_, MTh_, MTl_, yacc);
            // ---- P_A: A = K K^T -> fp32 ----
#pragma unroll
            for (int j = 0; j < 4; ++j) acc[j] = (f32x4){0.f, 0.f, 0.f, 0.f};
            prod_band(Kh_, Kl_, Kh_, Kl_, acc);
#pragma unroll
            for (int j = 0; j < 4; ++j)
#pragma unroll
                for (int rg = 0; rg < 4; ++rg) {
                    const int row = wave * 16 + kg * 4 + rg, col = j * 16 + m16;
                    A32[row * 68 + col] = acc[j][rg];
                }
            // ---- P_QK: G = tril_(Q K^T) -> split ----
#pragma unroll
            for (int j = 0; j < 4; ++j) acc[j] = (f32x4){0.f, 0.f, 0.f, 0.f};
            prod_band(Qh_, Ql_, Kh_, Kl_, acc);
#pragma unroll
            for (int j = 0; j < 4; ++j)
#pragma unroll
                for (int rg = 0; rg < 4; ++rg) {
                    const int row = wave * 16 + kg * 4 + rg, col = j * 16 + m16;
                    float gv = (row > col) ? acc[j][rg] : 0.f;
                    ushort h = f2bf(gv);
                    const int ii = fidx(row, col);
                    Gh_[ii] = h; Gl_[ii] = f2bf(gv - bf2f(h));
                }
        }
        __syncthreads();   // B2 (V0sp complete; Vf32 dead -> C032 may be written)

        {
            // ---- P_C0: C0 = K * V0^T -> fp32 (into Vf32 region) ----
            f32x4 acc[4];
#pragma unroll
            for (int j = 0; j < 4; ++j) acc[j] = (f32x4){0.f, 0.f, 0.f, 0.f};
            prod_band(Kh_, Kl_, V0h_, V0l_, acc);
#pragma unroll
            for (int j = 0; j < 4; ++j)
#pragma unroll
                for (int rg = 0; rg < 4; ++rg) {
                    const int row = wave * 16 + kg * 4 + rg, col = j * 16 + m16;
                    C032[row * 68 + col] = acc[j][rg];
                }
        }
        __syncthreads();   // B3

        // ---- solve (wave 0 only): forward substitution, columns s=0..63 ----
        // stores xn[t][s] = -beta_s * X[t,s] in C032 (in place over C0) and
        // split-bf16 into Xbsp. A is symmetric (used for the scalar tail).
        if (wave == 0) {
            float4 af[16];
#pragma unroll
            for (int u4 = 0; u4 < 16; ++u4)
                af[u4] = *(const float4*)&A32[lane * 68 + u4 * 4];
            for (int s = 0; s < 64; ++s) {
                float sum = 0.f;
                const float* rowp = &C032[s * 68];
                const int nf = s >> 2;
#pragma unroll
                for (int u4 = 0; u4 < 16; ++u4) {
                    if (u4 < nf) {
                        float4 c4 = *(const float4*)&rowp[u4 * 4];
                        sum += af[u4].x * c4.x + af[u4].y * c4.y +
                               af[u4].z * c4.z + af[u4].w * c4.w;
                    }
                }
                for (int u = nf * 4; u < s; ++u)
                    sum += A32[u * 68 + lane] * rowp[u];
                float val = C032[lane * 68 + s] + sum;  // = X[t,s]
                float xn = (lane > s) ? (-bv[s] * val) : 0.f;
                C032[lane * 68 + s] = xn;
                ushort hh = f2bf(xn);
                const int ii = fidx(lane, s);
                Xbh_[ii] = hh;
                Xbl_[ii] = f2bf(xn - bf2f(hh));
            }
        }
        __syncthreads();   // B4

        {
            // ---- P_Delta: Delta = V0 + Xn * K^T ; write DT = (beta Delta)^T ----
            f32x4 acc[4];
#pragma unroll
            for (int j = 0; j < 4; ++j)
#pragma unroll
                for (int rg = 0; rg < 4; ++rg) {
                    const int row = wave * 16 + kg * 4 + rg, col = j * 16 + m16;
                    const int ii = fidx(row, col);
                    acc[j][rg] = bf2f(V0h_[ii]) + bf2f(V0l_[ii]);
                }
            prod_band(Xbh_, Xbl_, KTh_, KTl_, acc);
            __syncthreads();  // B4.5: Xbsp (union2) fully consumed before... (kept for safety vs DT aliasing timing)
#pragma unroll
            for (int j = 0; j < 4; ++j)
#pragma unroll
                for (int rg = 0; rg < 4; ++rg) {
                    const int row = wave * 16 + kg * 4 + rg, col = j * 16 + m16;
                    float dv = acc[j][rg] * bv[row];     // beta_s * delta_s[d]
                    ushort h = f2bf(dv);
                    const int ii = fidx(col, row);       // DT[d][s]
                    DTh_[ii] = h; DTl_[ii] = f2bf(dv - bf2f(h));
                }
        }
        __syncthreads();   // B5 (DT ready)

        {
            // ---- P_Y2: Y = yacc + G * DT^T -> global ----
            prod_band(Gh_, Gl_, DTh_, DTl_, yacc);
#pragma unroll
            for (int j = 0; j < 4; ++j)
#pragma unroll
                for (int rg = 0; rg < 4; ++rg) {
                    const int row = wave * 16 + kg * 4 + rg, col = j * 16 + m16;
                    Yg[(size_t)(bS + s0 + row) * D_MODEL + nOff + col] = yacc[j][rg];
                }
            // ---- P_M: M += K^T * DT^T ----
            f32x4 acc[4];
#pragma unroll
            for (int j = 0; j < 4; ++j)
#pragma unroll
                for (int rg = 0; rg < 4; ++rg) {
                    const int row = wave * 16 + kg * 4 + rg, col = j * 16 + m16;
                    const int ii = fidx(row, col);
                    acc[j][rg] = bf2f(Mh_[ii]) + bf2f(Ml_[ii]);
                }
            prod_band(KTh_, KTl_, DTh_, DTl_, acc);
#pragma unroll
            for (int j = 0; j < 4; ++j)
#pragma unroll
                for (int rg = 0; rg < 4; ++rg) {
                    const int row = wave * 16 + kg * 4 + rg, col = j * 16 + m16;
                    float mv = acc[j][rg];
                    ushort h = f2bf(mv);
                    const int ii = fidx(row, col);
                    Mh_[ii] = h; Ml_[ii] = f2bf(mv - bf2f(h));
                }
            // ---- P_MT: MT += DT * K ----
#pragma unroll
            for (int j = 0; j < 4; ++j)
#pragma unroll
                for (int rg = 0; rg < 4; ++rg) {
                    const int row = wave * 16 + kg * 4 + rg, col = j * 16 + m16;
                    const int ii = fidx(row, col);
                    acc[j][rg] = bf2f(MTh_[ii]) + bf2f(MTl_[ii]);
                }
            prod_band(DTh_, DTl_, KTh_, KTl_, acc);
#pragma unroll
            for (int j = 0; j < 4; ++j)
#pragma unroll
                for (int rg = 0; rg < 4; ++rg) {
                    const int row = wave * 16 + kg * 4 + rg, col = j * 16 + m16;
                    float mv = acc[j][rg];
                    ushort h = f2bf(mv);
                    const int ii = fidx(row, col);
                    MTh_[ii] = h; MTl_[ii] = f2bf(mv - bf2f(h));
                }
        }
        __syncthreads();   // B6 (state updated; unions free for next stage)
    }
}

// ---------------------------------------------------------------------------
// RMSNorm. SPLIT=1: write (hi,lo) bf16 for final GEMM. SPLIT=0: fp32 in place.
// ---------------------------------------------------------------------------
template <int SPLIT>
__global__ __launch_bounds__(256) void rmsnorm_kernel(float* __restrict__ Y,
                                                      const float* __restrict__ w,
                                                      unsigned short* __restrict__ H,
                                                      unsigned short* __restrict__ L) {
    __shared__ float red[4];
    float* y = Y + (size_t)blockIdx.x * D_MODEL;
    const int t = threadIdx.x;
    const int wv = t >> 6, ln = t & 63;
    float4 v = ((float4*)y)[t];
    float ss = v.x * v.x + v.y * v.y + v.z * v.z + v.w * v.w;
#pragma unroll
    for (int off = 32; off; off >>= 1) ss += __shfl_xor(ss, off);
    if (ln == 0) red[wv] = ss;
    __syncthreads();
    float tot = red[0] + red[1] + red[2] + red[3];
    float inv = 1.f / sqrtf(tot * (1.f / D_MODEL) + 1e-6f);
    const float4 wv4 = ((const float4*)w)[t];
    v.x *= inv * wv4.x; v.y *= inv * wv4.y;
    v.z *= inv * wv4.z; v.w *= inv * wv4.w;
    if (SPLIT) {
        us4 h, l;
        h.x = f2bf(v.x); l.x = f2bf(v.x - bf2f(h.x));
        h.y = f2bf(v.y); l.y = f2bf(v.y - bf2f(h.y));
        h.z = f2bf(v.z); l.z = f2bf(v.z - bf2f(h.z));
        h.w = f2bf(v.w); l.w = f2bf(v.w - bf2f(h.w));
        size_t i = (size_t)blockIdx.x * 256 + t;
        ((us4*)H)[i] = h;
        ((us4*)L)[i] = l;
    } else {
        ((float4*)y)[t] = v;
    }
}

// ---------------------------------------------------------------------------
extern "C" void kernel_launch(void* const* d_in, const int* in_sizes, int n_in,
                              void* d_out, int out_size, void* d_ws, size_t ws_size,
                              hipStream_t stream) {
    const float* x     = (const float*)d_in[0];
    const float* Wq    = (const float*)d_in[1];
    const float* Wk    = (const float*)d_in[2];
    const float* Wv    = (const float*)d_in[3];
    const float* Wb    = (const float*)d_in[4];
    const float* Wo    = (const float*)d_in[5];
    const float* rms_w = (const float*)d_in[6];
    float* out = (float*)d_out;

    char* p = (char*)d_ws;
    float* Q  = (float*)p;  p += (size_t)RD * 4;
    float* Kp = (float*)p;  p += (size_t)RD * 4;
    float* Vp = (float*)p;  p += (size_t)RD * 4;
    float* Y  = (float*)p;  p += (size_t)RD * 4;
    float* Bt = (float*)p;  p += (size_t)32768 * 4;
    unsigned short* xh  = (unsigned short*)p;  p += (size_t)RD * 2;   // reused as Yh
    unsigned short* xl  = (unsigned short*)p;  p += (size_t)RD * 2;   // reused as Yl
    unsigned short* Wsh = (unsigned short*)p;  p += (size_t)WSZ * 2;
    unsigned short* Wsl = (unsigned short*)p;  p += (size_t)WSZ * 2;
    const size_t need_fast = (size_t)RD * 16 + 131072 + (size_t)RD * 4 + (size_t)WSZ * 4;
    const bool fast = ws_size >= need_fast;

    // allow 146 KB dynamic LDS for the chunked scan
    (void)hipFuncSetAttribute(reinterpret_cast<const void*>(scan_chunked),
                              hipFuncAttributeMaxDynamicSharedMemorySize, SMEM_SCAN);

    if (fast) {
        dim3 ggrid(D_MODEL / 64, ROWS / 128);   // (16,16) = 256 blocks
        split_kernel<<<RD / 4 / 256, 256, 0, stream>>>(x, xh, xl, RD / 4);
        split_kernel<<<WSZ / 4 / 256, 256, 0, stream>>>(Wq, Wsh, Wsl, WSZ / 4);
        gemm_bf16s<1><<<ggrid, 256, 0, stream>>>(xh, xl, Wsh, Wsl, Q, ROWS, D_MODEL, D_MODEL);
        split_kernel<<<WSZ / 4 / 256, 256, 0, stream>>>(Wk, Wsh, Wsl, WSZ / 4);
        gemm_bf16s<1><<<ggrid, 256, 0, stream>>>(xh, xl, Wsh, Wsl, Kp, ROWS, D_MODEL, D_MODEL);
        split_kernel<<<WSZ / 4 / 256, 256, 0, stream>>>(Wv, Wsh, Wsl, WSZ / 4);
        gemm_bf16s<1><<<ggrid, 256, 0, stream>>>(xh, xl, Wsh, Wsl, Vp, ROWS, D_MODEL, D_MODEL);
        beta_kernel<<<ROWS / 4, 256, 0, stream>>>(x, Wb, Bt);
        norm_qk<<<2 * ROWS * NHEAD / 4, 256, 0, stream>>>(Q, Kp);
        scan_chunked<<<BATCH * NHEAD, 256, SMEM_SCAN, stream>>>(Q, Kp, Vp, Bt, Y);
        rmsnorm_kernel<1><<<ROWS, 256, 0, stream>>>(Y, rms_w, xh, xl);
        split_kernel<<<WSZ / 4 / 256, 256, 0, stream>>>(Wo, Wsh, Wsl, WSZ / 4);
        gemm_bf16s<0><<<ggrid, 256, 0, stream>>>(xh, xl, Wsh, Wsl, out, ROWS, D_MODEL, D_MODEL);
    } else {
        dim3 ggrid(D_MODEL / 128, ROWS / 128);  // (8,16)
        gemm_mfma<1><<<ggrid, 256, 0, stream>>>(x, Wq, Q, ROWS, D_MODEL, D_MODEL);
        gemm_mfma<1><<<ggrid, 256, 0, stream>>>(x, Wk, Kp, ROWS, D_MODEL, D_MODEL);
        gemm_mfma<1><<<ggrid, 256, 0, stream>>>(x, Wv, Vp, ROWS, D_MODEL, D_MODEL);
        beta_kernel<<<ROWS / 4, 256, 0, stream>>>(x, Wb, Bt);
        norm_qk<<<2 * ROWS * NHEAD / 4, 256, 0, stream>>>(Q, Kp);
        scan_chunked<<<BATCH * NHEAD, 256, SMEM_SCAN, stream>>>(Q, Kp, Vp, Bt, Y);
        rmsnorm_kernel<0><<<ROWS, 256, 0, stream>>>(Y, rms_w, nullptr, nullptr);
        gemm_mfma<0><<<ggrid, 256, 0, stream>>>(Y, Wo, out, ROWS, D_MODEL, D_MODEL);
    }
}

// Round 6
// 552.903 us; speedup vs baseline: 1.9504x; 1.9504x over previous
//
#include <hip/hip_runtime.h>
#include <math.h>

#define D_MODEL 1024
#define NHEAD 16
#define HEAD_DIM 64
#define BATCH 2
#define SEQ 1024
#define ROWS (BATCH * SEQ)        // 2048
#define RD (ROWS * D_MODEL)       // 2097152
#define WSZ (D_MODEL * D_MODEL)   // 1048576
#define CHUNK 64
#define NCHUNK (SEQ / CHUNK)      // 16

typedef __attribute__((ext_vector_type(8))) short bf16x8;
typedef __attribute__((ext_vector_type(8))) unsigned short ushort8;
typedef __attribute__((ext_vector_type(4))) unsigned short us4;
typedef __attribute__((ext_vector_type(4))) float f32x4;
typedef __attribute__((ext_vector_type(4))) unsigned int uint4v;
typedef unsigned short ushort;

// ---------------------------------------------------------------------------
// helpers
// ---------------------------------------------------------------------------
__device__ __forceinline__ void load_lds_16u(const unsigned short* g, unsigned short* l) {
    __builtin_amdgcn_global_load_lds((const __attribute__((address_space(1))) void*)g,
                                     (__attribute__((address_space(3))) void*)l, 16, 0, 0);
}
// fp32 -> bf16 RNE, and back
__device__ __forceinline__ unsigned short f2bf(float x) {
    unsigned int u = __float_as_uint(x);
    unsigned int r = (u + 0x7FFFu + ((u >> 16) & 1u)) >> 16;
    return (unsigned short)r;
}
__device__ __forceinline__ float bf2f(unsigned short h) {
    return __uint_as_float(((unsigned int)h) << 16);
}
// uniform-lane broadcast (SALU path, not LDS)
__device__ __forceinline__ float lane_bcast(float v, int lane) {
    return __uint_as_float(__builtin_amdgcn_readlane(__float_as_uint(v), lane));
}
// fragment-order index into a 64x64 bf16 operand buffer (R4/R5-validated):
// element (r,k) at subtile ((r>>4)*2 + (k>>5)) * 512 + ((((k&31)>>3)<<4) + (r&15))*8 + (k&7)
// NOTE: for k 8-aligned, elements (r, k..k+7) are CONTIGUOUS -> ushort8 stores.
__device__ __forceinline__ int fidx(int r, int k) {
    return (((r >> 4) * 2 + (k >> 5)) << 9) + ((((k & 31) >> 3) << 4) + (r & 15)) * 8 + (k & 7);
}

// ---------------------------------------------------------------------------
// split: fp32 -> (hi, lo) bf16 buffers. n4 = n/4 float4 groups.
// ---------------------------------------------------------------------------
__global__ __launch_bounds__(256) void split_kernel(const float* __restrict__ X,
                                                    unsigned short* __restrict__ H,
                                                    unsigned short* __restrict__ L,
                                                    int n4) {
    int i = blockIdx.x * 256 + threadIdx.x;
    if (i >= n4) return;
    float4 v = ((const float4*)X)[i];
    us4 h, l;
    h.x = f2bf(v.x); l.x = f2bf(v.x - bf2f(h.x));
    h.y = f2bf(v.y); l.y = f2bf(v.y - bf2f(h.y));
    h.z = f2bf(v.z); l.z = f2bf(v.z - bf2f(h.z));
    h.w = f2bf(v.w); l.w = f2bf(v.w - bf2f(h.w));
    ((us4*)H)[i] = h;
    ((us4*)L)[i] = l;
}

// ---------------------------------------------------------------------------
// Fast GEMM on pre-split inputs (unchanged from R4).
// ---------------------------------------------------------------------------
template <int ACT>
__global__ __launch_bounds__(256) void gemm_bf16s(const unsigned short* __restrict__ Ah,
                                                  const unsigned short* __restrict__ Al,
                                                  const unsigned short* __restrict__ Bh,
                                                  const unsigned short* __restrict__ Bl,
                                                  float* __restrict__ C,
                                                  int M, int N, int K) {
    __shared__ unsigned short LA[2][8 * 512];
    __shared__ unsigned short LB[2][4 * 512];

    const int t = threadIdx.x;
    const int wave = t >> 6, lane = t & 63;
    const int wm = wave >> 1, wn = wave & 1;
    const int m16 = lane & 15, kg = lane >> 4;
    const int row0 = blockIdx.y * 128, col0 = blockIdx.x * 64;

    f32x4 acc[4][2];
#pragma unroll
    for (int i = 0; i < 4; ++i)
#pragma unroll
        for (int j = 0; j < 2; ++j) acc[i][j] = (f32x4){0.f, 0.f, 0.f, 0.f};

    for (int k0 = 0; k0 < K; k0 += 32) {
#pragma unroll
        for (int ci = 0; ci < 6; ++ci) {
            const int c = wave * 6 + ci;
            const unsigned short* src;
            unsigned short* dst;
            int g16, rbase;
            if (c < 8)       { src = Ah; dst = &LA[0][c * 512];        g16 = c;      rbase = row0; }
            else if (c < 16) { src = Al; dst = &LA[1][(c - 8) * 512];  g16 = c - 8;  rbase = row0; }
            else if (c < 20) { src = Bh; dst = &LB[0][(c - 16) * 512]; g16 = c - 16; rbase = col0; }
            else             { src = Bl; dst = &LB[1][(c - 20) * 512]; g16 = c - 20; rbase = col0; }
            const unsigned short* gp = src + (size_t)(rbase + g16 * 16 + m16) * K + k0 + kg * 8;
            load_lds_16u(gp, dst);
        }
        __syncthreads();

        bf16x8 fah[4], fal[4], fbh[2], fbl[2];
#pragma unroll
        for (int mt = 0; mt < 4; ++mt) {
            const int off = (wm * 4 + mt) * 512 + lane * 8;
            fah[mt] = *(const bf16x8*)&LA[0][off];
            fal[mt] = *(const bf16x8*)&LA[1][off];
        }
#pragma unroll
        for (int nt = 0; nt < 2; ++nt) {
            const int off = (wn * 2 + nt) * 512 + lane * 8;
            fbh[nt] = *(const bf16x8*)&LB[0][off];
            fbl[nt] = *(const bf16x8*)&LB[1][off];
        }
#pragma unroll
        for (int mt = 0; mt < 4; ++mt)
#pragma unroll
            for (int nt = 0; nt < 2; ++nt) {
                acc[mt][nt] = __builtin_amdgcn_mfma_f32_16x16x32_bf16(fal[mt], fbh[nt], acc[mt][nt], 0, 0, 0);
                acc[mt][nt] = __builtin_amdgcn_mfma_f32_16x16x32_bf16(fah[mt], fbl[nt], acc[mt][nt], 0, 0, 0);
                acc[mt][nt] = __builtin_amdgcn_mfma_f32_16x16x32_bf16(fah[mt], fbh[nt], acc[mt][nt], 0, 0, 0);
            }
        __syncthreads();
    }

#pragma unroll
    for (int mt = 0; mt < 4; ++mt)
#pragma unroll
        for (int nt = 0; nt < 2; ++nt) {
            const int rowb = row0 + wm * 64 + mt * 16 + kg * 4;
            const int col  = col0 + wn * 32 + nt * 16 + m16;
#pragma unroll
            for (int rg = 0; rg < 4; ++rg) {
                float v = acc[mt][nt][rg];
                if (ACT == 1) v = v / (1.f + expf(-v));
                C[(size_t)(rowb + rg) * N + col] = v;
            }
        }
}

// ---------------------------------------------------------------------------
// Fallback GEMM (inline split) — only if ws_size too small.
// ---------------------------------------------------------------------------
#define LDST 40
template <int ACT>
__global__ __launch_bounds__(256) void gemm_mfma(const float* __restrict__ A,
                                                 const float* __restrict__ B,
                                                 float* __restrict__ C,
                                                 int M, int N, int K) {
    __shared__ unsigned short Ahi[128 * LDST], Alo[128 * LDST];
    __shared__ unsigned short Bhi[128 * LDST], Blo[128 * LDST];

    const int t = threadIdx.x;
    const int wave = t >> 6, lane = t & 63;
    const int wm = wave >> 1, wn = wave & 1;
    const int row0 = blockIdx.y * 128, col0 = blockIdx.x * 128;
    const int sr = t >> 1;
    const int sh = t & 1;
    const int m16 = lane & 15, kg = lane >> 4;

    f32x4 acc[4][4];
#pragma unroll
    for (int i = 0; i < 4; ++i)
#pragma unroll
        for (int j = 0; j < 4; ++j) acc[i][j] = (f32x4){0.f, 0.f, 0.f, 0.f};

    const float* ga = A + (size_t)(row0 + sr) * K + sh * 16;
    const float* gb = B + (size_t)(col0 + sr) * K + sh * 16;
    const int sbase = sr * LDST + sh * 16;

    for (int k0 = 0; k0 < K; k0 += 32) {
        float af[16], bf[16];
#pragma unroll
        for (int i = 0; i < 4; ++i) {
            float4 a4 = *(const float4*)(ga + k0 + i * 4);
            float4 b4 = *(const float4*)(gb + k0 + i * 4);
            af[i * 4 + 0] = a4.x; af[i * 4 + 1] = a4.y; af[i * 4 + 2] = a4.z; af[i * 4 + 3] = a4.w;
            bf[i * 4 + 0] = b4.x; bf[i * 4 + 1] = b4.y; bf[i * 4 + 2] = b4.z; bf[i * 4 + 3] = b4.w;
        }
        ushort8 ah0, ah1, al0, al1, bh0, bh1, bl0, bl1;
#pragma unroll
        for (int j = 0; j < 8; ++j) {
            unsigned short h = f2bf(af[j]);       ah0[j] = h; al0[j] = f2bf(af[j] - bf2f(h));
            h = f2bf(af[j + 8]);                  ah1[j] = h; al1[j] = f2bf(af[j + 8] - bf2f(h));
            h = f2bf(bf[j]);                      bh0[j] = h; bl0[j] = f2bf(bf[j] - bf2f(h));
            h = f2bf(bf[j + 8]);                  bh1[j] = h; bl1[j] = f2bf(bf[j + 8] - bf2f(h));
        }
        *(ushort8*)&Ahi[sbase] = ah0;  *(ushort8*)&Ahi[sbase + 8] = ah1;
        *(ushort8*)&Alo[sbase] = al0;  *(ushort8*)&Alo[sbase + 8] = al1;
        *(ushort8*)&Bhi[sbase] = bh0;  *(ushort8*)&Bhi[sbase + 8] = bh1;
        *(ushort8*)&Blo[sbase] = bl0;  *(ushort8*)&Blo[sbase + 8] = bl1;
        __syncthreads();

        bf16x8 fah[4], fal[4], fbh[4], fbl[4];
#pragma unroll
        for (int i = 0; i < 4; ++i) {
            const int ar = (wm * 64 + i * 16 + m16) * LDST + kg * 8;
            const int br = (wn * 64 + i * 16 + m16) * LDST + kg * 8;
            fah[i] = *(const bf16x8*)&Ahi[ar];
            fal[i] = *(const bf16x8*)&Alo[ar];
            fbh[i] = *(const bf16x8*)&Bhi[br];
            fbl[i] = *(const bf16x8*)&Blo[br];
        }
#pragma unroll
        for (int i = 0; i < 4; ++i)
#pragma unroll
            for (int j = 0; j < 4; ++j) {
                acc[i][j] = __builtin_amdgcn_mfma_f32_16x16x32_bf16(fal[i], fbh[j], acc[i][j], 0, 0, 0);
                acc[i][j] = __builtin_amdgcn_mfma_f32_16x16x32_bf16(fah[i], fbl[j], acc[i][j], 0, 0, 0);
                acc[i][j] = __builtin_amdgcn_mfma_f32_16x16x32_bf16(fah[i], fbh[j], acc[i][j], 0, 0, 0);
            }
        __syncthreads();
    }

#pragma unroll
    for (int i = 0; i < 4; ++i)
#pragma unroll
        for (int j = 0; j < 4; ++j) {
            const int col = col0 + wn * 64 + j * 16 + m16;
            const int rowb = row0 + wm * 64 + i * 16 + kg * 4;
#pragma unroll
            for (int rg = 0; rg < 4; ++rg) {
                float v = acc[i][j][rg];
                if (ACT == 1) v = v / (1.f + expf(-v));
                C[(size_t)(rowb + rg) * N + col] = v;
            }
        }
}

// ---------------------------------------------------------------------------
// beta = 2*sigmoid(x @ Wb^T)  : (ROWS, NHEAD). One wave per row.
// ---------------------------------------------------------------------------
__global__ __launch_bounds__(256) void beta_kernel(const float* __restrict__ x,
                                                   const float* __restrict__ Wb,
                                                   float* __restrict__ beta) {
    const int wave = blockIdx.x * 4 + (threadIdx.x >> 6);
    const int lane = threadIdx.x & 63;
    const float* xr = x + (size_t)wave * D_MODEL;
    float xv[16];
#pragma unroll
    for (int j = 0; j < 16; ++j) xv[j] = xr[lane + 64 * j];
    for (int n = 0; n < NHEAD; ++n) {
        const float* wr = Wb + (size_t)n * D_MODEL;
        float s = 0.f;
#pragma unroll
        for (int j = 0; j < 16; ++j) s += xv[j] * wr[lane + 64 * j];
#pragma unroll
        for (int off = 32; off; off >>= 1) s += __shfl_xor(s, off);
        if (lane == 0) beta[(size_t)wave * NHEAD + n] = 2.f / (1.f + expf(-s));
    }
}

// ---------------------------------------------------------------------------
// L2-normalize q and k per (row, head) over HEAD_DIM=64.
// ---------------------------------------------------------------------------
__global__ __launch_bounds__(256) void norm_qk(float* __restrict__ Q,
                                               float* __restrict__ Kp) {
    const int TOT = ROWS * NHEAD;
    int wave = blockIdx.x * 4 + (threadIdx.x >> 6);
    const int lane = threadIdx.x & 63;
    float* T = (wave < TOT) ? Q : Kp;
    int w = (wave < TOT) ? wave : wave - TOT;
    float* p = T + (size_t)(w >> 4) * D_MODEL + (size_t)(w & 15) * HEAD_DIM;
    float v = p[lane];
    float ss = v * v;
#pragma unroll
    for (int off = 32; off; off >>= 1) ss += __shfl_xor(ss, off);
    p[lane] = v / (sqrtf(ss) + 1e-6f);
}

// ---------------------------------------------------------------------------
// Chunked delta-rule scan v2: blocked solve.
//   W[t,s] = -beta_s*(C0[t,s] + sum_{u<s} A[t,u] W[s,u]),  strictly lower.
// Split sum: u < 16J  -> MFMA  N_J = A * W_J^T (W zero-padded above),
//            16J<=u<s -> in-register readlane chain (16 unrolled steps).
// Everything else as R5 (verified): products split-bf16 MFMA.
// ---------------------------------------------------------------------------
#define SMEM_SCAN 153088

__global__ __launch_bounds__(256, 1) void scan_chunked(const float* __restrict__ Qg,
                                                       const float* __restrict__ Kg,
                                                       const float* __restrict__ Vg,
                                                       const float* __restrict__ Btg,
                                                       float* __restrict__ Yg) {
    extern __shared__ char smem[];
    ushort* Mh_  = (ushort*)(smem + 0);
    ushort* Ml_  = (ushort*)(smem + 8192);
    ushort* MTh_ = (ushort*)(smem + 16384);
    ushort* MTl_ = (ushort*)(smem + 24576);
    ushort* KTh_ = (ushort*)(smem + 32768);
    ushort* KTl_ = (ushort*)(smem + 40960);
    ushort* V0h_ = (ushort*)(smem + 49152);
    ushort* V0l_ = (ushort*)(smem + 57344);
    ushort* Gh_  = (ushort*)(smem + 65536);
    ushort* Gl_  = (ushort*)(smem + 73728);
    ushort* Kh_  = (ushort*)(smem + 81920);   // union1: K (stage..C0) / DT (Delta..end)
    ushort* Kl_  = (ushort*)(smem + 90112);
    ushort* DTh_ = Kh_;
    ushort* DTl_ = Kl_;
    ushort* Qh_  = (ushort*)(smem + 98304);   // union2: Q (stage..QK) / W (solve..Delta)
    ushort* Ql_  = (ushort*)(smem + 106496);
    ushort* Wh_  = Qh_;
    ushort* Wl_  = Ql_;
    float*  V32  = (float*)(smem + 114688);   // 64x68 fp32 (union with C032)
    float*  C032 = V32;                       // written after V consumed (P_R)
    ushort* Ah_  = (ushort*)(smem + 132096);  // A split-bf16, fragment order
    ushort* Al_  = (ushort*)(smem + 140288);
    float*  N32  = (float*)(smem + 148480);   // 64x17 fp32
    float*  bv   = (float*)(smem + 152832);   // 64 fp32

    const int b = blockIdx.x >> 4;
    const int n = blockIdx.x & 15;
    const int t = threadIdx.x;
    const int wave = t >> 6, lane = t & 63;
    const int m16 = lane & 15, kg = lane >> 4;
    const int bS = b * SEQ;
    const int nOff = n * HEAD_DIM;
    const int r = t >> 2, g = t & 3;   // staging: row r, col-quarter g

    // zero state M, MT (hi+lo)
    for (int i = t; i < 2048; i += 256) {
        ((unsigned int*)Mh_)[i] = 0; ((unsigned int*)Ml_)[i] = 0;
        ((unsigned int*)MTh_)[i] = 0; ((unsigned int*)MTl_)[i] = 0;
    }
    __syncthreads();

    // product: wave's 16-row band x 64 cols, K=64, split operands, D = X*Y^T
    auto prod_band = [&](const ushort* Ah, const ushort* Al,
                         const ushort* Bh, const ushort* Bl, f32x4 acc[4]) {
        const int lo8 = lane * 8;
#pragma unroll
        for (int half = 0; half < 2; ++half) {
            bf16x8 ah = *(const bf16x8*)&Ah[((wave * 2 + half) << 9) + lo8];
            bf16x8 al = *(const bf16x8*)&Al[((wave * 2 + half) << 9) + lo8];
#pragma unroll
            for (int j = 0; j < 4; ++j) {
                bf16x8 bh = *(const bf16x8*)&Bh[((j * 2 + half) << 9) + lo8];
                bf16x8 bl = *(const bf16x8*)&Bl[((j * 2 + half) << 9) + lo8];
                acc[j] = __builtin_amdgcn_mfma_f32_16x16x32_bf16(al, bh, acc[j], 0, 0, 0);
                acc[j] = __builtin_amdgcn_mfma_f32_16x16x32_bf16(ah, bl, acc[j], 0, 0, 0);
                acc[j] = __builtin_amdgcn_mfma_f32_16x16x32_bf16(ah, bh, acc[j], 0, 0, 0);
            }
        }
    };

    for (int c = 0; c < NCHUNK; ++c) {
        const int s0 = c * CHUNK;

        // ---- stage K (+transpose), Q, V, beta; K/Q via octet b128 stores ----
        {
            const float* gK = Kg + (size_t)(bS + s0 + r) * D_MODEL + nOff + g * 16;
            const float* gQ = Qg + (size_t)(bS + s0 + r) * D_MODEL + nOff + g * 16;
            const float* gV = Vg + (size_t)(bS + s0 + r) * D_MODEL + nOff + g * 16;
            float kf[16], qf[16];
            ushort khv[16], klv[16];
#pragma unroll
            for (int j4 = 0; j4 < 4; ++j4) {
                float4 kv = ((const float4*)gK)[j4];
                float4 qv = ((const float4*)gQ)[j4];
                float4 vv = ((const float4*)gV)[j4];
                kf[j4 * 4 + 0] = kv.x; kf[j4 * 4 + 1] = kv.y;
                kf[j4 * 4 + 2] = kv.z; kf[j4 * 4 + 3] = kv.w;
                qf[j4 * 4 + 0] = qv.x; qf[j4 * 4 + 1] = qv.y;
                qf[j4 * 4 + 2] = qv.z; qf[j4 * 4 + 3] = qv.w;
                *(float4*)&V32[r * 68 + g * 16 + j4 * 4] = vv;
            }
            ushort8 kh8[2], kl8[2], qh8[2], ql8[2];
#pragma unroll
            for (int e = 0; e < 16; ++e) {
                ushort h = f2bf(kf[e]);
                ushort l = f2bf(kf[e] - bf2f(h));
                khv[e] = h; klv[e] = l;
                kh8[e >> 3][e & 7] = h; kl8[e >> 3][e & 7] = l;
                h = f2bf(qf[e]); l = f2bf(qf[e] - bf2f(h));
                qh8[e >> 3][e & 7] = h; ql8[e >> 3][e & 7] = l;
            }
            const int o0 = fidx(r, g * 16), o1 = fidx(r, g * 16 + 8);
            *(ushort8*)&Kh_[o0] = kh8[0]; *(ushort8*)&Kh_[o1] = kh8[1];
            *(ushort8*)&Kl_[o0] = kl8[0]; *(ushort8*)&Kl_[o1] = kl8[1];
            *(ushort8*)&Qh_[o0] = qh8[0]; *(ushort8*)&Qh_[o1] = qh8[1];
            *(ushort8*)&Ql_[o0] = ql8[0]; *(ushort8*)&Ql_[o1] = ql8[1];
#pragma unroll
            for (int e = 0; e < 16; ++e) {
                const int ib = fidx(g * 16 + e, r);
                KTh_[ib] = khv[e]; KTl_[ib] = klv[e];
            }
            if (t < 64) bv[t] = Btg[(size_t)(bS + s0 + t) * NHEAD + n];
        }
        __syncthreads();   // B1

        f32x4 yacc[4];
        {
            // ---- P_R: V0 = V - K*M0^T -> V0sp ----
            f32x4 acc[4];
#pragma unroll
            for (int j = 0; j < 4; ++j) acc[j] = (f32x4){0.f, 0.f, 0.f, 0.f};
            prod_band(Kh_, Kl_, Mh_, Ml_, acc);
#pragma unroll
            for (int j = 0; j < 4; ++j)
#pragma unroll
                for (int rg = 0; rg < 4; ++rg) {
                    const int row = wave * 16 + kg * 4 + rg, col = j * 16 + m16;
                    float v0 = V32[row * 68 + col] - acc[j][rg];
                    ushort h = f2bf(v0);
                    const int ii = fidx(row, col);
                    V0h_[ii] = h; V0l_[ii] = f2bf(v0 - bf2f(h));
                }
            // ---- P_YM: yacc = Q*M0 (via MT) ----
#pragma unroll
            for (int j = 0; j < 4; ++j) yacc[j] = (f32x4){0.f, 0.f, 0.f, 0.f};
            prod_band(Qh_, Ql_, MTh_, MTl_, yacc);
            // ---- P_A: A = K K^T -> Asp (split, fragment order) ----
#pragma unroll
            for (int j = 0; j < 4; ++j) acc[j] = (f32x4){0.f, 0.f, 0.f, 0.f};
            prod_band(Kh_, Kl_, Kh_, Kl_, acc);
#pragma unroll
            for (int j = 0; j < 4; ++j)
#pragma unroll
                for (int rg = 0; rg < 4; ++rg) {
                    const int row = wave * 16 + kg * 4 + rg, col = j * 16 + m16;
                    float av = acc[j][rg];
                    ushort h = f2bf(av);
                    const int ii = fidx(row, col);
                    Ah_[ii] = h; Al_[ii] = f2bf(av - bf2f(h));
                }
            // ---- P_QK: G = tril_(Q K^T) -> Gsp ----
#pragma unroll
            for (int j = 0; j < 4; ++j) acc[j] = (f32x4){0.f, 0.f, 0.f, 0.f};
            prod_band(Qh_, Ql_, Kh_, Kl_, acc);
#pragma unroll
            for (int j = 0; j < 4; ++j)
#pragma unroll
                for (int rg = 0; rg < 4; ++rg) {
                    const int row = wave * 16 + kg * 4 + rg, col = j * 16 + m16;
                    float gv = (row > col) ? acc[j][rg] : 0.f;
                    ushort h = f2bf(gv);
                    const int ii = fidx(row, col);
                    Gh_[ii] = h; Gl_[ii] = f2bf(gv - bf2f(h));
                }
        }
        __syncthreads();   // B2 (V32 dead -> C032 writable; Q dead -> W writable)

        {
            // ---- P_C0: C0 = K * V0^T -> fp32 ----
            f32x4 acc[4];
#pragma unroll
            for (int j = 0; j < 4; ++j) acc[j] = (f32x4){0.f, 0.f, 0.f, 0.f};
            prod_band(Kh_, Kl_, V0h_, V0l_, acc);
#pragma unroll
            for (int j = 0; j < 4; ++j)
#pragma unroll
                for (int rg = 0; rg < 4; ++rg) {
                    const int row = wave * 16 + kg * 4 + rg, col = j * 16 + m16;
                    C032[row * 68 + col] = acc[j][rg];
                }
            // zero W (over dead Q region): full-K N-prod needs zeros rightward
            uint4v z = (uint4v){0u, 0u, 0u, 0u};
            *(uint4v*)&((unsigned int*)Wh_)[t * 8]     = z;
            *(uint4v*)&((unsigned int*)Wh_)[t * 8 + 4] = z;
            *(uint4v*)&((unsigned int*)Wl_)[t * 8]     = z;
            *(uint4v*)&((unsigned int*)Wl_)[t * 8 + 4] = z;
        }
        __syncthreads();   // B3

        // ---- blocked solve: 4 column-blocks of 16 ----
#pragma unroll
        for (int J = 0; J < 4; ++J) {
            if (J > 0) {
                // N_J[t, s in J] = A * W_J^T (full K=64; W zero beyond computed)
                f32x4 acc1 = (f32x4){0.f, 0.f, 0.f, 0.f};
                const int lo8 = lane * 8;
#pragma unroll
                for (int half = 0; half < 2; ++half) {
                    bf16x8 ah = *(const bf16x8*)&Ah_[((wave * 2 + half) << 9) + lo8];
                    bf16x8 al = *(const bf16x8*)&Al_[((wave * 2 + half) << 9) + lo8];
                    bf16x8 bh = *(const bf16x8*)&Wh_[((J * 2 + half) << 9) + lo8];
                    bf16x8 bl = *(const bf16x8*)&Wl_[((J * 2 + half) << 9) + lo8];
                    acc1 = __builtin_amdgcn_mfma_f32_16x16x32_bf16(al, bh, acc1, 0, 0, 0);
                    acc1 = __builtin_amdgcn_mfma_f32_16x16x32_bf16(ah, bl, acc1, 0, 0, 0);
                    acc1 = __builtin_amdgcn_mfma_f32_16x16x32_bf16(ah, bh, acc1, 0, 0, 0);
                }
#pragma unroll
                for (int rg = 0; rg < 4; ++rg)
                    N32[(wave * 16 + kg * 4 + rg) * 17 + m16] = acc1[rg];
                __syncthreads();   // B4a
            }

            // preload A row (split->fp32), C0+N row slice, beta
            float Areg[16], CNreg[16];
            {
                bf16x8 a0 = *(const bf16x8*)&Ah_[fidx(lane, 16 * J)];
                bf16x8 a1 = *(const bf16x8*)&Ah_[fidx(lane, 16 * J + 8)];
                bf16x8 b0 = *(const bf16x8*)&Al_[fidx(lane, 16 * J)];
                bf16x8 b1 = *(const bf16x8*)&Al_[fidx(lane, 16 * J + 8)];
#pragma unroll
                for (int e = 0; e < 8; ++e) {
                    Areg[e]     = bf2f((ushort)a0[e]) + bf2f((ushort)b0[e]);
                    Areg[e + 8] = bf2f((ushort)a1[e]) + bf2f((ushort)b1[e]);
                }
#pragma unroll
                for (int j = 0; j < 16; ++j) CNreg[j] = C032[lane * 68 + 16 * J + j];
                if (J > 0) {
#pragma unroll
                    for (int j = 0; j < 16; ++j) CNreg[j] += N32[lane * 17 + j];
                }
            }
            float bvreg = bv[16 * J + m16];

            // 16 serial steps, branch-free, register+readlane only
            float wreg[16];
#pragma unroll
            for (int j = 0; j < 16; ++j) {
                float sum = CNreg[j];
#pragma unroll
                for (int jj = 0; jj < 16; ++jj) {
                    if (jj < j)
                        sum += Areg[jj] * lane_bcast(wreg[jj], 16 * J + j);
                }
                float beta_s = lane_bcast(bvreg, j);
                wreg[j] = (lane > 16 * J + j) ? (-beta_s * sum) : 0.f;
            }

            // wave 0 publishes W columns J (octet stores)
            if (wave == 0) {
                ushort8 h8[2], l8[2];
#pragma unroll
                for (int e = 0; e < 16; ++e) {
                    ushort h = f2bf(wreg[e]);
                    h8[e >> 3][e & 7] = h;
                    l8[e >> 3][e & 7] = f2bf(wreg[e] - bf2f(h));
                }
                const int o0 = fidx(lane, 16 * J), o1 = fidx(lane, 16 * J + 8);
                *(ushort8*)&Wh_[o0] = h8[0]; *(ushort8*)&Wh_[o1] = h8[1];
                *(ushort8*)&Wl_[o0] = l8[0]; *(ushort8*)&Wl_[o1] = l8[1];
            }
            __syncthreads();   // B4b
        }

        {
            // ---- P_Delta: Delta = V0 + W * K  (W as A-op, KT as B-op) ----
            f32x4 acc[4];
#pragma unroll
            for (int j = 0; j < 4; ++j)
#pragma unroll
                for (int rg = 0; rg < 4; ++rg) {
                    const int row = wave * 16 + kg * 4 + rg, col = j * 16 + m16;
                    const int ii = fidx(row, col);
                    acc[j][rg] = bf2f(V0h_[ii]) + bf2f(V0l_[ii]);
                }
            prod_band(Wh_, Wl_, KTh_, KTl_, acc);
#pragma unroll
            for (int j = 0; j < 4; ++j)
#pragma unroll
                for (int rg = 0; rg < 4; ++rg) {
                    const int row = wave * 16 + kg * 4 + rg, col = j * 16 + m16;
                    float dv = acc[j][rg] * bv[row];     // beta_s * delta_s[d]
                    ushort h = f2bf(dv);
                    const int ii = fidx(col, row);       // DT[d][s]
                    DTh_[ii] = h; DTl_[ii] = f2bf(dv - bf2f(h));
                }
        }
        __syncthreads();   // B5 (DT ready)

        {
            // ---- P_Y2: Y = yacc + G * DT^T -> global ----
            prod_band(Gh_, Gl_, DTh_, DTl_, yacc);
#pragma unroll
            for (int j = 0; j < 4; ++j)
#pragma unroll
                for (int rg = 0; rg < 4; ++rg) {
                    const int row = wave * 16 + kg * 4 + rg, col = j * 16 + m16;
                    Yg[(size_t)(bS + s0 + row) * D_MODEL + nOff + col] = yacc[j][rg];
                }
            // ---- P_M: M += K^T * DT^T ----
            f32x4 acc[4];
#pragma unroll
            for (int j = 0; j < 4; ++j)
#pragma unroll
                for (int rg = 0; rg < 4; ++rg) {
                    const int row = wave * 16 + kg * 4 + rg, col = j * 16 + m16;
                    const int ii = fidx(row, col);
                    acc[j][rg] = bf2f(Mh_[ii]) + bf2f(Ml_[ii]);
                }
            prod_band(KTh_, KTl_, DTh_, DTl_, acc);
#pragma unroll
            for (int j = 0; j < 4; ++j)
#pragma unroll
                for (int rg = 0; rg < 4; ++rg) {
                    const int row = wave * 16 + kg * 4 + rg, col = j * 16 + m16;
                    float mv = acc[j][rg];
                    ushort h = f2bf(mv);
                    const int ii = fidx(row, col);
                    Mh_[ii] = h; Ml_[ii] = f2bf(mv - bf2f(h));
                }
            // ---- P_MT: MT += DT * K ----
#pragma unroll
            for (int j = 0; j < 4; ++j)
#pragma unroll
                for (int rg = 0; rg < 4; ++rg) {
                    const int row = wave * 16 + kg * 4 + rg, col = j * 16 + m16;
                    const int ii = fidx(row, col);
                    acc[j][rg] = bf2f(MTh_[ii]) + bf2f(MTl_[ii]);
                }
            prod_band(DTh_, DTl_, KTh_, KTl_, acc);
#pragma unroll
            for (int j = 0; j < 4; ++j)
#pragma unroll
                for (int rg = 0; rg < 4; ++rg) {
                    const int row = wave * 16 + kg * 4 + rg, col = j * 16 + m16;
                    float mv = acc[j][rg];
                    ushort h = f2bf(mv);
                    const int ii = fidx(row, col);
                    MTh_[ii] = h; MTl_[ii] = f2bf(mv - bf2f(h));
                }
        }
        __syncthreads();   // B6
    }
}

// ---------------------------------------------------------------------------
// RMSNorm. SPLIT=1: write (hi,lo) bf16 for final GEMM. SPLIT=0: fp32 in place.
// ---------------------------------------------------------------------------
template <int SPLIT>
__global__ __launch_bounds__(256) void rmsnorm_kernel(float* __restrict__ Y,
                                                      const float* __restrict__ w,
                                                      unsigned short* __restrict__ H,
                                                      unsigned short* __restrict__ L) {
    __shared__ float red[4];
    float* y = Y + (size_t)blockIdx.x * D_MODEL;
    const int t = threadIdx.x;
    const int wv = t >> 6, ln = t & 63;
    float4 v = ((float4*)y)[t];
    float ss = v.x * v.x + v.y * v.y + v.z * v.z + v.w * v.w;
#pragma unroll
    for (int off = 32; off; off >>= 1) ss += __shfl_xor(ss, off);
    if (ln == 0) red[wv] = ss;
    __syncthreads();
    float tot = red[0] + red[1] + red[2] + red[3];
    float inv = 1.f / sqrtf(tot * (1.f / D_MODEL) + 1e-6f);
    const float4 wv4 = ((const float4*)w)[t];
    v.x *= inv * wv4.x; v.y *= inv * wv4.y;
    v.z *= inv * wv4.z; v.w *= inv * wv4.w;
    if (SPLIT) {
        us4 h, l;
        h.x = f2bf(v.x); l.x = f2bf(v.x - bf2f(h.x));
        h.y = f2bf(v.y); l.y = f2bf(v.y - bf2f(h.y));
        h.z = f2bf(v.z); l.z = f2bf(v.z - bf2f(h.z));
        h.w = f2bf(v.w); l.w = f2bf(v.w - bf2f(h.w));
        size_t i = (size_t)blockIdx.x * 256 + t;
        ((us4*)H)[i] = h;
        ((us4*)L)[i] = l;
    } else {
        ((float4*)y)[t] = v;
    }
}

// ---------------------------------------------------------------------------
extern "C" void kernel_launch(void* const* d_in, const int* in_sizes, int n_in,
                              void* d_out, int out_size, void* d_ws, size_t ws_size,
                              hipStream_t stream) {
    const float* x     = (const float*)d_in[0];
    const float* Wq    = (const float*)d_in[1];
    const float* Wk    = (const float*)d_in[2];
    const float* Wv    = (const float*)d_in[3];
    const float* Wb    = (const float*)d_in[4];
    const float* Wo    = (const float*)d_in[5];
    const float* rms_w = (const float*)d_in[6];
    float* out = (float*)d_out;

    char* p = (char*)d_ws;
    float* Q  = (float*)p;  p += (size_t)RD * 4;
    float* Kp = (float*)p;  p += (size_t)RD * 4;
    float* Vp = (float*)p;  p += (size_t)RD * 4;
    float* Y  = (float*)p;  p += (size_t)RD * 4;
    float* Bt = (float*)p;  p += (size_t)32768 * 4;
    unsigned short* xh  = (unsigned short*)p;  p += (size_t)RD * 2;   // reused as Yh
    unsigned short* xl  = (unsigned short*)p;  p += (size_t)RD * 2;   // reused as Yl
    unsigned short* Wsh = (unsigned short*)p;  p += (size_t)WSZ * 2;
    unsigned short* Wsl = (unsigned short*)p;  p += (size_t)WSZ * 2;
    const size_t need_fast = (size_t)RD * 16 + 131072 + (size_t)RD * 4 + (size_t)WSZ * 4;
    const bool fast = ws_size >= need_fast;

    (void)hipFuncSetAttribute(reinterpret_cast<const void*>(scan_chunked),
                              hipFuncAttributeMaxDynamicSharedMemorySize, SMEM_SCAN);

    if (fast) {
        dim3 ggrid(D_MODEL / 64, ROWS / 128);   // (16,16) = 256 blocks
        split_kernel<<<RD / 4 / 256, 256, 0, stream>>>(x, xh, xl, RD / 4);
        split_kernel<<<WSZ / 4 / 256, 256, 0, stream>>>(Wq, Wsh, Wsl, WSZ / 4);
        gemm_bf16s<1><<<ggrid, 256, 0, stream>>>(xh, xl, Wsh, Wsl, Q, ROWS, D_MODEL, D_MODEL);
        split_kernel<<<WSZ / 4 / 256, 256, 0, stream>>>(Wk, Wsh, Wsl, WSZ / 4);
        gemm_bf16s<1><<<ggrid, 256, 0, stream>>>(xh, xl, Wsh, Wsl, Kp, ROWS, D_MODEL, D_MODEL);
        split_kernel<<<WSZ / 4 / 256, 256, 0, stream>>>(Wv, Wsh, Wsl, WSZ / 4);
        gemm_bf16s<1><<<ggrid, 256, 0, stream>>>(xh, xl, Wsh, Wsl, Vp, ROWS, D_MODEL, D_MODEL);
        beta_kernel<<<ROWS / 4, 256, 0, stream>>>(x, Wb, Bt);
        norm_qk<<<2 * ROWS * NHEAD / 4, 256, 0, stream>>>(Q, Kp);
        scan_chunked<<<BATCH * NHEAD, 256, SMEM_SCAN, stream>>>(Q, Kp, Vp, Bt, Y);
        rmsnorm_kernel<1><<<ROWS, 256, 0, stream>>>(Y, rms_w, xh, xl);
        split_kernel<<<WSZ / 4 / 256, 256, 0, stream>>>(Wo, Wsh, Wsl, WSZ / 4);
        gemm_bf16s<0><<<ggrid, 256, 0, stream>>>(xh, xl, Wsh, Wsl, out, ROWS, D_MODEL, D_MODEL);
    } else {
        dim3 ggrid(D_MODEL / 128, ROWS / 128);  // (8,16)
        gemm_mfma<1><<<ggrid, 256, 0, stream>>>(x, Wq, Q, ROWS, D_MODEL, D_MODEL);
        gemm_mfma<1><<<ggrid, 256, 0, stream>>>(x, Wk, Kp, ROWS, D_MODEL, D_MODEL);
        gemm_mfma<1><<<ggrid, 256, 0, stream>>>(x, Wv, Vp, ROWS, D_MODEL, D_MODEL);
        beta_kernel<<<ROWS / 4, 256, 0, stream>>>(x, Wb, Bt);
        norm_qk<<<2 * ROWS * NHEAD / 4, 256, 0, stream>>>(Q, Kp);
        scan_chunked<<<BATCH * NHEAD, 256, SMEM_SCAN, stream>>>(Q, Kp, Vp, Bt, Y);
        rmsnorm_kernel<0><<<ROWS, 256, 0, stream>>>(Y, rms_w, nullptr, nullptr);
        gemm_mfma<0><<<ggrid, 256, 0, stream>>>(Y, Wo, out, ROWS, D_MODEL, D_MODEL);
    }
}

// Round 7
// 505.417 us; speedup vs baseline: 2.1336x; 1.0940x over previous
//
#include <hip/hip_runtime.h>
#include <math.h>

#define D_MODEL 1024
#define NHEAD 16
#define HEAD_DIM 64
#define BATCH 2
#define SEQ 1024
#define ROWS (BATCH * SEQ)        // 2048
#define RD (ROWS * D_MODEL)       // 2097152
#define WSZ (D_MODEL * D_MODEL)   // 1048576
#define CHUNK 64
#define NCHUNK (SEQ / CHUNK)      // 16

typedef __attribute__((ext_vector_type(8))) short bf16x8;
typedef __attribute__((ext_vector_type(8))) unsigned short ushort8;
typedef __attribute__((ext_vector_type(4))) unsigned short us4;
typedef __attribute__((ext_vector_type(4))) float f32x4;
typedef __attribute__((ext_vector_type(4))) unsigned int uint4v;
typedef unsigned short ushort;

// ---------------------------------------------------------------------------
// helpers
// ---------------------------------------------------------------------------
__device__ __forceinline__ void load_lds_16u(const unsigned short* g, unsigned short* l) {
    __builtin_amdgcn_global_load_lds((const __attribute__((address_space(1))) void*)g,
                                     (__attribute__((address_space(3))) void*)l, 16, 0, 0);
}
// fp32 -> bf16 RNE, and back
__device__ __forceinline__ unsigned short f2bf(float x) {
    unsigned int u = __float_as_uint(x);
    unsigned int r = (u + 0x7FFFu + ((u >> 16) & 1u)) >> 16;
    return (unsigned short)r;
}
__device__ __forceinline__ float bf2f(unsigned short h) {
    return __uint_as_float(((unsigned int)h) << 16);
}
// uniform-lane broadcast (SALU path, not LDS)
__device__ __forceinline__ float lane_bcast(float v, int lane) {
    return __uint_as_float(__builtin_amdgcn_readlane(__float_as_uint(v), lane));
}
// fragment-order index, PADDED subtile stride 520 ushorts (1040 B):
//   subtile = (r>>4)*2 + (k>>5); within = (((k&31)>>3)*16 + (r&15))*8 + (k&7)
// 520 stride rotates banks by 8 per subtile -> breaks the KT-scatter 8-way
// conflict (R6 measured 2.88M SQ_LDS_BANK_CONFLICT with 512 stride).
#define SUBST 520
#define FBUF (8 * SUBST * 2)   // bytes per 64x64 operand buffer = 8320
__device__ __forceinline__ int fidx(int r, int k) {
    return ((r >> 4) * 2 + (k >> 5)) * SUBST + ((((k & 31) >> 3) << 4) + (r & 15)) * 8 + (k & 7);
}

// ---------------------------------------------------------------------------
// split: fp32 -> (hi, lo) bf16 buffers. n4 = n/4 float4 groups.
// ---------------------------------------------------------------------------
__global__ __launch_bounds__(256) void split_kernel(const float* __restrict__ X,
                                                    unsigned short* __restrict__ H,
                                                    unsigned short* __restrict__ L,
                                                    int n4) {
    int i = blockIdx.x * 256 + threadIdx.x;
    if (i >= n4) return;
    float4 v = ((const float4*)X)[i];
    us4 h, l;
    h.x = f2bf(v.x); l.x = f2bf(v.x - bf2f(h.x));
    h.y = f2bf(v.y); l.y = f2bf(v.y - bf2f(h.y));
    h.z = f2bf(v.z); l.z = f2bf(v.z - bf2f(h.z));
    h.w = f2bf(v.w); l.w = f2bf(v.w - bf2f(h.w));
    ((us4*)H)[i] = h;
    ((us4*)L)[i] = l;
}

// fused 3-way weight split (one launch for Wq, Wk, Wv)
__global__ __launch_bounds__(256) void split3_kernel(const float* __restrict__ W0,
                                                     const float* __restrict__ W1,
                                                     const float* __restrict__ W2,
                                                     unsigned short* __restrict__ H0,
                                                     unsigned short* __restrict__ L0,
                                                     unsigned short* __restrict__ H1,
                                                     unsigned short* __restrict__ L1,
                                                     unsigned short* __restrict__ H2,
                                                     unsigned short* __restrict__ L2) {
    const int n4 = WSZ / 4;
    int i = blockIdx.x * 256 + threadIdx.x;
    const int which = i / n4;
    const int j = i - which * n4;
    const float* X = (which == 0) ? W0 : (which == 1) ? W1 : W2;
    unsigned short* H = (which == 0) ? H0 : (which == 1) ? H1 : H2;
    unsigned short* L = (which == 0) ? L0 : (which == 1) ? L1 : L2;
    float4 v = ((const float4*)X)[j];
    us4 h, l;
    h.x = f2bf(v.x); l.x = f2bf(v.x - bf2f(h.x));
    h.y = f2bf(v.y); l.y = f2bf(v.y - bf2f(h.y));
    h.z = f2bf(v.z); l.z = f2bf(v.z - bf2f(h.z));
    h.w = f2bf(v.w); l.w = f2bf(v.w - bf2f(h.w));
    ((us4*)H)[j] = h;
    ((us4*)L)[j] = l;
}

// ---------------------------------------------------------------------------
// GEMM core on pre-split inputs (R4-validated structure).
// Tile 128(M)x64(N), BK=32, 256 thr = 4 waves (2x2; wave tile 64x32).
// ---------------------------------------------------------------------------
template <int ACT>
__device__ __forceinline__ void gemm_core(const unsigned short* __restrict__ Ah,
                                          const unsigned short* __restrict__ Al,
                                          const unsigned short* __restrict__ Bh,
                                          const unsigned short* __restrict__ Bl,
                                          float* __restrict__ C,
                                          int M, int N, int K,
                                          unsigned short* LA0, unsigned short* LA1,
                                          unsigned short* LB0, unsigned short* LB1) {
    const int t = threadIdx.x;
    const int wave = t >> 6, lane = t & 63;
    const int wm = wave >> 1, wn = wave & 1;
    const int m16 = lane & 15, kg = lane >> 4;
    const int row0 = blockIdx.y * 128, col0 = blockIdx.x * 64;

    f32x4 acc[4][2];
#pragma unroll
    for (int i = 0; i < 4; ++i)
#pragma unroll
        for (int j = 0; j < 2; ++j) acc[i][j] = (f32x4){0.f, 0.f, 0.f, 0.f};

    for (int k0 = 0; k0 < K; k0 += 32) {
#pragma unroll
        for (int ci = 0; ci < 6; ++ci) {
            const int c = wave * 6 + ci;
            const unsigned short* src;
            unsigned short* dst;
            int g16, rbase;
            if (c < 8)       { src = Ah; dst = &LA0[c * 512];        g16 = c;      rbase = row0; }
            else if (c < 16) { src = Al; dst = &LA1[(c - 8) * 512];  g16 = c - 8;  rbase = row0; }
            else if (c < 20) { src = Bh; dst = &LB0[(c - 16) * 512]; g16 = c - 16; rbase = col0; }
            else             { src = Bl; dst = &LB1[(c - 20) * 512]; g16 = c - 20; rbase = col0; }
            const unsigned short* gp = src + (size_t)(rbase + g16 * 16 + m16) * K + k0 + kg * 8;
            load_lds_16u(gp, dst);
        }
        __syncthreads();

        bf16x8 fah[4], fal[4], fbh[2], fbl[2];
#pragma unroll
        for (int mt = 0; mt < 4; ++mt) {
            const int off = (wm * 4 + mt) * 512 + lane * 8;
            fah[mt] = *(const bf16x8*)&LA0[off];
            fal[mt] = *(const bf16x8*)&LA1[off];
        }
#pragma unroll
        for (int nt = 0; nt < 2; ++nt) {
            const int off = (wn * 2 + nt) * 512 + lane * 8;
            fbh[nt] = *(const bf16x8*)&LB0[off];
            fbl[nt] = *(const bf16x8*)&LB1[off];
        }
#pragma unroll
        for (int mt = 0; mt < 4; ++mt)
#pragma unroll
            for (int nt = 0; nt < 2; ++nt) {
                acc[mt][nt] = __builtin_amdgcn_mfma_f32_16x16x32_bf16(fal[mt], fbh[nt], acc[mt][nt], 0, 0, 0);
                acc[mt][nt] = __builtin_amdgcn_mfma_f32_16x16x32_bf16(fah[mt], fbl[nt], acc[mt][nt], 0, 0, 0);
                acc[mt][nt] = __builtin_amdgcn_mfma_f32_16x16x32_bf16(fah[mt], fbh[nt], acc[mt][nt], 0, 0, 0);
            }
        __syncthreads();
    }

#pragma unroll
    for (int mt = 0; mt < 4; ++mt)
#pragma unroll
        for (int nt = 0; nt < 2; ++nt) {
            const int rowb = row0 + wm * 64 + mt * 16 + kg * 4;
            const int col  = col0 + wn * 32 + nt * 16 + m16;
#pragma unroll
            for (int rg = 0; rg < 4; ++rg) {
                float v = acc[mt][nt][rg];
                if (ACT == 1) v = v / (1.f + expf(-v));
                C[(size_t)(rowb + rg) * N + col] = v;
            }
        }
}

// single GEMM (final projection)
template <int ACT>
__global__ __launch_bounds__(256) void gemm_bf16s(const unsigned short* __restrict__ Ah,
                                                  const unsigned short* __restrict__ Al,
                                                  const unsigned short* __restrict__ Bh,
                                                  const unsigned short* __restrict__ Bl,
                                                  float* __restrict__ C,
                                                  int M, int N, int K) {
    __shared__ unsigned short LA[2][8 * 512];
    __shared__ unsigned short LB[2][4 * 512];
    gemm_core<ACT>(Ah, Al, Bh, Bl, C, M, N, K, LA[0], LA[1], LB[0], LB[1]);
}

// fused QKV GEMM: blockIdx.z selects weight/output; 768 blocks = 3/CU
__global__ __launch_bounds__(256) void gemm_qkv(const unsigned short* __restrict__ Ah,
                                                const unsigned short* __restrict__ Al,
                                                const unsigned short* __restrict__ Bqh,
                                                const unsigned short* __restrict__ Bql,
                                                const unsigned short* __restrict__ Bkh,
                                                const unsigned short* __restrict__ Bkl,
                                                const unsigned short* __restrict__ Bvh,
                                                const unsigned short* __restrict__ Bvl,
                                                float* __restrict__ Cq,
                                                float* __restrict__ Ck,
                                                float* __restrict__ Cv) {
    __shared__ unsigned short LA[2][8 * 512];
    __shared__ unsigned short LB[2][4 * 512];
    const int z = blockIdx.z;
    const unsigned short* Bh = (z == 0) ? Bqh : (z == 1) ? Bkh : Bvh;
    const unsigned short* Bl = (z == 0) ? Bql : (z == 1) ? Bkl : Bvl;
    float* C = (z == 0) ? Cq : (z == 1) ? Ck : Cv;
    gemm_core<1>(Ah, Al, Bh, Bl, C, ROWS, D_MODEL, D_MODEL, LA[0], LA[1], LB[0], LB[1]);
}

// ---------------------------------------------------------------------------
// Fallback GEMM (inline split) — only if ws_size too small.
// ---------------------------------------------------------------------------
#define LDST 40
template <int ACT>
__global__ __launch_bounds__(256) void gemm_mfma(const float* __restrict__ A,
                                                 const float* __restrict__ B,
                                                 float* __restrict__ C,
                                                 int M, int N, int K) {
    __shared__ unsigned short Ahi[128 * LDST], Alo[128 * LDST];
    __shared__ unsigned short Bhi[128 * LDST], Blo[128 * LDST];

    const int t = threadIdx.x;
    const int wave = t >> 6, lane = t & 63;
    const int wm = wave >> 1, wn = wave & 1;
    const int row0 = blockIdx.y * 128, col0 = blockIdx.x * 128;
    const int sr = t >> 1;
    const int sh = t & 1;
    const int m16 = lane & 15, kg = lane >> 4;

    f32x4 acc[4][4];
#pragma unroll
    for (int i = 0; i < 4; ++i)
#pragma unroll
        for (int j = 0; j < 4; ++j) acc[i][j] = (f32x4){0.f, 0.f, 0.f, 0.f};

    const float* ga = A + (size_t)(row0 + sr) * K + sh * 16;
    const float* gb = B + (size_t)(col0 + sr) * K + sh * 16;
    const int sbase = sr * LDST + sh * 16;

    for (int k0 = 0; k0 < K; k0 += 32) {
        float af[16], bf[16];
#pragma unroll
        for (int i = 0; i < 4; ++i) {
            float4 a4 = *(const float4*)(ga + k0 + i * 4);
            float4 b4 = *(const float4*)(gb + k0 + i * 4);
            af[i * 4 + 0] = a4.x; af[i * 4 + 1] = a4.y; af[i * 4 + 2] = a4.z; af[i * 4 + 3] = a4.w;
            bf[i * 4 + 0] = b4.x; bf[i * 4 + 1] = b4.y; bf[i * 4 + 2] = b4.z; bf[i * 4 + 3] = b4.w;
        }
        ushort8 ah0, ah1, al0, al1, bh0, bh1, bl0, bl1;
#pragma unroll
        for (int j = 0; j < 8; ++j) {
            unsigned short h = f2bf(af[j]);       ah0[j] = h; al0[j] = f2bf(af[j] - bf2f(h));
            h = f2bf(af[j + 8]);                  ah1[j] = h; al1[j] = f2bf(af[j + 8] - bf2f(h));
            h = f2bf(bf[j]);                      bh0[j] = h; bl0[j] = f2bf(bf[j] - bf2f(h));
            h = f2bf(bf[j + 8]);                  bh1[j] = h; bl1[j] = f2bf(bf[j + 8] - bf2f(h));
        }
        *(ushort8*)&Ahi[sbase] = ah0;  *(ushort8*)&Ahi[sbase + 8] = ah1;
        *(ushort8*)&Alo[sbase] = al0;  *(ushort8*)&Alo[sbase + 8] = al1;
        *(ushort8*)&Bhi[sbase] = bh0;  *(ushort8*)&Bhi[sbase + 8] = bh1;
        *(ushort8*)&Blo[sbase] = bl0;  *(ushort8*)&Blo[sbase + 8] = bl1;
        __syncthreads();

        bf16x8 fah[4], fal[4], fbh[4], fbl[4];
#pragma unroll
        for (int i = 0; i < 4; ++i) {
            const int ar = (wm * 64 + i * 16 + m16) * LDST + kg * 8;
            const int br = (wn * 64 + i * 16 + m16) * LDST + kg * 8;
            fah[i] = *(const bf16x8*)&Ahi[ar];
            fal[i] = *(const bf16x8*)&Alo[ar];
            fbh[i] = *(const bf16x8*)&Bhi[br];
            fbl[i] = *(const bf16x8*)&Blo[br];
        }
#pragma unroll
        for (int i = 0; i < 4; ++i)
#pragma unroll
            for (int j = 0; j < 4; ++j) {
                acc[i][j] = __builtin_amdgcn_mfma_f32_16x16x32_bf16(fal[i], fbh[j], acc[i][j], 0, 0, 0);
                acc[i][j] = __builtin_amdgcn_mfma_f32_16x16x32_bf16(fah[i], fbl[j], acc[i][j], 0, 0, 0);
                acc[i][j] = __builtin_amdgcn_mfma_f32_16x16x32_bf16(fah[i], fbh[j], acc[i][j], 0, 0, 0);
            }
        __syncthreads();
    }

#pragma unroll
    for (int i = 0; i < 4; ++i)
#pragma unroll
        for (int j = 0; j < 4; ++j) {
            const int col = col0 + wn * 64 + j * 16 + m16;
            const int rowb = row0 + wm * 64 + i * 16 + kg * 4;
#pragma unroll
            for (int rg = 0; rg < 4; ++rg) {
                float v = acc[i][j][rg];
                if (ACT == 1) v = v / (1.f + expf(-v));
                C[(size_t)(rowb + rg) * N + col] = v;
            }
        }
}

// ---------------------------------------------------------------------------
// beta = 2*sigmoid(x @ Wb^T)  : (ROWS, NHEAD). One wave per row.
// ---------------------------------------------------------------------------
__global__ __launch_bounds__(256) void beta_kernel(const float* __restrict__ x,
                                                   const float* __restrict__ Wb,
                                                   float* __restrict__ beta) {
    const int wave = blockIdx.x * 4 + (threadIdx.x >> 6);
    const int lane = threadIdx.x & 63;
    const float* xr = x + (size_t)wave * D_MODEL;
    float xv[16];
#pragma unroll
    for (int j = 0; j < 16; ++j) xv[j] = xr[lane + 64 * j];
    for (int n = 0; n < NHEAD; ++n) {
        const float* wr = Wb + (size_t)n * D_MODEL;
        float s = 0.f;
#pragma unroll
        for (int j = 0; j < 16; ++j) s += xv[j] * wr[lane + 64 * j];
#pragma unroll
        for (int off = 32; off; off >>= 1) s += __shfl_xor(s, off);
        if (lane == 0) beta[(size_t)wave * NHEAD + n] = 2.f / (1.f + expf(-s));
    }
}

// ---------------------------------------------------------------------------
// L2-normalize q and k per (row, head) over HEAD_DIM=64.
// ---------------------------------------------------------------------------
__global__ __launch_bounds__(256) void norm_qk(float* __restrict__ Q,
                                               float* __restrict__ Kp) {
    const int TOT = ROWS * NHEAD;
    int wave = blockIdx.x * 4 + (threadIdx.x >> 6);
    const int lane = threadIdx.x & 63;
    float* T = (wave < TOT) ? Q : Kp;
    int w = (wave < TOT) ? wave : wave - TOT;
    float* p = T + (size_t)(w >> 4) * D_MODEL + (size_t)(w & 15) * HEAD_DIM;
    float v = p[lane];
    float ss = v * v;
#pragma unroll
    for (int off = 32; off; off >>= 1) ss += __shfl_xor(ss, off);
    p[lane] = v / (sqrtf(ss) + 1e-6f);
}

// ---------------------------------------------------------------------------
// Chunked delta-rule scan (R6-validated math; buffers padded to SUBST=520).
// ---------------------------------------------------------------------------
#define SMEM_SCAN 155136

__global__ __launch_bounds__(256, 1) void scan_chunked(const float* __restrict__ Qg,
                                                       const float* __restrict__ Kg,
                                                       const float* __restrict__ Vg,
                                                       const float* __restrict__ Btg,
                                                       float* __restrict__ Yg) {
    extern __shared__ char smem[];
    ushort* Mh_  = (ushort*)(smem + 0 * FBUF);
    ushort* Ml_  = (ushort*)(smem + 1 * FBUF);
    ushort* MTh_ = (ushort*)(smem + 2 * FBUF);
    ushort* MTl_ = (ushort*)(smem + 3 * FBUF);
    ushort* KTh_ = (ushort*)(smem + 4 * FBUF);
    ushort* KTl_ = (ushort*)(smem + 5 * FBUF);
    ushort* V0h_ = (ushort*)(smem + 6 * FBUF);
    ushort* V0l_ = (ushort*)(smem + 7 * FBUF);
    ushort* Gh_  = (ushort*)(smem + 8 * FBUF);
    ushort* Gl_  = (ushort*)(smem + 9 * FBUF);
    ushort* Kh_  = (ushort*)(smem + 10 * FBUF);  // union1: K / DT
    ushort* Kl_  = (ushort*)(smem + 11 * FBUF);
    ushort* DTh_ = Kh_;
    ushort* DTl_ = Kl_;
    ushort* Qh_  = (ushort*)(smem + 12 * FBUF);  // union2: Q / W (adjacent hi,lo)
    ushort* Ql_  = (ushort*)(smem + 13 * FBUF);
    ushort* Wh_  = Qh_;
    ushort* Wl_  = Ql_;
    float*  V32  = (float*)(smem + 14 * FBUF);             // 64x68 fp32 (union C032)
    float*  C032 = V32;
    ushort* Ah_  = (ushort*)(smem + 14 * FBUF + 17408);
    ushort* Al_  = (ushort*)(smem + 15 * FBUF + 17408);
    float*  N32  = (float*)(smem + 16 * FBUF + 17408);     // 64x17 fp32
    float*  bv   = (float*)(smem + 16 * FBUF + 17408 + 4352);

    const int b = blockIdx.x >> 4;
    const int n = blockIdx.x & 15;
    const int t = threadIdx.x;
    const int wave = t >> 6, lane = t & 63;
    const int m16 = lane & 15, kg = lane >> 4;
    const int bS = b * SEQ;
    const int nOff = n * HEAD_DIM;
    const int r = t >> 2, g = t & 3;   // staging: row r, col-quarter g

    // zero state M, MT (hi+lo): 4 x FBUF bytes
    for (int i = t; i < 4 * FBUF / 16; i += 256)
        ((uint4v*)Mh_)[i] = (uint4v){0u, 0u, 0u, 0u};
    __syncthreads();

    // product: wave's 16-row band x 64 cols, K=64, split operands, D = X*Y^T
    auto prod_band = [&](const ushort* Ah, const ushort* Al,
                         const ushort* Bh, const ushort* Bl, f32x4 acc[4]) {
        const int lo8 = lane * 8;
#pragma unroll
        for (int half = 0; half < 2; ++half) {
            bf16x8 ah = *(const bf16x8*)&Ah[(wave * 2 + half) * SUBST + lo8];
            bf16x8 al = *(const bf16x8*)&Al[(wave * 2 + half) * SUBST + lo8];
#pragma unroll
            for (int j = 0; j < 4; ++j) {
                bf16x8 bh = *(const bf16x8*)&Bh[(j * 2 + half) * SUBST + lo8];
                bf16x8 bl = *(const bf16x8*)&Bl[(j * 2 + half) * SUBST + lo8];
                acc[j] = __builtin_amdgcn_mfma_f32_16x16x32_bf16(al, bh, acc[j], 0, 0, 0);
                acc[j] = __builtin_amdgcn_mfma_f32_16x16x32_bf16(ah, bl, acc[j], 0, 0, 0);
                acc[j] = __builtin_amdgcn_mfma_f32_16x16x32_bf16(ah, bh, acc[j], 0, 0, 0);
            }
        }
    };

    for (int c = 0; c < NCHUNK; ++c) {
        const int s0 = c * CHUNK;

        // ---- stage K (+transpose), Q, V, beta; K/Q via octet b128 stores ----
        {
            const float* gK = Kg + (size_t)(bS + s0 + r) * D_MODEL + nOff + g * 16;
            const float* gQ = Qg + (size_t)(bS + s0 + r) * D_MODEL + nOff + g * 16;
            const float* gV = Vg + (size_t)(bS + s0 + r) * D_MODEL + nOff + g * 16;
            float kf[16], qf[16];
            ushort khv[16], klv[16];
#pragma unroll
            for (int j4 = 0; j4 < 4; ++j4) {
                float4 kv = ((const float4*)gK)[j4];
                float4 qv = ((const float4*)gQ)[j4];
                float4 vv = ((const float4*)gV)[j4];
                kf[j4 * 4 + 0] = kv.x; kf[j4 * 4 + 1] = kv.y;
                kf[j4 * 4 + 2] = kv.z; kf[j4 * 4 + 3] = kv.w;
                qf[j4 * 4 + 0] = qv.x; qf[j4 * 4 + 1] = qv.y;
                qf[j4 * 4 + 2] = qv.z; qf[j4 * 4 + 3] = qv.w;
                *(float4*)&V32[r * 68 + g * 16 + j4 * 4] = vv;
            }
            ushort8 kh8[2], kl8[2], qh8[2], ql8[2];
#pragma unroll
            for (int e = 0; e < 16; ++e) {
                ushort h = f2bf(kf[e]);
                ushort l = f2bf(kf[e] - bf2f(h));
                khv[e] = h; klv[e] = l;
                kh8[e >> 3][e & 7] = h; kl8[e >> 3][e & 7] = l;
                h = f2bf(qf[e]); l = f2bf(qf[e] - bf2f(h));
                qh8[e >> 3][e & 7] = h; ql8[e >> 3][e & 7] = l;
            }
            const int o0 = fidx(r, g * 16), o1 = fidx(r, g * 16 + 8);
            *(ushort8*)&Kh_[o0] = kh8[0]; *(ushort8*)&Kh_[o1] = kh8[1];
            *(ushort8*)&Kl_[o0] = kl8[0]; *(ushort8*)&Kl_[o1] = kl8[1];
            *(ushort8*)&Qh_[o0] = qh8[0]; *(ushort8*)&Qh_[o1] = qh8[1];
            *(ushort8*)&Ql_[o0] = ql8[0]; *(ushort8*)&Ql_[o1] = ql8[1];
#pragma unroll
            for (int e = 0; e < 16; ++e) {
                const int ib = fidx(g * 16 + e, r);
                KTh_[ib] = khv[e]; KTl_[ib] = klv[e];
            }
            if (t < 64) bv[t] = Btg[(size_t)(bS + s0 + t) * NHEAD + n];
        }
        __syncthreads();   // B1

        f32x4 yacc[4];
        {
            // ---- P_R: V0 = V - K*M0^T -> V0sp ----
            f32x4 acc[4];
#pragma unroll
            for (int j = 0; j < 4; ++j) acc[j] = (f32x4){0.f, 0.f, 0.f, 0.f};
            prod_band(Kh_, Kl_, Mh_, Ml_, acc);
#pragma unroll
            for (int j = 0; j < 4; ++j)
#pragma unroll
                for (int rg = 0; rg < 4; ++rg) {
                    const int row = wave * 16 + kg * 4 + rg, col = j * 16 + m16;
                    float v0 = V32[row * 68 + col] - acc[j][rg];
                    ushort h = f2bf(v0);
                    const int ii = fidx(row, col);
                    V0h_[ii] = h; V0l_[ii] = f2bf(v0 - bf2f(h));
                }
            // ---- P_YM: yacc = Q*M0 (via MT) ----
#pragma unroll
            for (int j = 0; j < 4; ++j) yacc[j] = (f32x4){0.f, 0.f, 0.f, 0.f};
            prod_band(Qh_, Ql_, MTh_, MTl_, yacc);
            // ---- P_A: A = K K^T -> Asp ----
#pragma unroll
            for (int j = 0; j < 4; ++j) acc[j] = (f32x4){0.f, 0.f, 0.f, 0.f};
            prod_band(Kh_, Kl_, Kh_, Kl_, acc);
#pragma unroll
            for (int j = 0; j < 4; ++j)
#pragma unroll
                for (int rg = 0; rg < 4; ++rg) {
                    const int row = wave * 16 + kg * 4 + rg, col = j * 16 + m16;
                    float av = acc[j][rg];
                    ushort h = f2bf(av);
                    const int ii = fidx(row, col);
                    Ah_[ii] = h; Al_[ii] = f2bf(av - bf2f(h));
                }
            // ---- P_QK: G = tril_(Q K^T) -> Gsp ----
#pragma unroll
            for (int j = 0; j < 4; ++j) acc[j] = (f32x4){0.f, 0.f, 0.f, 0.f};
            prod_band(Qh_, Ql_, Kh_, Kl_, acc);
#pragma unroll
            for (int j = 0; j < 4; ++j)
#pragma unroll
                for (int rg = 0; rg < 4; ++rg) {
                    const int row = wave * 16 + kg * 4 + rg, col = j * 16 + m16;
                    float gv = (row > col) ? acc[j][rg] : 0.f;
                    ushort h = f2bf(gv);
                    const int ii = fidx(row, col);
                    Gh_[ii] = h; Gl_[ii] = f2bf(gv - bf2f(h));
                }
        }
        __syncthreads();   // B2 (V32 dead -> C032 writable; Q dead -> W writable)

        {
            // ---- P_C0: C0 = K * V0^T -> fp32 ----
            f32x4 acc[4];
#pragma unroll
            for (int j = 0; j < 4; ++j) acc[j] = (f32x4){0.f, 0.f, 0.f, 0.f};
            prod_band(Kh_, Kl_, V0h_, V0l_, acc);
#pragma unroll
            for (int j = 0; j < 4; ++j)
#pragma unroll
                for (int rg = 0; rg < 4; ++rg) {
                    const int row = wave * 16 + kg * 4 + rg, col = j * 16 + m16;
                    C032[row * 68 + col] = acc[j][rg];
                }
            // zero W region (Wh_,Wl_ adjacent): 2*FBUF bytes
            for (int i = t; i < 2 * FBUF / 16; i += 256)
                ((uint4v*)Wh_)[i] = (uint4v){0u, 0u, 0u, 0u};
        }
        __syncthreads();   // B3

        // ---- blocked solve: 4 column-blocks of 16 ----
#pragma unroll
        for (int J = 0; J < 4; ++J) {
            if (J > 0) {
                f32x4 acc1 = (f32x4){0.f, 0.f, 0.f, 0.f};
                const int lo8 = lane * 8;
#pragma unroll
                for (int half = 0; half < 2; ++half) {
                    bf16x8 ah = *(const bf16x8*)&Ah_[(wave * 2 + half) * SUBST + lo8];
                    bf16x8 al = *(const bf16x8*)&Al_[(wave * 2 + half) * SUBST + lo8];
                    bf16x8 bh = *(const bf16x8*)&Wh_[(J * 2 + half) * SUBST + lo8];
                    bf16x8 bl = *(const bf16x8*)&Wl_[(J * 2 + half) * SUBST + lo8];
                    acc1 = __builtin_amdgcn_mfma_f32_16x16x32_bf16(al, bh, acc1, 0, 0, 0);
                    acc1 = __builtin_amdgcn_mfma_f32_16x16x32_bf16(ah, bl, acc1, 0, 0, 0);
                    acc1 = __builtin_amdgcn_mfma_f32_16x16x32_bf16(ah, bh, acc1, 0, 0, 0);
                }
#pragma unroll
                for (int rg = 0; rg < 4; ++rg)
                    N32[(wave * 16 + kg * 4 + rg) * 17 + m16] = acc1[rg];
                __syncthreads();   // B4a
            }

            float Areg[16], CNreg[16];
            {
                bf16x8 a0 = *(const bf16x8*)&Ah_[fidx(lane, 16 * J)];
                bf16x8 a1 = *(const bf16x8*)&Ah_[fidx(lane, 16 * J + 8)];
                bf16x8 b0 = *(const bf16x8*)&Al_[fidx(lane, 16 * J)];
                bf16x8 b1 = *(const bf16x8*)&Al_[fidx(lane, 16 * J + 8)];
#pragma unroll
                for (int e = 0; e < 8; ++e) {
                    Areg[e]     = bf2f((ushort)a0[e]) + bf2f((ushort)b0[e]);
                    Areg[e + 8] = bf2f((ushort)a1[e]) + bf2f((ushort)b1[e]);
                }
#pragma unroll
                for (int j = 0; j < 16; ++j) CNreg[j] = C032[lane * 68 + 16 * J + j];
                if (J > 0) {
#pragma unroll
                    for (int j = 0; j < 16; ++j) CNreg[j] += N32[lane * 17 + j];
                }
            }
            float bvreg = bv[16 * J + m16];

            float wreg[16];
#pragma unroll
            for (int j = 0; j < 16; ++j) {
                float sum = CNreg[j];
#pragma unroll
                for (int jj = 0; jj < 16; ++jj) {
                    if (jj < j)
                        sum += Areg[jj] * lane_bcast(wreg[jj], 16 * J + j);
                }
                float beta_s = lane_bcast(bvreg, j);
                wreg[j] = (lane > 16 * J + j) ? (-beta_s * sum) : 0.f;
            }

            if (wave == 0) {
                ushort8 h8[2], l8[2];
#pragma unroll
                for (int e = 0; e < 16; ++e) {
                    ushort h = f2bf(wreg[e]);
                    h8[e >> 3][e & 7] = h;
                    l8[e >> 3][e & 7] = f2bf(wreg[e] - bf2f(h));
                }
                const int o0 = fidx(lane, 16 * J), o1 = fidx(lane, 16 * J + 8);
                *(ushort8*)&Wh_[o0] = h8[0]; *(ushort8*)&Wh_[o1] = h8[1];
                *(ushort8*)&Wl_[o0] = l8[0]; *(ushort8*)&Wl_[o1] = l8[1];
            }
            __syncthreads();   // B4b
        }

        {
            // ---- P_Delta: Delta = V0 + W * K ; write DT = (beta Delta)^T ----
            f32x4 acc[4];
#pragma unroll
            for (int j = 0; j < 4; ++j)
#pragma unroll
                for (int rg = 0; rg < 4; ++rg) {
                    const int row = wave * 16 + kg * 4 + rg, col = j * 16 + m16;
                    const int ii = fidx(row, col);
                    acc[j][rg] = bf2f(V0h_[ii]) + bf2f(V0l_[ii]);
                }
            prod_band(Wh_, Wl_, KTh_, KTl_, acc);
#pragma unroll
            for (int j = 0; j < 4; ++j)
#pragma unroll
                for (int rg = 0; rg < 4; ++rg) {
                    const int row = wave * 16 + kg * 4 + rg, col = j * 16 + m16;
                    float dv = acc[j][rg] * bv[row];     // beta_s * delta_s[d]
                    ushort h = f2bf(dv);
                    const int ii = fidx(col, row);       // DT[d][s]
                    DTh_[ii] = h; DTl_[ii] = f2bf(dv - bf2f(h));
                }
        }
        __syncthreads();   // B5 (DT ready)

        {
            // ---- P_Y2: Y = yacc + G * DT^T -> global ----
            prod_band(Gh_, Gl_, DTh_, DTl_, yacc);
#pragma unroll
            for (int j = 0; j < 4; ++j)
#pragma unroll
                for (int rg = 0; rg < 4; ++rg) {
                    const int row = wave * 16 + kg * 4 + rg, col = j * 16 + m16;
                    Yg[(size_t)(bS + s0 + row) * D_MODEL + nOff + col] = yacc[j][rg];
                }
            // ---- P_M: M += K^T * DT^T ----
            f32x4 acc[4];
#pragma unroll
            for (int j = 0; j < 4; ++j)
#pragma unroll
                for (int rg = 0; rg < 4; ++rg) {
                    const int row = wave * 16 + kg * 4 + rg, col = j * 16 + m16;
                    const int ii = fidx(row, col);
                    acc[j][rg] = bf2f(Mh_[ii]) + bf2f(Ml_[ii]);
                }
            prod_band(KTh_, KTl_, DTh_, DTl_, acc);
#pragma unroll
            for (int j = 0; j < 4; ++j)
#pragma unroll
                for (int rg = 0; rg < 4; ++rg) {
                    const int row = wave * 16 + kg * 4 + rg, col = j * 16 + m16;
                    float mv = acc[j][rg];
                    ushort h = f2bf(mv);
                    const int ii = fidx(row, col);
                    Mh_[ii] = h; Ml_[ii] = f2bf(mv - bf2f(h));
                }
            // ---- P_MT: MT += DT * K ----
#pragma unroll
            for (int j = 0; j < 4; ++j)
#pragma unroll
                for (int rg = 0; rg < 4; ++rg) {
                    const int row = wave * 16 + kg * 4 + rg, col = j * 16 + m16;
                    const int ii = fidx(row, col);
                    acc[j][rg] = bf2f(MTh_[ii]) + bf2f(MTl_[ii]);
                }
            prod_band(DTh_, DTl_, KTh_, KTl_, acc);
#pragma unroll
            for (int j = 0; j < 4; ++j)
#pragma unroll
                for (int rg = 0; rg < 4; ++rg) {
                    const int row = wave * 16 + kg * 4 + rg, col = j * 16 + m16;
                    float mv = acc[j][rg];
                    ushort h = f2bf(mv);
                    const int ii = fidx(row, col);
                    MTh_[ii] = h; MTl_[ii] = f2bf(mv - bf2f(h));
                }
        }
        __syncthreads();   // B6
    }
}

// ---------------------------------------------------------------------------
// RMSNorm. SPLIT=1: write (hi,lo) bf16 for final GEMM. SPLIT=0: fp32 in place.
// ---------------------------------------------------------------------------
template <int SPLIT>
__global__ __launch_bounds__(256) void rmsnorm_kernel(float* __restrict__ Y,
                                                      const float* __restrict__ w,
                                                      unsigned short* __restrict__ H,
                                                      unsigned short* __restrict__ L) {
    __shared__ float red[4];
    float* y = Y + (size_t)blockIdx.x * D_MODEL;
    const int t = threadIdx.x;
    const int wv = t >> 6, ln = t & 63;
    float4 v = ((float4*)y)[t];
    float ss = v.x * v.x + v.y * v.y + v.z * v.z + v.w * v.w;
#pragma unroll
    for (int off = 32; off; off >>= 1) ss += __shfl_xor(ss, off);
    if (ln == 0) red[wv] = ss;
    __syncthreads();
    float tot = red[0] + red[1] + red[2] + red[3];
    float inv = 1.f / sqrtf(tot * (1.f / D_MODEL) + 1e-6f);
    const float4 wv4 = ((const float4*)w)[t];
    v.x *= inv * wv4.x; v.y *= inv * wv4.y;
    v.z *= inv * wv4.z; v.w *= inv * wv4.w;
    if (SPLIT) {
        us4 h, l;
        h.x = f2bf(v.x); l.x = f2bf(v.x - bf2f(h.x));
        h.y = f2bf(v.y); l.y = f2bf(v.y - bf2f(h.y));
        h.z = f2bf(v.z); l.z = f2bf(v.z - bf2f(h.z));
        h.w = f2bf(v.w); l.w = f2bf(v.w - bf2f(h.w));
        size_t i = (size_t)blockIdx.x * 256 + t;
        ((us4*)H)[i] = h;
        ((us4*)L)[i] = l;
    } else {
        ((float4*)y)[t] = v;
    }
}

// ---------------------------------------------------------------------------
extern "C" void kernel_launch(void* const* d_in, const int* in_sizes, int n_in,
                              void* d_out, int out_size, void* d_ws, size_t ws_size,
                              hipStream_t stream) {
    const float* x     = (const float*)d_in[0];
    const float* Wq    = (const float*)d_in[1];
    const float* Wk    = (const float*)d_in[2];
    const float* Wv    = (const float*)d_in[3];
    const float* Wb    = (const float*)d_in[4];
    const float* Wo    = (const float*)d_in[5];
    const float* rms_w = (const float*)d_in[6];
    float* out = (float*)d_out;

    char* p = (char*)d_ws;
    float* Q  = (float*)p;  p += (size_t)RD * 4;
    float* Kp = (float*)p;  p += (size_t)RD * 4;
    float* Vp = (float*)p;  p += (size_t)RD * 4;
    float* Y  = (float*)p;  p += (size_t)RD * 4;
    float* Bt = (float*)p;  p += (size_t)32768 * 4;
    unsigned short* xh  = (unsigned short*)p;  p += (size_t)RD * 2;   // reused as Yh
    unsigned short* xl  = (unsigned short*)p;  p += (size_t)RD * 2;   // reused as Yl
    unsigned short* Wsh = (unsigned short*)p;  p += (size_t)WSZ * 2;
    unsigned short* Wsl = (unsigned short*)p;  p += (size_t)WSZ * 2;
    const size_t need_fast = (size_t)RD * 16 + 131072 + (size_t)RD * 4 + (size_t)WSZ * 4;
    const bool fast = ws_size >= need_fast;

    // Wk/Wv splits parked in Y (dead until scan writes it): 4*WSZ ushorts = RD*4 B
    unsigned short* Wkh = (unsigned short*)Y;
    unsigned short* Wkl = Wkh + WSZ;
    unsigned short* Wvh = Wkl + WSZ;
    unsigned short* Wvl = Wvh + WSZ;

    (void)hipFuncSetAttribute(reinterpret_cast<const void*>(scan_chunked),
                              hipFuncAttributeMaxDynamicSharedMemorySize, SMEM_SCAN);

    if (fast) {
        dim3 ggrid(D_MODEL / 64, ROWS / 128);       // (16,16) = 256 blocks
        dim3 qgrid(D_MODEL / 64, ROWS / 128, 3);    // 768 blocks = 3/CU
        split_kernel<<<RD / 4 / 256, 256, 0, stream>>>(x, xh, xl, RD / 4);
        split3_kernel<<<3 * WSZ / 4 / 256, 256, 0, stream>>>(Wq, Wk, Wv,
                                                             Wsh, Wsl, Wkh, Wkl, Wvh, Wvl);
        gemm_qkv<<<qgrid, 256, 0, stream>>>(xh, xl, Wsh, Wsl, Wkh, Wkl, Wvh, Wvl,
                                            Q, Kp, Vp);
        beta_kernel<<<ROWS / 4, 256, 0, stream>>>(x, Wb, Bt);
        norm_qk<<<2 * ROWS * NHEAD / 4, 256, 0, stream>>>(Q, Kp);
        scan_chunked<<<BATCH * NHEAD, 256, SMEM_SCAN, stream>>>(Q, Kp, Vp, Bt, Y);
        rmsnorm_kernel<1><<<ROWS, 256, 0, stream>>>(Y, rms_w, xh, xl);
        split_kernel<<<WSZ / 4 / 256, 256, 0, stream>>>(Wo, Wsh, Wsl, WSZ / 4);
        gemm_bf16s<0><<<ggrid, 256, 0, stream>>>(xh, xl, Wsh, Wsl, out, ROWS, D_MODEL, D_MODEL);
    } else {
        dim3 ggrid(D_MODEL / 128, ROWS / 128);  // (8,16)
        gemm_mfma<1><<<ggrid, 256, 0, stream>>>(x, Wq, Q, ROWS, D_MODEL, D_MODEL);
        gemm_mfma<1><<<ggrid, 256, 0, stream>>>(x, Wk, Kp, ROWS, D_MODEL, D_MODEL);
        gemm_mfma<1><<<ggrid, 256, 0, stream>>>(x, Wv, Vp, ROWS, D_MODEL, D_MODEL);
        beta_kernel<<<ROWS / 4, 256, 0, stream>>>(x, Wb, Bt);
        norm_qk<<<2 * ROWS * NHEAD / 4, 256, 0, stream>>>(Q, Kp);
        scan_chunked<<<BATCH * NHEAD, 256, SMEM_SCAN, stream>>>(Q, Kp, Vp, Bt, Y);
        rmsnorm_kernel<0><<<ROWS, 256, 0, stream>>>(Y, rms_w, nullptr, nullptr);
        gemm_mfma<0><<<ggrid, 256, 0, stream>>>(Y, Wo, out, ROWS, D_MODEL, D_MODEL);
    }
}

// Round 8
// 479.642 us; speedup vs baseline: 2.2483x; 1.0537x over previous
//
#include <hip/hip_runtime.h>
#include <math.h>

#define D_MODEL 1024
#define NHEAD 16
#define HEAD_DIM 64
#define BATCH 2
#define SEQ 1024
#define ROWS (BATCH * SEQ)        // 2048
#define RD (ROWS * D_MODEL)       // 2097152
#define WSZ (D_MODEL * D_MODEL)   // 1048576
#define CHUNK 64
#define NCHUNK (SEQ / CHUNK)      // 16

typedef __attribute__((ext_vector_type(8))) short bf16x8;
typedef __attribute__((ext_vector_type(8))) unsigned short ushort8;
typedef __attribute__((ext_vector_type(4))) unsigned short us4;
typedef __attribute__((ext_vector_type(4))) float f32x4;
typedef __attribute__((ext_vector_type(4))) unsigned int uint4v;
typedef unsigned short ushort;

// ---------------------------------------------------------------------------
// helpers
// ---------------------------------------------------------------------------
__device__ __forceinline__ void load_lds_16u(const unsigned short* g, unsigned short* l) {
    __builtin_amdgcn_global_load_lds((const __attribute__((address_space(1))) void*)g,
                                     (__attribute__((address_space(3))) void*)l, 16, 0, 0);
}
// fp32 -> bf16 RNE, and back
__device__ __forceinline__ unsigned short f2bf(float x) {
    unsigned int u = __float_as_uint(x);
    unsigned int r = (u + 0x7FFFu + ((u >> 16) & 1u)) >> 16;
    return (unsigned short)r;
}
__device__ __forceinline__ float bf2f(unsigned short h) {
    return __uint_as_float(((unsigned int)h) << 16);
}
// uniform-lane broadcast (SALU path, not LDS)
__device__ __forceinline__ float lane_bcast(float v, int lane) {
    return __uint_as_float(__builtin_amdgcn_readlane(__float_as_uint(v), lane));
}
// fragment-order index (SUBST=512: R6-validated; 520 padding REGRESSED 24% - reverted)
#define SUBST 512
#define FBUF (8 * SUBST * 2)   // 8192 bytes per 64x64 operand buffer
__device__ __forceinline__ int fidx(int r, int k) {
    return ((r >> 4) * 2 + (k >> 5)) * SUBST + ((((k & 31) >> 3) << 4) + (r & 15)) * 8 + (k & 7);
}

// ---------------------------------------------------------------------------
// split: fp32 -> (hi, lo) bf16 buffers. n4 = n/4 float4 groups.
// ---------------------------------------------------------------------------
__global__ __launch_bounds__(256) void split_kernel(const float* __restrict__ X,
                                                    unsigned short* __restrict__ H,
                                                    unsigned short* __restrict__ L,
                                                    int n4) {
    int i = blockIdx.x * 256 + threadIdx.x;
    if (i >= n4) return;
    float4 v = ((const float4*)X)[i];
    us4 h, l;
    h.x = f2bf(v.x); l.x = f2bf(v.x - bf2f(h.x));
    h.y = f2bf(v.y); l.y = f2bf(v.y - bf2f(h.y));
    h.z = f2bf(v.z); l.z = f2bf(v.z - bf2f(h.z));
    h.w = f2bf(v.w); l.w = f2bf(v.w - bf2f(h.w));
    ((us4*)H)[i] = h;
    ((us4*)L)[i] = l;
}

// fused 3-way weight split (one launch for Wq, Wk, Wv)
__global__ __launch_bounds__(256) void split3_kernel(const float* __restrict__ W0,
                                                     const float* __restrict__ W1,
                                                     const float* __restrict__ W2,
                                                     unsigned short* __restrict__ H0,
                                                     unsigned short* __restrict__ L0,
                                                     unsigned short* __restrict__ H1,
                                                     unsigned short* __restrict__ L1,
                                                     unsigned short* __restrict__ H2,
                                                     unsigned short* __restrict__ L2) {
    const int n4 = WSZ / 4;
    int i = blockIdx.x * 256 + threadIdx.x;
    const int which = i / n4;
    const int j = i - which * n4;
    const float* X = (which == 0) ? W0 : (which == 1) ? W1 : W2;
    unsigned short* H = (which == 0) ? H0 : (which == 1) ? H1 : H2;
    unsigned short* L = (which == 0) ? L0 : (which == 1) ? L1 : L2;
    float4 v = ((const float4*)X)[j];
    us4 h, l;
    h.x = f2bf(v.x); l.x = f2bf(v.x - bf2f(h.x));
    h.y = f2bf(v.y); l.y = f2bf(v.y - bf2f(h.y));
    h.z = f2bf(v.z); l.z = f2bf(v.z - bf2f(h.z));
    h.w = f2bf(v.w); l.w = f2bf(v.w - bf2f(h.w));
    ((us4*)H)[j] = h;
    ((us4*)L)[j] = l;
}

// ---------------------------------------------------------------------------
// GEMM core on pre-split inputs (R4-validated structure).
// ---------------------------------------------------------------------------
template <int ACT>
__device__ __forceinline__ void gemm_core(const unsigned short* __restrict__ Ah,
                                          const unsigned short* __restrict__ Al,
                                          const unsigned short* __restrict__ Bh,
                                          const unsigned short* __restrict__ Bl,
                                          float* __restrict__ C,
                                          int M, int N, int K,
                                          unsigned short* LA0, unsigned short* LA1,
                                          unsigned short* LB0, unsigned short* LB1) {
    const int t = threadIdx.x;
    const int wave = t >> 6, lane = t & 63;
    const int wm = wave >> 1, wn = wave & 1;
    const int m16 = lane & 15, kg = lane >> 4;
    const int row0 = blockIdx.y * 128, col0 = blockIdx.x * 64;

    f32x4 acc[4][2];
#pragma unroll
    for (int i = 0; i < 4; ++i)
#pragma unroll
        for (int j = 0; j < 2; ++j) acc[i][j] = (f32x4){0.f, 0.f, 0.f, 0.f};

    for (int k0 = 0; k0 < K; k0 += 32) {
#pragma unroll
        for (int ci = 0; ci < 6; ++ci) {
            const int c = wave * 6 + ci;
            const unsigned short* src;
            unsigned short* dst;
            int g16, rbase;
            if (c < 8)       { src = Ah; dst = &LA0[c * 512];        g16 = c;      rbase = row0; }
            else if (c < 16) { src = Al; dst = &LA1[(c - 8) * 512];  g16 = c - 8;  rbase = row0; }
            else if (c < 20) { src = Bh; dst = &LB0[(c - 16) * 512]; g16 = c - 16; rbase = col0; }
            else             { src = Bl; dst = &LB1[(c - 20) * 512]; g16 = c - 20; rbase = col0; }
            const unsigned short* gp = src + (size_t)(rbase + g16 * 16 + m16) * K + k0 + kg * 8;
            load_lds_16u(gp, dst);
        }
        __syncthreads();

        bf16x8 fah[4], fal[4], fbh[2], fbl[2];
#pragma unroll
        for (int mt = 0; mt < 4; ++mt) {
            const int off = (wm * 4 + mt) * 512 + lane * 8;
            fah[mt] = *(const bf16x8*)&LA0[off];
            fal[mt] = *(const bf16x8*)&LA1[off];
        }
#pragma unroll
        for (int nt = 0; nt < 2; ++nt) {
            const int off = (wn * 2 + nt) * 512 + lane * 8;
            fbh[nt] = *(const bf16x8*)&LB0[off];
            fbl[nt] = *(const bf16x8*)&LB1[off];
        }
#pragma unroll
        for (int mt = 0; mt < 4; ++mt)
#pragma unroll
            for (int nt = 0; nt < 2; ++nt) {
                acc[mt][nt] = __builtin_amdgcn_mfma_f32_16x16x32_bf16(fal[mt], fbh[nt], acc[mt][nt], 0, 0, 0);
                acc[mt][nt] = __builtin_amdgcn_mfma_f32_16x16x32_bf16(fah[mt], fbl[nt], acc[mt][nt], 0, 0, 0);
                acc[mt][nt] = __builtin_amdgcn_mfma_f32_16x16x32_bf16(fah[mt], fbh[nt], acc[mt][nt], 0, 0, 0);
            }
        __syncthreads();
    }

#pragma unroll
    for (int mt = 0; mt < 4; ++mt)
#pragma unroll
        for (int nt = 0; nt < 2; ++nt) {
            const int rowb = row0 + wm * 64 + mt * 16 + kg * 4;
            const int col  = col0 + wn * 32 + nt * 16 + m16;
#pragma unroll
            for (int rg = 0; rg < 4; ++rg) {
                float v = acc[mt][nt][rg];
                if (ACT == 1) v = v / (1.f + expf(-v));
                C[(size_t)(rowb + rg) * N + col] = v;
            }
        }
}

template <int ACT>
__global__ __launch_bounds__(256) void gemm_bf16s(const unsigned short* __restrict__ Ah,
                                                  const unsigned short* __restrict__ Al,
                                                  const unsigned short* __restrict__ Bh,
                                                  const unsigned short* __restrict__ Bl,
                                                  float* __restrict__ C,
                                                  int M, int N, int K) {
    __shared__ unsigned short LA[2][8 * 512];
    __shared__ unsigned short LB[2][4 * 512];
    gemm_core<ACT>(Ah, Al, Bh, Bl, C, M, N, K, LA[0], LA[1], LB[0], LB[1]);
}

// fused QKV GEMM: blockIdx.z selects weight/output; 768 blocks = 3/CU
__global__ __launch_bounds__(256) void gemm_qkv(const unsigned short* __restrict__ Ah,
                                                const unsigned short* __restrict__ Al,
                                                const unsigned short* __restrict__ Bqh,
                                                const unsigned short* __restrict__ Bql,
                                                const unsigned short* __restrict__ Bkh,
                                                const unsigned short* __restrict__ Bkl,
                                                const unsigned short* __restrict__ Bvh,
                                                const unsigned short* __restrict__ Bvl,
                                                float* __restrict__ Cq,
                                                float* __restrict__ Ck,
                                                float* __restrict__ Cv) {
    __shared__ unsigned short LA[2][8 * 512];
    __shared__ unsigned short LB[2][4 * 512];
    const int z = blockIdx.z;
    const unsigned short* Bh = (z == 0) ? Bqh : (z == 1) ? Bkh : Bvh;
    const unsigned short* Bl = (z == 0) ? Bql : (z == 1) ? Bkl : Bvl;
    float* C = (z == 0) ? Cq : (z == 1) ? Ck : Cv;
    gemm_core<1>(Ah, Al, Bh, Bl, C, ROWS, D_MODEL, D_MODEL, LA[0], LA[1], LB[0], LB[1]);
}

// ---------------------------------------------------------------------------
// Fallback GEMM (inline split) — only if ws_size too small.
// ---------------------------------------------------------------------------
#define LDST 40
template <int ACT>
__global__ __launch_bounds__(256) void gemm_mfma(const float* __restrict__ A,
                                                 const float* __restrict__ B,
                                                 float* __restrict__ C,
                                                 int M, int N, int K) {
    __shared__ unsigned short Ahi[128 * LDST], Alo[128 * LDST];
    __shared__ unsigned short Bhi[128 * LDST], Blo[128 * LDST];

    const int t = threadIdx.x;
    const int wave = t >> 6, lane = t & 63;
    const int wm = wave >> 1, wn = wave & 1;
    const int row0 = blockIdx.y * 128, col0 = blockIdx.x * 128;
    const int sr = t >> 1;
    const int sh = t & 1;
    const int m16 = lane & 15, kg = lane >> 4;

    f32x4 acc[4][4];
#pragma unroll
    for (int i = 0; i < 4; ++i)
#pragma unroll
        for (int j = 0; j < 4; ++j) acc[i][j] = (f32x4){0.f, 0.f, 0.f, 0.f};

    const float* ga = A + (size_t)(row0 + sr) * K + sh * 16;
    const float* gb = B + (size_t)(col0 + sr) * K + sh * 16;
    const int sbase = sr * LDST + sh * 16;

    for (int k0 = 0; k0 < K; k0 += 32) {
        float af[16], bf[16];
#pragma unroll
        for (int i = 0; i < 4; ++i) {
            float4 a4 = *(const float4*)(ga + k0 + i * 4);
            float4 b4 = *(const float4*)(gb + k0 + i * 4);
            af[i * 4 + 0] = a4.x; af[i * 4 + 1] = a4.y; af[i * 4 + 2] = a4.z; af[i * 4 + 3] = a4.w;
            bf[i * 4 + 0] = b4.x; bf[i * 4 + 1] = b4.y; bf[i * 4 + 2] = b4.z; bf[i * 4 + 3] = b4.w;
        }
        ushort8 ah0, ah1, al0, al1, bh0, bh1, bl0, bl1;
#pragma unroll
        for (int j = 0; j < 8; ++j) {
            unsigned short h = f2bf(af[j]);       ah0[j] = h; al0[j] = f2bf(af[j] - bf2f(h));
            h = f2bf(af[j + 8]);                  ah1[j] = h; al1[j] = f2bf(af[j + 8] - bf2f(h));
            h = f2bf(bf[j]);                      bh0[j] = h; bl0[j] = f2bf(bf[j] - bf2f(h));
            h = f2bf(bf[j + 8]);                  bh1[j] = h; bl1[j] = f2bf(bf[j + 8] - bf2f(h));
        }
        *(ushort8*)&Ahi[sbase] = ah0;  *(ushort8*)&Ahi[sbase + 8] = ah1;
        *(ushort8*)&Alo[sbase] = al0;  *(ushort8*)&Alo[sbase + 8] = al1;
        *(ushort8*)&Bhi[sbase] = bh0;  *(ushort8*)&Bhi[sbase + 8] = bh1;
        *(ushort8*)&Blo[sbase] = bl0;  *(ushort8*)&Blo[sbase + 8] = bl1;
        __syncthreads();

        bf16x8 fah[4], fal[4], fbh[4], fbl[4];
#pragma unroll
        for (int i = 0; i < 4; ++i) {
            const int ar = (wm * 64 + i * 16 + m16) * LDST + kg * 8;
            const int br = (wn * 64 + i * 16 + m16) * LDST + kg * 8;
            fah[i] = *(const bf16x8*)&Ahi[ar];
            fal[i] = *(const bf16x8*)&Alo[ar];
            fbh[i] = *(const bf16x8*)&Bhi[br];
            fbl[i] = *(const bf16x8*)&Blo[br];
        }
#pragma unroll
        for (int i = 0; i < 4; ++i)
#pragma unroll
            for (int j = 0; j < 4; ++j) {
                acc[i][j] = __builtin_amdgcn_mfma_f32_16x16x32_bf16(fal[i], fbh[j], acc[i][j], 0, 0, 0);
                acc[i][j] = __builtin_amdgcn_mfma_f32_16x16x32_bf16(fah[i], fbl[j], acc[i][j], 0, 0, 0);
                acc[i][j] = __builtin_amdgcn_mfma_f32_16x16x32_bf16(fah[i], fbh[j], acc[i][j], 0, 0, 0);
            }
        __syncthreads();
    }

#pragma unroll
    for (int i = 0; i < 4; ++i)
#pragma unroll
        for (int j = 0; j < 4; ++j) {
            const int col = col0 + wn * 64 + j * 16 + m16;
            const int rowb = row0 + wm * 64 + i * 16 + kg * 4;
#pragma unroll
            for (int rg = 0; rg < 4; ++rg) {
                float v = acc[i][j][rg];
                if (ACT == 1) v = v / (1.f + expf(-v));
                C[(size_t)(rowb + rg) * N + col] = v;
            }
        }
}

// ---------------------------------------------------------------------------
// beta = 2*sigmoid(x @ Wb^T)  : (ROWS, NHEAD). One wave per row.
// ---------------------------------------------------------------------------
__global__ __launch_bounds__(256) void beta_kernel(const float* __restrict__ x,
                                                   const float* __restrict__ Wb,
                                                   float* __restrict__ beta) {
    const int wave = blockIdx.x * 4 + (threadIdx.x >> 6);
    const int lane = threadIdx.x & 63;
    const float* xr = x + (size_t)wave * D_MODEL;
    float xv[16];
#pragma unroll
    for (int j = 0; j < 16; ++j) xv[j] = xr[lane + 64 * j];
    for (int n = 0; n < NHEAD; ++n) {
        const float* wr = Wb + (size_t)n * D_MODEL;
        float s = 0.f;
#pragma unroll
        for (int j = 0; j < 16; ++j) s += xv[j] * wr[lane + 64 * j];
#pragma unroll
        for (int off = 32; off; off >>= 1) s += __shfl_xor(s, off);
        if (lane == 0) beta[(size_t)wave * NHEAD + n] = 2.f / (1.f + expf(-s));
    }
}

// ---------------------------------------------------------------------------
// L2-normalize q and k per (row, head) over HEAD_DIM=64.
// ---------------------------------------------------------------------------
__global__ __launch_bounds__(256) void norm_qk(float* __restrict__ Q,
                                               float* __restrict__ Kp) {
    const int TOT = ROWS * NHEAD;
    int wave = blockIdx.x * 4 + (threadIdx.x >> 6);
    const int lane = threadIdx.x & 63;
    float* T = (wave < TOT) ? Q : Kp;
    int w = (wave < TOT) ? wave : wave - TOT;
    float* p = T + (size_t)(w >> 4) * D_MODEL + (size_t)(w & 15) * HEAD_DIM;
    float v = p[lane];
    float ss = v * v;
#pragma unroll
    for (int off = 32; off; off >>= 1) ss += __shfl_xor(ss, off);
    p[lane] = v / (sqrtf(ss) + 1e-6f);
}

// ---------------------------------------------------------------------------
// Chunked delta-rule scan v3 (R6 math, SUBST=512): V0, M, MT live in fp32
// REGISTERS across the chunk (acc-layout positions are identical between the
// producing product and the consuming acc-init). LDS split-bf16 copies of
// M/MT/V0 are written only as MFMA operands. Chunk 0 skips the state products.
// ---------------------------------------------------------------------------
#define SMEM_SCAN 153088

__global__ __launch_bounds__(256, 1) void scan_chunked(const float* __restrict__ Qg,
                                                       const float* __restrict__ Kg,
                                                       const float* __restrict__ Vg,
                                                       const float* __restrict__ Btg,
                                                       float* __restrict__ Yg) {
    extern __shared__ char smem[];
    ushort* Mh_  = (ushort*)(smem + 0 * FBUF);
    ushort* Ml_  = (ushort*)(smem + 1 * FBUF);
    ushort* MTh_ = (ushort*)(smem + 2 * FBUF);
    ushort* MTl_ = (ushort*)(smem + 3 * FBUF);
    ushort* KTh_ = (ushort*)(smem + 4 * FBUF);
    ushort* KTl_ = (ushort*)(smem + 5 * FBUF);
    ushort* V0h_ = (ushort*)(smem + 6 * FBUF);
    ushort* V0l_ = (ushort*)(smem + 7 * FBUF);
    ushort* Gh_  = (ushort*)(smem + 8 * FBUF);
    ushort* Gl_  = (ushort*)(smem + 9 * FBUF);
    ushort* Kh_  = (ushort*)(smem + 10 * FBUF);  // union1: K / DT
    ushort* Kl_  = (ushort*)(smem + 11 * FBUF);
    ushort* DTh_ = Kh_;
    ushort* DTl_ = Kl_;
    ushort* Qh_  = (ushort*)(smem + 12 * FBUF);  // union2: Q / W (adjacent hi,lo)
    ushort* Ql_  = (ushort*)(smem + 13 * FBUF);
    ushort* Wh_  = Qh_;
    ushort* Wl_  = Ql_;
    float*  V32  = (float*)(smem + 14 * FBUF);             // 64x68 fp32 (union C032)
    float*  C032 = V32;
    ushort* Ah_  = (ushort*)(smem + 14 * FBUF + 17408);
    ushort* Al_  = (ushort*)(smem + 15 * FBUF + 17408);
    float*  N32  = (float*)(smem + 16 * FBUF + 17408);     // 64x17 fp32
    float*  bv   = (float*)(smem + 16 * FBUF + 17408 + 4352);

    const int b = blockIdx.x >> 4;
    const int n = blockIdx.x & 15;
    const int t = threadIdx.x;
    const int wave = t >> 6, lane = t & 63;
    const int m16 = lane & 15, kg = lane >> 4;
    const int bS = b * SEQ;
    const int nOff = n * HEAD_DIM;
    const int r = t >> 2, g = t & 3;   // staging: row r, col-quarter g

    // fp32 register state (acc layout: row = wave*16 + kg*4 + rg, col = j*16 + m16)
    f32x4 Macc[4], MTacc[4];
#pragma unroll
    for (int j = 0; j < 4; ++j) {
        Macc[j] = (f32x4){0.f, 0.f, 0.f, 0.f};
        MTacc[j] = (f32x4){0.f, 0.f, 0.f, 0.f};
    }

    // product: wave's 16-row band x 64 cols, K=64, split operands, D = X*Y^T
    auto prod_band = [&](const ushort* Ah, const ushort* Al,
                         const ushort* Bh, const ushort* Bl, f32x4 acc[4]) {
        const int lo8 = lane * 8;
#pragma unroll
        for (int half = 0; half < 2; ++half) {
            bf16x8 ah = *(const bf16x8*)&Ah[(wave * 2 + half) * SUBST + lo8];
            bf16x8 al = *(const bf16x8*)&Al[(wave * 2 + half) * SUBST + lo8];
#pragma unroll
            for (int j = 0; j < 4; ++j) {
                bf16x8 bh = *(const bf16x8*)&Bh[(j * 2 + half) * SUBST + lo8];
                bf16x8 bl = *(const bf16x8*)&Bl[(j * 2 + half) * SUBST + lo8];
                acc[j] = __builtin_amdgcn_mfma_f32_16x16x32_bf16(al, bh, acc[j], 0, 0, 0);
                acc[j] = __builtin_amdgcn_mfma_f32_16x16x32_bf16(ah, bl, acc[j], 0, 0, 0);
                acc[j] = __builtin_amdgcn_mfma_f32_16x16x32_bf16(ah, bh, acc[j], 0, 0, 0);
            }
        }
    };

    for (int c = 0; c < NCHUNK; ++c) {
        const int s0 = c * CHUNK;

        // ---- stage K (+transpose), Q, V, beta; K/Q via octet b128 stores ----
        {
            const float* gK = Kg + (size_t)(bS + s0 + r) * D_MODEL + nOff + g * 16;
            const float* gQ = Qg + (size_t)(bS + s0 + r) * D_MODEL + nOff + g * 16;
            const float* gV = Vg + (size_t)(bS + s0 + r) * D_MODEL + nOff + g * 16;
            float kf[16], qf[16];
            ushort khv[16], klv[16];
#pragma unroll
            for (int j4 = 0; j4 < 4; ++j4) {
                float4 kv = ((const float4*)gK)[j4];
                float4 qv = ((const float4*)gQ)[j4];
                float4 vv = ((const float4*)gV)[j4];
                kf[j4 * 4 + 0] = kv.x; kf[j4 * 4 + 1] = kv.y;
                kf[j4 * 4 + 2] = kv.z; kf[j4 * 4 + 3] = kv.w;
                qf[j4 * 4 + 0] = qv.x; qf[j4 * 4 + 1] = qv.y;
                qf[j4 * 4 + 2] = qv.z; qf[j4 * 4 + 3] = qv.w;
                *(float4*)&V32[r * 68 + g * 16 + j4 * 4] = vv;
            }
            ushort8 kh8[2], kl8[2], qh8[2], ql8[2];
#pragma unroll
            for (int e = 0; e < 16; ++e) {
                ushort h = f2bf(kf[e]);
                ushort l = f2bf(kf[e] - bf2f(h));
                khv[e] = h; klv[e] = l;
                kh8[e >> 3][e & 7] = h; kl8[e >> 3][e & 7] = l;
                h = f2bf(qf[e]); l = f2bf(qf[e] - bf2f(h));
                qh8[e >> 3][e & 7] = h; ql8[e >> 3][e & 7] = l;
            }
            const int o0 = fidx(r, g * 16), o1 = fidx(r, g * 16 + 8);
            *(ushort8*)&Kh_[o0] = kh8[0]; *(ushort8*)&Kh_[o1] = kh8[1];
            *(ushort8*)&Kl_[o0] = kl8[0]; *(ushort8*)&Kl_[o1] = kl8[1];
            *(ushort8*)&Qh_[o0] = qh8[0]; *(ushort8*)&Qh_[o1] = qh8[1];
            *(ushort8*)&Ql_[o0] = ql8[0]; *(ushort8*)&Ql_[o1] = ql8[1];
#pragma unroll
            for (int e = 0; e < 16; ++e) {
                const int ib = fidx(g * 16 + e, r);
                KTh_[ib] = khv[e]; KTl_[ib] = klv[e];
            }
            if (t < 64) bv[t] = Btg[(size_t)(bS + s0 + t) * NHEAD + n];
        }
        __syncthreads();   // B1

        f32x4 yacc[4], V0acc[4];
        {
            // ---- P_R: V0 = V - K*M0^T (register result + split-bf16 operand copy) ----
            if (c > 0) {
#pragma unroll
                for (int j = 0; j < 4; ++j) V0acc[j] = (f32x4){0.f, 0.f, 0.f, 0.f};
                prod_band(Kh_, Kl_, Mh_, Ml_, V0acc);
#pragma unroll
                for (int j = 0; j < 4; ++j)
#pragma unroll
                    for (int rg = 0; rg < 4; ++rg) {
                        const int row = wave * 16 + kg * 4 + rg, col = j * 16 + m16;
                        V0acc[j][rg] = V32[row * 68 + col] - V0acc[j][rg];
                    }
            } else {
#pragma unroll
                for (int j = 0; j < 4; ++j)
#pragma unroll
                    for (int rg = 0; rg < 4; ++rg) {
                        const int row = wave * 16 + kg * 4 + rg, col = j * 16 + m16;
                        V0acc[j][rg] = V32[row * 68 + col];
                    }
            }
#pragma unroll
            for (int j = 0; j < 4; ++j)
#pragma unroll
                for (int rg = 0; rg < 4; ++rg) {
                    const int row = wave * 16 + kg * 4 + rg, col = j * 16 + m16;
                    float v0 = V0acc[j][rg];
                    ushort h = f2bf(v0);
                    const int ii = fidx(row, col);
                    V0h_[ii] = h; V0l_[ii] = f2bf(v0 - bf2f(h));
                }
            // ---- P_YM: yacc = Q*M0 (via MT) ----
#pragma unroll
            for (int j = 0; j < 4; ++j) yacc[j] = (f32x4){0.f, 0.f, 0.f, 0.f};
            if (c > 0) prod_band(Qh_, Ql_, MTh_, MTl_, yacc);
            // ---- P_A: A = K K^T -> Asp ----
            f32x4 acc[4];
#pragma unroll
            for (int j = 0; j < 4; ++j) acc[j] = (f32x4){0.f, 0.f, 0.f, 0.f};
            prod_band(Kh_, Kl_, Kh_, Kl_, acc);
#pragma unroll
            for (int j = 0; j < 4; ++j)
#pragma unroll
                for (int rg = 0; rg < 4; ++rg) {
                    const int row = wave * 16 + kg * 4 + rg, col = j * 16 + m16;
                    float av = acc[j][rg];
                    ushort h = f2bf(av);
                    const int ii = fidx(row, col);
                    Ah_[ii] = h; Al_[ii] = f2bf(av - bf2f(h));
                }
            // ---- P_QK: G = tril_(Q K^T) -> Gsp ----
#pragma unroll
            for (int j = 0; j < 4; ++j) acc[j] = (f32x4){0.f, 0.f, 0.f, 0.f};
            prod_band(Qh_, Ql_, Kh_, Kl_, acc);
#pragma unroll
            for (int j = 0; j < 4; ++j)
#pragma unroll
                for (int rg = 0; rg < 4; ++rg) {
                    const int row = wave * 16 + kg * 4 + rg, col = j * 16 + m16;
                    float gv = (row > col) ? acc[j][rg] : 0.f;
                    ushort h = f2bf(gv);
                    const int ii = fidx(row, col);
                    Gh_[ii] = h; Gl_[ii] = f2bf(gv - bf2f(h));
                }
        }
        __syncthreads();   // B2 (V32 dead -> C032 writable; Q dead -> W writable)

        {
            // ---- P_C0: C0 = K * V0^T -> fp32 ----
            f32x4 acc[4];
#pragma unroll
            for (int j = 0; j < 4; ++j) acc[j] = (f32x4){0.f, 0.f, 0.f, 0.f};
            prod_band(Kh_, Kl_, V0h_, V0l_, acc);
#pragma unroll
            for (int j = 0; j < 4; ++j)
#pragma unroll
                for (int rg = 0; rg < 4; ++rg) {
                    const int row = wave * 16 + kg * 4 + rg, col = j * 16 + m16;
                    C032[row * 68 + col] = acc[j][rg];
                }
            // zero W region (needed every chunk: N-product reads full K incl.
            // not-yet-published columns, which must be 0, not stale)
            for (int i = t; i < 2 * FBUF / 16; i += 256)
                ((uint4v*)Wh_)[i] = (uint4v){0u, 0u, 0u, 0u};
        }
        __syncthreads();   // B3

        // ---- blocked solve: 4 column-blocks of 16 ----
#pragma unroll
        for (int J = 0; J < 4; ++J) {
            if (J > 0) {
                f32x4 acc1 = (f32x4){0.f, 0.f, 0.f, 0.f};
                const int lo8 = lane * 8;
#pragma unroll
                for (int half = 0; half < 2; ++half) {
                    bf16x8 ah = *(const bf16x8*)&Ah_[(wave * 2 + half) * SUBST + lo8];
                    bf16x8 al = *(const bf16x8*)&Al_[(wave * 2 + half) * SUBST + lo8];
                    bf16x8 bh = *(const bf16x8*)&Wh_[(J * 2 + half) * SUBST + lo8];
                    bf16x8 bl = *(const bf16x8*)&Wl_[(J * 2 + half) * SUBST + lo8];
                    acc1 = __builtin_amdgcn_mfma_f32_16x16x32_bf16(al, bh, acc1, 0, 0, 0);
                    acc1 = __builtin_amdgcn_mfma_f32_16x16x32_bf16(ah, bl, acc1, 0, 0, 0);
                    acc1 = __builtin_amdgcn_mfma_f32_16x16x32_bf16(ah, bh, acc1, 0, 0, 0);
                }
#pragma unroll
                for (int rg = 0; rg < 4; ++rg)
                    N32[(wave * 16 + kg * 4 + rg) * 17 + m16] = acc1[rg];
                __syncthreads();   // B4a
            }

            float Areg[16], CNreg[16];
            {
                bf16x8 a0 = *(const bf16x8*)&Ah_[fidx(lane, 16 * J)];
                bf16x8 a1 = *(const bf16x8*)&Ah_[fidx(lane, 16 * J + 8)];
                bf16x8 b0 = *(const bf16x8*)&Al_[fidx(lane, 16 * J)];
                bf16x8 b1 = *(const bf16x8*)&Al_[fidx(lane, 16 * J + 8)];
#pragma unroll
                for (int e = 0; e < 8; ++e) {
                    Areg[e]     = bf2f((ushort)a0[e]) + bf2f((ushort)b0[e]);
                    Areg[e + 8] = bf2f((ushort)a1[e]) + bf2f((ushort)b1[e]);
                }
#pragma unroll
                for (int j = 0; j < 16; ++j) CNreg[j] = C032[lane * 68 + 16 * J + j];
                if (J > 0) {
#pragma unroll
                    for (int j = 0; j < 16; ++j) CNreg[j] += N32[lane * 17 + j];
                }
            }
            float bvreg = bv[16 * J + m16];

            float wreg[16];
#pragma unroll
            for (int j = 0; j < 16; ++j) {
                float sum = CNreg[j];
#pragma unroll
                for (int jj = 0; jj < 16; ++jj) {
                    if (jj < j)
                        sum += Areg[jj] * lane_bcast(wreg[jj], 16 * J + j);
                }
                float beta_s = lane_bcast(bvreg, j);
                wreg[j] = (lane > 16 * J + j) ? (-beta_s * sum) : 0.f;
            }

            if (wave == 0) {
                ushort8 h8[2], l8[2];
#pragma unroll
                for (int e = 0; e < 16; ++e) {
                    ushort h = f2bf(wreg[e]);
                    h8[e >> 3][e & 7] = h;
                    l8[e >> 3][e & 7] = f2bf(wreg[e] - bf2f(h));
                }
                const int o0 = fidx(lane, 16 * J), o1 = fidx(lane, 16 * J + 8);
                *(ushort8*)&Wh_[o0] = h8[0]; *(ushort8*)&Wh_[o1] = h8[1];
                *(ushort8*)&Wl_[o0] = l8[0]; *(ushort8*)&Wl_[o1] = l8[1];
            }
            __syncthreads();   // B4b
        }

        {
            // ---- P_Delta: Delta = V0(reg) + W * K ; write DT = (beta Delta)^T ----
            f32x4 acc[4];
#pragma unroll
            for (int j = 0; j < 4; ++j) acc[j] = V0acc[j];
            prod_band(Wh_, Wl_, KTh_, KTl_, acc);
#pragma unroll
            for (int j = 0; j < 4; ++j)
#pragma unroll
                for (int rg = 0; rg < 4; ++rg) {
                    const int row = wave * 16 + kg * 4 + rg, col = j * 16 + m16;
                    float dv = acc[j][rg] * bv[row];     // beta_s * delta_s[d]
                    ushort h = f2bf(dv);
                    const int ii = fidx(col, row);       // DT[d][s]
                    DTh_[ii] = h; DTl_[ii] = f2bf(dv - bf2f(h));
                }
        }
        __syncthreads();   // B5 (DT ready)

        {
            // ---- P_Y2: Y = yacc + G * DT^T -> global ----
            prod_band(Gh_, Gl_, DTh_, DTl_, yacc);
#pragma unroll
            for (int j = 0; j < 4; ++j)
#pragma unroll
                for (int rg = 0; rg < 4; ++rg) {
                    const int row = wave * 16 + kg * 4 + rg, col = j * 16 + m16;
                    Yg[(size_t)(bS + s0 + row) * D_MODEL + nOff + col] = yacc[j][rg];
                }
            // ---- P_M: Macc += K^T * DT^T (fp32 registers); write operand copy ----
            prod_band(KTh_, KTl_, DTh_, DTl_, Macc);
            // ---- P_MT: MTacc += DT * K ----
            prod_band(DTh_, DTl_, KTh_, KTl_, MTacc);
        }
        __syncthreads();   // B6a (DT consumed; Mh_/MTh_ stale-readable no more)
        if (c < NCHUNK - 1) {
#pragma unroll
            for (int j = 0; j < 4; ++j)
#pragma unroll
                for (int rg = 0; rg < 4; ++rg) {
                    const int row = wave * 16 + kg * 4 + rg, col = j * 16 + m16;
                    const int ii = fidx(row, col);
                    float mv = Macc[j][rg];
                    ushort h = f2bf(mv);
                    Mh_[ii] = h; Ml_[ii] = f2bf(mv - bf2f(h));
                    mv = MTacc[j][rg];
                    h = f2bf(mv);
                    MTh_[ii] = h; MTl_[ii] = f2bf(mv - bf2f(h));
                }
        }
        __syncthreads();   // B6b (state operand copies ready for next chunk)
    }
}

// ---------------------------------------------------------------------------
// RMSNorm. SPLIT=1: write (hi,lo) bf16 for final GEMM. SPLIT=0: fp32 in place.
// ---------------------------------------------------------------------------
template <int SPLIT>
__global__ __launch_bounds__(256) void rmsnorm_kernel(float* __restrict__ Y,
                                                      const float* __restrict__ w,
                                                      unsigned short* __restrict__ H,
                                                      unsigned short* __restrict__ L) {
    __shared__ float red[4];
    float* y = Y + (size_t)blockIdx.x * D_MODEL;
    const int t = threadIdx.x;
    const int wv = t >> 6, ln = t & 63;
    float4 v = ((float4*)y)[t];
    float ss = v.x * v.x + v.y * v.y + v.z * v.z + v.w * v.w;
#pragma unroll
    for (int off = 32; off; off >>= 1) ss += __shfl_xor(ss, off);
    if (ln == 0) red[wv] = ss;
    __syncthreads();
    float tot = red[0] + red[1] + red[2] + red[3];
    float inv = 1.f / sqrtf(tot * (1.f / D_MODEL) + 1e-6f);
    const float4 wv4 = ((const float4*)w)[t];
    v.x *= inv * wv4.x; v.y *= inv * wv4.y;
    v.z *= inv * wv4.z; v.w *= inv * wv4.w;
    if (SPLIT) {
        us4 h, l;
        h.x = f2bf(v.x); l.x = f2bf(v.x - bf2f(h.x));
        h.y = f2bf(v.y); l.y = f2bf(v.y - bf2f(h.y));
        h.z = f2bf(v.z); l.z = f2bf(v.z - bf2f(h.z));
        h.w = f2bf(v.w); l.w = f2bf(v.w - bf2f(h.w));
        size_t i = (size_t)blockIdx.x * 256 + t;
        ((us4*)H)[i] = h;
        ((us4*)L)[i] = l;
    } else {
        ((float4*)y)[t] = v;
    }
}

// ---------------------------------------------------------------------------
extern "C" void kernel_launch(void* const* d_in, const int* in_sizes, int n_in,
                              void* d_out, int out_size, void* d_ws, size_t ws_size,
                              hipStream_t stream) {
    const float* x     = (const float*)d_in[0];
    const float* Wq    = (const float*)d_in[1];
    const float* Wk    = (const float*)d_in[2];
    const float* Wv    = (const float*)d_in[3];
    const float* Wb    = (const float*)d_in[4];
    const float* Wo    = (const float*)d_in[5];
    const float* rms_w = (const float*)d_in[6];
    float* out = (float*)d_out;

    char* p = (char*)d_ws;
    float* Q  = (float*)p;  p += (size_t)RD * 4;
    float* Kp = (float*)p;  p += (size_t)RD * 4;
    float* Vp = (float*)p;  p += (size_t)RD * 4;
    float* Y  = (float*)p;  p += (size_t)RD * 4;
    float* Bt = (float*)p;  p += (size_t)32768 * 4;
    unsigned short* xh  = (unsigned short*)p;  p += (size_t)RD * 2;   // reused as Yh
    unsigned short* xl  = (unsigned short*)p;  p += (size_t)RD * 2;   // reused as Yl
    unsigned short* Wsh = (unsigned short*)p;  p += (size_t)WSZ * 2;
    unsigned short* Wsl = (unsigned short*)p;  p += (size_t)WSZ * 2;
    const size_t need_fast = (size_t)RD * 16 + 131072 + (size_t)RD * 4 + (size_t)WSZ * 4;
    const bool fast = ws_size >= need_fast;

    // Wk/Wv splits parked in Y (dead until scan writes it)
    unsigned short* Wkh = (unsigned short*)Y;
    unsigned short* Wkl = Wkh + WSZ;
    unsigned short* Wvh = Wkl + WSZ;
    unsigned short* Wvl = Wvh + WSZ;

    (void)hipFuncSetAttribute(reinterpret_cast<const void*>(scan_chunked),
                              hipFuncAttributeMaxDynamicSharedMemorySize, SMEM_SCAN);

    if (fast) {
        dim3 ggrid(D_MODEL / 64, ROWS / 128);       // (16,16) = 256 blocks
        dim3 qgrid(D_MODEL / 64, ROWS / 128, 3);    // 768 blocks = 3/CU
        split_kernel<<<RD / 4 / 256, 256, 0, stream>>>(x, xh, xl, RD / 4);
        split3_kernel<<<3 * WSZ / 4 / 256, 256, 0, stream>>>(Wq, Wk, Wv,
                                                             Wsh, Wsl, Wkh, Wkl, Wvh, Wvl);
        gemm_qkv<<<qgrid, 256, 0, stream>>>(xh, xl, Wsh, Wsl, Wkh, Wkl, Wvh, Wvl,
                                            Q, Kp, Vp);
        beta_kernel<<<ROWS / 4, 256, 0, stream>>>(x, Wb, Bt);
        norm_qk<<<2 * ROWS * NHEAD / 4, 256, 0, stream>>>(Q, Kp);
        scan_chunked<<<BATCH * NHEAD, 256, SMEM_SCAN, stream>>>(Q, Kp, Vp, Bt, Y);
        rmsnorm_kernel<1><<<ROWS, 256, 0, stream>>>(Y, rms_w, xh, xl);
        split_kernel<<<WSZ / 4 / 256, 256, 0, stream>>>(Wo, Wsh, Wsl, WSZ / 4);
        gemm_bf16s<0><<<ggrid, 256, 0, stream>>>(xh, xl, Wsh, Wsl, out, ROWS, D_MODEL, D_MODEL);
    } else {
        dim3 ggrid(D_MODEL / 128, ROWS / 128);  // (8,16)
        gemm_mfma<1><<<ggrid, 256, 0, stream>>>(x, Wq, Q, ROWS, D_MODEL, D_MODEL);
        gemm_mfma<1><<<ggrid, 256, 0, stream>>>(x, Wk, Kp, ROWS, D_MODEL, D_MODEL);
        gemm_mfma<1><<<ggrid, 256, 0, stream>>>(x, Wv, Vp, ROWS, D_MODEL, D_MODEL);
        beta_kernel<<<ROWS / 4, 256, 0, stream>>>(x, Wb, Bt);
        norm_qk<<<2 * ROWS * NHEAD / 4, 256, 0, stream>>>(Q, Kp);
        scan_chunked<<<BATCH * NHEAD, 256, SMEM_SCAN, stream>>>(Q, Kp, Vp, Bt, Y);
        rmsnorm_kernel<0><<<ROWS, 256, 0, stream>>>(Y, rms_w, nullptr, nullptr);
        gemm_mfma<0><<<ggrid, 256, 0, stream>>>(Y, Wo, out, ROWS, D_MODEL, D_MODEL);
    }
}

// Round 9
// 477.627 us; speedup vs baseline: 2.2578x; 1.0042x over previous
//
#include <hip/hip_runtime.h>
#include <math.h>

#define D_MODEL 1024
#define NHEAD 16
#define HEAD_DIM 64
#define BATCH 2
#define SEQ 1024
#define ROWS (BATCH * SEQ)        // 2048
#define RD (ROWS * D_MODEL)       // 2097152
#define WSZ (D_MODEL * D_MODEL)   // 1048576
#define CHUNK 64
#define NCHUNK (SEQ / CHUNK)      // 16

typedef __attribute__((ext_vector_type(8))) short bf16x8;
typedef __attribute__((ext_vector_type(8))) unsigned short ushort8;
typedef __attribute__((ext_vector_type(4))) unsigned short us4;
typedef __attribute__((ext_vector_type(4))) float f32x4;
typedef __attribute__((ext_vector_type(4))) unsigned int uint4v;
typedef unsigned short ushort;

// ---------------------------------------------------------------------------
// helpers
// ---------------------------------------------------------------------------
__device__ __forceinline__ void load_lds_16u(const unsigned short* g, unsigned short* l) {
    __builtin_amdgcn_global_load_lds((const __attribute__((address_space(1))) void*)g,
                                     (__attribute__((address_space(3))) void*)l, 16, 0, 0);
}
// fp32 -> bf16 RNE, and back
__device__ __forceinline__ unsigned short f2bf(float x) {
    unsigned int u = __float_as_uint(x);
    unsigned int r = (u + 0x7FFFu + ((u >> 16) & 1u)) >> 16;
    return (unsigned short)r;
}
__device__ __forceinline__ float bf2f(unsigned short h) {
    return __uint_as_float(((unsigned int)h) << 16);
}
// uniform-lane broadcast (SALU path, not LDS)
__device__ __forceinline__ float lane_bcast(float v, int lane) {
    return __uint_as_float(__builtin_amdgcn_readlane(__float_as_uint(v), lane));
}
// fragment-order index (SUBST=512 validated; 520 pad regressed 24% — do not pad)
#define SUBST 512
#define FBUF (8 * SUBST * 2)   // 8192 bytes per 64x64 operand buffer
__device__ __forceinline__ int fidx(int r, int k) {
    return ((r >> 4) * 2 + (k >> 5)) * SUBST + ((((k & 31) >> 3) << 4) + (r & 15)) * 8 + (k & 7);
}

// ---------------------------------------------------------------------------
// split: fp32 -> (hi, lo) bf16 buffers. n4 = n/4 float4 groups.
// ---------------------------------------------------------------------------
__global__ __launch_bounds__(256) void split_kernel(const float* __restrict__ X,
                                                    unsigned short* __restrict__ H,
                                                    unsigned short* __restrict__ L,
                                                    int n4) {
    int i = blockIdx.x * 256 + threadIdx.x;
    if (i >= n4) return;
    float4 v = ((const float4*)X)[i];
    us4 h, l;
    h.x = f2bf(v.x); l.x = f2bf(v.x - bf2f(h.x));
    h.y = f2bf(v.y); l.y = f2bf(v.y - bf2f(h.y));
    h.z = f2bf(v.z); l.z = f2bf(v.z - bf2f(h.z));
    h.w = f2bf(v.w); l.w = f2bf(v.w - bf2f(h.w));
    ((us4*)H)[i] = h;
    ((us4*)L)[i] = l;
}

// fused 3-way weight split (one launch for Wq, Wk, Wv)
__global__ __launch_bounds__(256) void split3_kernel(const float* __restrict__ W0,
                                                     const float* __restrict__ W1,
                                                     const float* __restrict__ W2,
                                                     unsigned short* __restrict__ H0,
                                                     unsigned short* __restrict__ L0,
                                                     unsigned short* __restrict__ H1,
                                                     unsigned short* __restrict__ L1,
                                                     unsigned short* __restrict__ H2,
                                                     unsigned short* __restrict__ L2) {
    const int n4 = WSZ / 4;
    int i = blockIdx.x * 256 + threadIdx.x;
    const int which = i / n4;
    const int j = i - which * n4;
    const float* X = (which == 0) ? W0 : (which == 1) ? W1 : W2;
    unsigned short* H = (which == 0) ? H0 : (which == 1) ? H1 : H2;
    unsigned short* L = (which == 0) ? L0 : (which == 1) ? L1 : L2;
    float4 v = ((const float4*)X)[j];
    us4 h, l;
    h.x = f2bf(v.x); l.x = f2bf(v.x - bf2f(h.x));
    h.y = f2bf(v.y); l.y = f2bf(v.y - bf2f(h.y));
    h.z = f2bf(v.z); l.z = f2bf(v.z - bf2f(h.z));
    h.w = f2bf(v.w); l.w = f2bf(v.w - bf2f(h.w));
    ((us4*)H)[j] = h;
    ((us4*)L)[j] = l;
}

// ---------------------------------------------------------------------------
// GEMM core on pre-split inputs (R4-validated structure).
// ---------------------------------------------------------------------------
template <int ACT>
__device__ __forceinline__ void gemm_core(const unsigned short* __restrict__ Ah,
                                          const unsigned short* __restrict__ Al,
                                          const unsigned short* __restrict__ Bh,
                                          const unsigned short* __restrict__ Bl,
                                          float* __restrict__ C,
                                          int M, int N, int K,
                                          unsigned short* LA0, unsigned short* LA1,
                                          unsigned short* LB0, unsigned short* LB1) {
    const int t = threadIdx.x;
    const int wave = t >> 6, lane = t & 63;
    const int wm = wave >> 1, wn = wave & 1;
    const int m16 = lane & 15, kg = lane >> 4;
    const int row0 = blockIdx.y * 128, col0 = blockIdx.x * 64;

    f32x4 acc[4][2];
#pragma unroll
    for (int i = 0; i < 4; ++i)
#pragma unroll
        for (int j = 0; j < 2; ++j) acc[i][j] = (f32x4){0.f, 0.f, 0.f, 0.f};

    for (int k0 = 0; k0 < K; k0 += 32) {
#pragma unroll
        for (int ci = 0; ci < 6; ++ci) {
            const int c = wave * 6 + ci;
            const unsigned short* src;
            unsigned short* dst;
            int g16, rbase;
            if (c < 8)       { src = Ah; dst = &LA0[c * 512];        g16 = c;      rbase = row0; }
            else if (c < 16) { src = Al; dst = &LA1[(c - 8) * 512];  g16 = c - 8;  rbase = row0; }
            else if (c < 20) { src = Bh; dst = &LB0[(c - 16) * 512]; g16 = c - 16; rbase = col0; }
            else             { src = Bl; dst = &LB1[(c - 20) * 512]; g16 = c - 20; rbase = col0; }
            const unsigned short* gp = src + (size_t)(rbase + g16 * 16 + m16) * K + k0 + kg * 8;
            load_lds_16u(gp, dst);
        }
        __syncthreads();

        bf16x8 fah[4], fal[4], fbh[2], fbl[2];
#pragma unroll
        for (int mt = 0; mt < 4; ++mt) {
            const int off = (wm * 4 + mt) * 512 + lane * 8;
            fah[mt] = *(const bf16x8*)&LA0[off];
            fal[mt] = *(const bf16x8*)&LA1[off];
        }
#pragma unroll
        for (int nt = 0; nt < 2; ++nt) {
            const int off = (wn * 2 + nt) * 512 + lane * 8;
            fbh[nt] = *(const bf16x8*)&LB0[off];
            fbl[nt] = *(const bf16x8*)&LB1[off];
        }
#pragma unroll
        for (int mt = 0; mt < 4; ++mt)
#pragma unroll
            for (int nt = 0; nt < 2; ++nt) {
                acc[mt][nt] = __builtin_amdgcn_mfma_f32_16x16x32_bf16(fal[mt], fbh[nt], acc[mt][nt], 0, 0, 0);
                acc[mt][nt] = __builtin_amdgcn_mfma_f32_16x16x32_bf16(fah[mt], fbl[nt], acc[mt][nt], 0, 0, 0);
                acc[mt][nt] = __builtin_amdgcn_mfma_f32_16x16x32_bf16(fah[mt], fbh[nt], acc[mt][nt], 0, 0, 0);
            }
        __syncthreads();
    }

#pragma unroll
    for (int mt = 0; mt < 4; ++mt)
#pragma unroll
        for (int nt = 0; nt < 2; ++nt) {
            const int rowb = row0 + wm * 64 + mt * 16 + kg * 4;
            const int col  = col0 + wn * 32 + nt * 16 + m16;
#pragma unroll
            for (int rg = 0; rg < 4; ++rg) {
                float v = acc[mt][nt][rg];
                if (ACT == 1) v = v / (1.f + expf(-v));
                C[(size_t)(rowb + rg) * N + col] = v;
            }
        }
}

template <int ACT>
__global__ __launch_bounds__(256) void gemm_bf16s(const unsigned short* __restrict__ Ah,
                                                  const unsigned short* __restrict__ Al,
                                                  const unsigned short* __restrict__ Bh,
                                                  const unsigned short* __restrict__ Bl,
                                                  float* __restrict__ C,
                                                  int M, int N, int K) {
    __shared__ unsigned short LA[2][8 * 512];
    __shared__ unsigned short LB[2][4 * 512];
    gemm_core<ACT>(Ah, Al, Bh, Bl, C, M, N, K, LA[0], LA[1], LB[0], LB[1]);
}

// fused QKV GEMM: blockIdx.z selects weight/output; 768 blocks = 3/CU
__global__ __launch_bounds__(256) void gemm_qkv(const unsigned short* __restrict__ Ah,
                                                const unsigned short* __restrict__ Al,
                                                const unsigned short* __restrict__ Bqh,
                                                const unsigned short* __restrict__ Bql,
                                                const unsigned short* __restrict__ Bkh,
                                                const unsigned short* __restrict__ Bkl,
                                                const unsigned short* __restrict__ Bvh,
                                                const unsigned short* __restrict__ Bvl,
                                                float* __restrict__ Cq,
                                                float* __restrict__ Ck,
                                                float* __restrict__ Cv) {
    __shared__ unsigned short LA[2][8 * 512];
    __shared__ unsigned short LB[2][4 * 512];
    const int z = blockIdx.z;
    const unsigned short* Bh = (z == 0) ? Bqh : (z == 1) ? Bkh : Bvh;
    const unsigned short* Bl = (z == 0) ? Bql : (z == 1) ? Bkl : Bvl;
    float* C = (z == 0) ? Cq : (z == 1) ? Ck : Cv;
    gemm_core<1>(Ah, Al, Bh, Bl, C, ROWS, D_MODEL, D_MODEL, LA[0], LA[1], LB[0], LB[1]);
}

// ---------------------------------------------------------------------------
// Fallback GEMM (inline split) — only if ws_size too small.
// ---------------------------------------------------------------------------
#define LDST 40
template <int ACT>
__global__ __launch_bounds__(256) void gemm_mfma(const float* __restrict__ A,
                                                 const float* __restrict__ B,
                                                 float* __restrict__ C,
                                                 int M, int N, int K) {
    __shared__ unsigned short Ahi[128 * LDST], Alo[128 * LDST];
    __shared__ unsigned short Bhi[128 * LDST], Blo[128 * LDST];

    const int t = threadIdx.x;
    const int wave = t >> 6, lane = t & 63;
    const int wm = wave >> 1, wn = wave & 1;
    const int row0 = blockIdx.y * 128, col0 = blockIdx.x * 128;
    const int sr = t >> 1;
    const int sh = t & 1;
    const int m16 = lane & 15, kg = lane >> 4;

    f32x4 acc[4][4];
#pragma unroll
    for (int i = 0; i < 4; ++i)
#pragma unroll
        for (int j = 0; j < 4; ++j) acc[i][j] = (f32x4){0.f, 0.f, 0.f, 0.f};

    const float* ga = A + (size_t)(row0 + sr) * K + sh * 16;
    const float* gb = B + (size_t)(col0 + sr) * K + sh * 16;
    const int sbase = sr * LDST + sh * 16;

    for (int k0 = 0; k0 < K; k0 += 32) {
        float af[16], bf[16];
#pragma unroll
        for (int i = 0; i < 4; ++i) {
            float4 a4 = *(const float4*)(ga + k0 + i * 4);
            float4 b4 = *(const float4*)(gb + k0 + i * 4);
            af[i * 4 + 0] = a4.x; af[i * 4 + 1] = a4.y; af[i * 4 + 2] = a4.z; af[i * 4 + 3] = a4.w;
            bf[i * 4 + 0] = b4.x; bf[i * 4 + 1] = b4.y; bf[i * 4 + 2] = b4.z; bf[i * 4 + 3] = b4.w;
        }
        ushort8 ah0, ah1, al0, al1, bh0, bh1, bl0, bl1;
#pragma unroll
        for (int j = 0; j < 8; ++j) {
            unsigned short h = f2bf(af[j]);       ah0[j] = h; al0[j] = f2bf(af[j] - bf2f(h));
            h = f2bf(af[j + 8]);                  ah1[j] = h; al1[j] = f2bf(af[j + 8] - bf2f(h));
            h = f2bf(bf[j]);                      bh0[j] = h; bl0[j] = f2bf(bf[j] - bf2f(h));
            h = f2bf(bf[j + 8]);                  bh1[j] = h; bl1[j] = f2bf(bf[j + 8] - bf2f(h));
        }
        *(ushort8*)&Ahi[sbase] = ah0;  *(ushort8*)&Ahi[sbase + 8] = ah1;
        *(ushort8*)&Alo[sbase] = al0;  *(ushort8*)&Alo[sbase + 8] = al1;
        *(ushort8*)&Bhi[sbase] = bh0;  *(ushort8*)&Bhi[sbase + 8] = bh1;
        *(ushort8*)&Blo[sbase] = bl0;  *(ushort8*)&Blo[sbase + 8] = bl1;
        __syncthreads();

        bf16x8 fah[4], fal[4], fbh[4], fbl[4];
#pragma unroll
        for (int i = 0; i < 4; ++i) {
            const int ar = (wm * 64 + i * 16 + m16) * LDST + kg * 8;
            const int br = (wn * 64 + i * 16 + m16) * LDST + kg * 8;
            fah[i] = *(const bf16x8*)&Ahi[ar];
            fal[i] = *(const bf16x8*)&Alo[ar];
            fbh[i] = *(const bf16x8*)&Bhi[br];
            fbl[i] = *(const bf16x8*)&Blo[br];
        }
#pragma unroll
        for (int i = 0; i < 4; ++i)
#pragma unroll
            for (int j = 0; j < 4; ++j) {
                acc[i][j] = __builtin_amdgcn_mfma_f32_16x16x32_bf16(fal[i], fbh[j], acc[i][j], 0, 0, 0);
                acc[i][j] = __builtin_amdgcn_mfma_f32_16x16x32_bf16(fah[i], fbl[j], acc[i][j], 0, 0, 0);
                acc[i][j] = __builtin_amdgcn_mfma_f32_16x16x32_bf16(fah[i], fbh[j], acc[i][j], 0, 0, 0);
            }
        __syncthreads();
    }

#pragma unroll
    for (int i = 0; i < 4; ++i)
#pragma unroll
        for (int j = 0; j < 4; ++j) {
            const int col = col0 + wn * 64 + j * 16 + m16;
            const int rowb = row0 + wm * 64 + i * 16 + kg * 4;
#pragma unroll
            for (int rg = 0; rg < 4; ++rg) {
                float v = acc[i][j][rg];
                if (ACT == 1) v = v / (1.f + expf(-v));
                C[(size_t)(rowb + rg) * N + col] = v;
            }
        }
}

// ---------------------------------------------------------------------------
// beta = 2*sigmoid(x @ Wb^T)  : (ROWS, NHEAD). One wave per row.
// ---------------------------------------------------------------------------
__global__ __launch_bounds__(256) void beta_kernel(const float* __restrict__ x,
                                                   const float* __restrict__ Wb,
                                                   float* __restrict__ beta) {
    const int wave = blockIdx.x * 4 + (threadIdx.x >> 6);
    const int lane = threadIdx.x & 63;
    const float* xr = x + (size_t)wave * D_MODEL;
    float xv[16];
#pragma unroll
    for (int j = 0; j < 16; ++j) xv[j] = xr[lane + 64 * j];
    for (int n = 0; n < NHEAD; ++n) {
        const float* wr = Wb + (size_t)n * D_MODEL;
        float s = 0.f;
#pragma unroll
        for (int j = 0; j < 16; ++j) s += xv[j] * wr[lane + 64 * j];
#pragma unroll
        for (int off = 32; off; off >>= 1) s += __shfl_xor(s, off);
        if (lane == 0) beta[(size_t)wave * NHEAD + n] = 2.f / (1.f + expf(-s));
    }
}

// ---------------------------------------------------------------------------
// L2-normalize q and k per (row, head) over HEAD_DIM=64.
// ---------------------------------------------------------------------------
__global__ __launch_bounds__(256) void norm_qk(float* __restrict__ Q,
                                               float* __restrict__ Kp) {
    const int TOT = ROWS * NHEAD;
    int wave = blockIdx.x * 4 + (threadIdx.x >> 6);
    const int lane = threadIdx.x & 63;
    float* T = (wave < TOT) ? Q : Kp;
    int w = (wave < TOT) ? wave : wave - TOT;
    float* p = T + (size_t)(w >> 4) * D_MODEL + (size_t)(w & 15) * HEAD_DIM;
    float v = p[lane];
    float ss = v * v;
#pragma unroll
    for (int off = 32; off; off >>= 1) ss += __shfl_xor(ss, off);
    p[lane] = v / (sqrtf(ss) + 1e-6f);
}

// ---------------------------------------------------------------------------
// Chunked delta-rule scan v4: 512 threads = 8 waves (2/SIMD -> TLP latency
// hiding). Wave grid 4x2: wm = 16-row band, wn = 32-col half. R8's fp32
// register state (Macc/MTacc/V0acc) retained. Solve chain unchanged
// (redundant across waves; wave 0 publishes).
// ---------------------------------------------------------------------------
#define SMEM_SCAN 153088

__global__ __launch_bounds__(512, 1) void scan_chunked(const float* __restrict__ Qg,
                                                       const float* __restrict__ Kg,
                                                       const float* __restrict__ Vg,
                                                       const float* __restrict__ Btg,
                                                       float* __restrict__ Yg) {
    extern __shared__ char smem[];
    ushort* Mh_  = (ushort*)(smem + 0 * FBUF);
    ushort* Ml_  = (ushort*)(smem + 1 * FBUF);
    ushort* MTh_ = (ushort*)(smem + 2 * FBUF);
    ushort* MTl_ = (ushort*)(smem + 3 * FBUF);
    ushort* KTh_ = (ushort*)(smem + 4 * FBUF);
    ushort* KTl_ = (ushort*)(smem + 5 * FBUF);
    ushort* V0h_ = (ushort*)(smem + 6 * FBUF);
    ushort* V0l_ = (ushort*)(smem + 7 * FBUF);
    ushort* Gh_  = (ushort*)(smem + 8 * FBUF);
    ushort* Gl_  = (ushort*)(smem + 9 * FBUF);
    ushort* Kh_  = (ushort*)(smem + 10 * FBUF);  // union1: K / DT
    ushort* Kl_  = (ushort*)(smem + 11 * FBUF);
    ushort* DTh_ = Kh_;
    ushort* DTl_ = Kl_;
    ushort* Qh_  = (ushort*)(smem + 12 * FBUF);  // union2: Q / W (adjacent hi,lo)
    ushort* Ql_  = (ushort*)(smem + 13 * FBUF);
    ushort* Wh_  = Qh_;
    ushort* Wl_  = Ql_;
    float*  V32  = (float*)(smem + 14 * FBUF);             // 64x68 fp32 (union C032)
    float*  C032 = V32;
    ushort* Ah_  = (ushort*)(smem + 14 * FBUF + 17408);
    ushort* Al_  = (ushort*)(smem + 15 * FBUF + 17408);
    float*  N32  = (float*)(smem + 16 * FBUF + 17408);     // 64x17 fp32
    float*  bv   = (float*)(smem + 16 * FBUF + 17408 + 4352);

    const int b = blockIdx.x >> 4;
    const int n = blockIdx.x & 15;
    const int t = threadIdx.x;
    const int wave = t >> 6, lane = t & 63;
    const int wm = wave >> 1, wn = wave & 1;      // 4x2 wave grid
    const int m16 = lane & 15, kg = lane >> 4;
    const int bS = b * SEQ;
    const int nOff = n * HEAD_DIM;
    const int r = t >> 3, g = t & 7;   // staging: row r (0..63), col-octet g (0..7)

    // fp32 register state: row = wm*16 + kg*4 + rg, col = wn*32 + j*16 + m16
    f32x4 Macc[2], MTacc[2];
#pragma unroll
    for (int j = 0; j < 2; ++j) {
        Macc[j] = (f32x4){0.f, 0.f, 0.f, 0.f};
        MTacc[j] = (f32x4){0.f, 0.f, 0.f, 0.f};
    }

    // product: wave's 16-row band x 32-col half, K=64, split operands, D = X*Y^T
    auto prod_band = [&](const ushort* Ah, const ushort* Al,
                         const ushort* Bh, const ushort* Bl, f32x4 acc[2]) {
        const int lo8 = lane * 8;
#pragma unroll
        for (int half = 0; half < 2; ++half) {
            bf16x8 ah = *(const bf16x8*)&Ah[(wm * 2 + half) * SUBST + lo8];
            bf16x8 al = *(const bf16x8*)&Al[(wm * 2 + half) * SUBST + lo8];
#pragma unroll
            for (int j = 0; j < 2; ++j) {
                const int jg = wn * 2 + j;
                bf16x8 bh = *(const bf16x8*)&Bh[(jg * 2 + half) * SUBST + lo8];
                bf16x8 bl = *(const bf16x8*)&Bl[(jg * 2 + half) * SUBST + lo8];
                acc[j] = __builtin_amdgcn_mfma_f32_16x16x32_bf16(al, bh, acc[j], 0, 0, 0);
                acc[j] = __builtin_amdgcn_mfma_f32_16x16x32_bf16(ah, bl, acc[j], 0, 0, 0);
                acc[j] = __builtin_amdgcn_mfma_f32_16x16x32_bf16(ah, bh, acc[j], 0, 0, 0);
            }
        }
    };

    for (int c = 0; c < NCHUNK; ++c) {
        const int s0 = c * CHUNK;

        // ---- stage K (+transpose), Q, V, beta; 8 elems/thread ----
        {
            const float* gK = Kg + (size_t)(bS + s0 + r) * D_MODEL + nOff + g * 8;
            const float* gQ = Qg + (size_t)(bS + s0 + r) * D_MODEL + nOff + g * 8;
            const float* gV = Vg + (size_t)(bS + s0 + r) * D_MODEL + nOff + g * 8;
            float kf[8], qf[8];
            ushort khv[8], klv[8];
            float4 kv0 = ((const float4*)gK)[0], kv1 = ((const float4*)gK)[1];
            float4 qv0 = ((const float4*)gQ)[0], qv1 = ((const float4*)gQ)[1];
            float4 vv0 = ((const float4*)gV)[0], vv1 = ((const float4*)gV)[1];
            kf[0] = kv0.x; kf[1] = kv0.y; kf[2] = kv0.z; kf[3] = kv0.w;
            kf[4] = kv1.x; kf[5] = kv1.y; kf[6] = kv1.z; kf[7] = kv1.w;
            qf[0] = qv0.x; qf[1] = qv0.y; qf[2] = qv0.z; qf[3] = qv0.w;
            qf[4] = qv1.x; qf[5] = qv1.y; qf[6] = qv1.z; qf[7] = qv1.w;
            *(float4*)&V32[r * 68 + g * 8] = vv0;
            *(float4*)&V32[r * 68 + g * 8 + 4] = vv1;
            ushort8 kh8, kl8, qh8, ql8;
#pragma unroll
            for (int e = 0; e < 8; ++e) {
                ushort h = f2bf(kf[e]);
                ushort l = f2bf(kf[e] - bf2f(h));
                khv[e] = h; klv[e] = l;
                kh8[e] = h; kl8[e] = l;
                h = f2bf(qf[e]); l = f2bf(qf[e] - bf2f(h));
                qh8[e] = h; ql8[e] = l;
            }
            const int o0 = fidx(r, g * 8);
            *(ushort8*)&Kh_[o0] = kh8;
            *(ushort8*)&Kl_[o0] = kl8;
            *(ushort8*)&Qh_[o0] = qh8;
            *(ushort8*)&Ql_[o0] = ql8;
#pragma unroll
            for (int e = 0; e < 8; ++e) {
                const int ib = fidx(g * 8 + e, r);
                KTh_[ib] = khv[e]; KTl_[ib] = klv[e];
            }
            if (t < 64) bv[t] = Btg[(size_t)(bS + s0 + t) * NHEAD + n];
        }
        __syncthreads();   // B1

        f32x4 yacc[2], V0acc[2];
        {
            // ---- P_R: V0 = V - K*M0^T (register result + split-bf16 operand copy) ----
            if (c > 0) {
#pragma unroll
                for (int j = 0; j < 2; ++j) V0acc[j] = (f32x4){0.f, 0.f, 0.f, 0.f};
                prod_band(Kh_, Kl_, Mh_, Ml_, V0acc);
#pragma unroll
                for (int j = 0; j < 2; ++j)
#pragma unroll
                    for (int rg = 0; rg < 4; ++rg) {
                        const int row = wm * 16 + kg * 4 + rg, col = wn * 32 + j * 16 + m16;
                        V0acc[j][rg] = V32[row * 68 + col] - V0acc[j][rg];
                    }
            } else {
#pragma unroll
                for (int j = 0; j < 2; ++j)
#pragma unroll
                    for (int rg = 0; rg < 4; ++rg) {
                        const int row = wm * 16 + kg * 4 + rg, col = wn * 32 + j * 16 + m16;
                        V0acc[j][rg] = V32[row * 68 + col];
                    }
            }
#pragma unroll
            for (int j = 0; j < 2; ++j)
#pragma unroll
                for (int rg = 0; rg < 4; ++rg) {
                    const int row = wm * 16 + kg * 4 + rg, col = wn * 32 + j * 16 + m16;
                    float v0 = V0acc[j][rg];
                    ushort h = f2bf(v0);
                    const int ii = fidx(row, col);
                    V0h_[ii] = h; V0l_[ii] = f2bf(v0 - bf2f(h));
                }
            // ---- P_YM: yacc = Q*M0 (via MT) ----
#pragma unroll
            for (int j = 0; j < 2; ++j) yacc[j] = (f32x4){0.f, 0.f, 0.f, 0.f};
            if (c > 0) prod_band(Qh_, Ql_, MTh_, MTl_, yacc);
            // ---- P_A: A = K K^T -> Asp ----
            f32x4 acc[2];
#pragma unroll
            for (int j = 0; j < 2; ++j) acc[j] = (f32x4){0.f, 0.f, 0.f, 0.f};
            prod_band(Kh_, Kl_, Kh_, Kl_, acc);
#pragma unroll
            for (int j = 0; j < 2; ++j)
#pragma unroll
                for (int rg = 0; rg < 4; ++rg) {
                    const int row = wm * 16 + kg * 4 + rg, col = wn * 32 + j * 16 + m16;
                    float av = acc[j][rg];
                    ushort h = f2bf(av);
                    const int ii = fidx(row, col);
                    Ah_[ii] = h; Al_[ii] = f2bf(av - bf2f(h));
                }
            // ---- P_QK: G = tril_(Q K^T) -> Gsp ----
#pragma unroll
            for (int j = 0; j < 2; ++j) acc[j] = (f32x4){0.f, 0.f, 0.f, 0.f};
            prod_band(Qh_, Ql_, Kh_, Kl_, acc);
#pragma unroll
            for (int j = 0; j < 2; ++j)
#pragma unroll
                for (int rg = 0; rg < 4; ++rg) {
                    const int row = wm * 16 + kg * 4 + rg, col = wn * 32 + j * 16 + m16;
                    float gv = (row > col) ? acc[j][rg] : 0.f;
                    ushort h = f2bf(gv);
                    const int ii = fidx(row, col);
                    Gh_[ii] = h; Gl_[ii] = f2bf(gv - bf2f(h));
                }
        }
        __syncthreads();   // B2 (V32 dead -> C032 writable; Q dead -> W writable)

        {
            // ---- P_C0: C0 = K * V0^T -> fp32 ----
            f32x4 acc[2];
#pragma unroll
            for (int j = 0; j < 2; ++j) acc[j] = (f32x4){0.f, 0.f, 0.f, 0.f};
            prod_band(Kh_, Kl_, V0h_, V0l_, acc);
#pragma unroll
            for (int j = 0; j < 2; ++j)
#pragma unroll
                for (int rg = 0; rg < 4; ++rg) {
                    const int row = wm * 16 + kg * 4 + rg, col = wn * 32 + j * 16 + m16;
                    C032[row * 68 + col] = acc[j][rg];
                }
            // zero W region (Wh_,Wl_ adjacent): must be 0, not stale, every chunk
            for (int i = t; i < 2 * FBUF / 16; i += 512)
                ((uint4v*)Wh_)[i] = (uint4v){0u, 0u, 0u, 0u};
        }
        __syncthreads();   // B3

        // ---- blocked solve: 4 column-blocks of 16 ----
#pragma unroll
        for (int J = 0; J < 4; ++J) {
            if (J > 0) {
                if (wave < 4) {
                    // N_J[t, s in J] = A * W_J^T (waves 0-3 = 16-row bands)
                    f32x4 acc1 = (f32x4){0.f, 0.f, 0.f, 0.f};
                    const int lo8 = lane * 8;
#pragma unroll
                    for (int half = 0; half < 2; ++half) {
                        bf16x8 ah = *(const bf16x8*)&Ah_[(wave * 2 + half) * SUBST + lo8];
                        bf16x8 al = *(const bf16x8*)&Al_[(wave * 2 + half) * SUBST + lo8];
                        bf16x8 bh = *(const bf16x8*)&Wh_[(J * 2 + half) * SUBST + lo8];
                        bf16x8 bl = *(const bf16x8*)&Wl_[(J * 2 + half) * SUBST + lo8];
                        acc1 = __builtin_amdgcn_mfma_f32_16x16x32_bf16(al, bh, acc1, 0, 0, 0);
                        acc1 = __builtin_amdgcn_mfma_f32_16x16x32_bf16(ah, bl, acc1, 0, 0, 0);
                        acc1 = __builtin_amdgcn_mfma_f32_16x16x32_bf16(ah, bh, acc1, 0, 0, 0);
                    }
#pragma unroll
                    for (int rg = 0; rg < 4; ++rg)
                        N32[(wave * 16 + kg * 4 + rg) * 17 + m16] = acc1[rg];
                }
                __syncthreads();   // B4a
            }

            float Areg[16], CNreg[16];
            {
                bf16x8 a0 = *(const bf16x8*)&Ah_[fidx(lane, 16 * J)];
                bf16x8 a1 = *(const bf16x8*)&Ah_[fidx(lane, 16 * J + 8)];
                bf16x8 b0 = *(const bf16x8*)&Al_[fidx(lane, 16 * J)];
                bf16x8 b1 = *(const bf16x8*)&Al_[fidx(lane, 16 * J + 8)];
#pragma unroll
                for (int e = 0; e < 8; ++e) {
                    Areg[e]     = bf2f((ushort)a0[e]) + bf2f((ushort)b0[e]);
                    Areg[e + 8] = bf2f((ushort)a1[e]) + bf2f((ushort)b1[e]);
                }
#pragma unroll
                for (int j = 0; j < 16; ++j) CNreg[j] = C032[lane * 68 + 16 * J + j];
                if (J > 0) {
#pragma unroll
                    for (int j = 0; j < 16; ++j) CNreg[j] += N32[lane * 17 + j];
                }
            }
            float bvreg = bv[16 * J + m16];

            // 16 serial steps; even/odd partial sums halve the FMA chain depth
            float wreg[16];
#pragma unroll
            for (int j = 0; j < 16; ++j) {
                float s0 = CNreg[j], s1 = 0.f;
#pragma unroll
                for (int jj = 0; jj < 16; ++jj) {
                    if (jj < j) {
                        float pr = Areg[jj] * lane_bcast(wreg[jj], 16 * J + j);
                        if (jj & 1) s1 += pr; else s0 += pr;
                    }
                }
                float sum = s0 + s1;
                float beta_s = lane_bcast(bvreg, j);
                wreg[j] = (lane > 16 * J + j) ? (-beta_s * sum) : 0.f;
            }

            if (wave == 0) {
                ushort8 h8[2], l8[2];
#pragma unroll
                for (int e = 0; e < 16; ++e) {
                    ushort h = f2bf(wreg[e]);
                    h8[e >> 3][e & 7] = h;
                    l8[e >> 3][e & 7] = f2bf(wreg[e] - bf2f(h));
                }
                const int o0 = fidx(lane, 16 * J), o1 = fidx(lane, 16 * J + 8);
                *(ushort8*)&Wh_[o0] = h8[0]; *(ushort8*)&Wh_[o1] = h8[1];
                *(ushort8*)&Wl_[o0] = l8[0]; *(ushort8*)&Wl_[o1] = l8[1];
            }
            __syncthreads();   // B4b
        }

        {
            // ---- P_Delta: Delta = V0(reg) + W * K ; write DT = (beta Delta)^T ----
            f32x4 acc[2];
#pragma unroll
            for (int j = 0; j < 2; ++j) acc[j] = V0acc[j];
            prod_band(Wh_, Wl_, KTh_, KTl_, acc);
#pragma unroll
            for (int j = 0; j < 2; ++j)
#pragma unroll
                for (int rg = 0; rg < 4; ++rg) {
                    const int row = wm * 16 + kg * 4 + rg, col = wn * 32 + j * 16 + m16;
                    float dv = acc[j][rg] * bv[row];     // beta_s * delta_s[d]
                    ushort h = f2bf(dv);
                    const int ii = fidx(col, row);       // DT[d][s]
                    DTh_[ii] = h; DTl_[ii] = f2bf(dv - bf2f(h));
                }
        }
        __syncthreads();   // B5 (DT ready)

        {
            // ---- P_Y2: Y = yacc + G * DT^T -> global ----
            prod_band(Gh_, Gl_, DTh_, DTl_, yacc);
#pragma unroll
            for (int j = 0; j < 2; ++j)
#pragma unroll
                for (int rg = 0; rg < 4; ++rg) {
                    const int row = wm * 16 + kg * 4 + rg, col = wn * 32 + j * 16 + m16;
                    Yg[(size_t)(bS + s0 + row) * D_MODEL + nOff + col] = yacc[j][rg];
                }
            // ---- P_M: Macc += K^T * DT^T (fp32 registers) ----
            prod_band(KTh_, KTl_, DTh_, DTl_, Macc);
            // ---- P_MT: MTacc += DT * K ----
            prod_band(DTh_, DTl_, KTh_, KTl_, MTacc);
        }
        __syncthreads();   // B6a (DT consumed)
        if (c < NCHUNK - 1) {
#pragma unroll
            for (int j = 0; j < 2; ++j)
#pragma unroll
                for (int rg = 0; rg < 4; ++rg) {
                    const int row = wm * 16 + kg * 4 + rg, col = wn * 32 + j * 16 + m16;
                    const int ii = fidx(row, col);
                    float mv = Macc[j][rg];
                    ushort h = f2bf(mv);
                    Mh_[ii] = h; Ml_[ii] = f2bf(mv - bf2f(h));
                    mv = MTacc[j][rg];
                    h = f2bf(mv);
                    MTh_[ii] = h; MTl_[ii] = f2bf(mv - bf2f(h));
                }
        }
        __syncthreads();   // B6b (state operand copies ready for next chunk)
    }
}

// ---------------------------------------------------------------------------
// RMSNorm. SPLIT=1: write (hi,lo) bf16 for final GEMM. SPLIT=0: fp32 in place.
// ---------------------------------------------------------------------------
template <int SPLIT>
__global__ __launch_bounds__(256) void rmsnorm_kernel(float* __restrict__ Y,
                                                      const float* __restrict__ w,
                                                      unsigned short* __restrict__ H,
                                                      unsigned short* __restrict__ L) {
    __shared__ float red[4];
    float* y = Y + (size_t)blockIdx.x * D_MODEL;
    const int t = threadIdx.x;
    const int wv = t >> 6, ln = t & 63;
    float4 v = ((float4*)y)[t];
    float ss = v.x * v.x + v.y * v.y + v.z * v.z + v.w * v.w;
#pragma unroll
    for (int off = 32; off; off >>= 1) ss += __shfl_xor(ss, off);
    if (ln == 0) red[wv] = ss;
    __syncthreads();
    float tot = red[0] + red[1] + red[2] + red[3];
    float inv = 1.f / sqrtf(tot * (1.f / D_MODEL) + 1e-6f);
    const float4 wv4 = ((const float4*)w)[t];
    v.x *= inv * wv4.x; v.y *= inv * wv4.y;
    v.z *= inv * wv4.z; v.w *= inv * wv4.w;
    if (SPLIT) {
        us4 h, l;
        h.x = f2bf(v.x); l.x = f2bf(v.x - bf2f(h.x));
        h.y = f2bf(v.y); l.y = f2bf(v.y - bf2f(h.y));
        h.z = f2bf(v.z); l.z = f2bf(v.z - bf2f(h.z));
        h.w = f2bf(v.w); l.w = f2bf(v.w - bf2f(h.w));
        size_t i = (size_t)blockIdx.x * 256 + t;
        ((us4*)H)[i] = h;
        ((us4*)L)[i] = l;
    } else {
        ((float4*)y)[t] = v;
    }
}

// ---------------------------------------------------------------------------
extern "C" void kernel_launch(void* const* d_in, const int* in_sizes, int n_in,
                              void* d_out, int out_size, void* d_ws, size_t ws_size,
                              hipStream_t stream) {
    const float* x     = (const float*)d_in[0];
    const float* Wq    = (const float*)d_in[1];
    const float* Wk    = (const float*)d_in[2];
    const float* Wv    = (const float*)d_in[3];
    const float* Wb    = (const float*)d_in[4];
    const float* Wo    = (const float*)d_in[5];
    const float* rms_w = (const float*)d_in[6];
    float* out = (float*)d_out;

    char* p = (char*)d_ws;
    float* Q  = (float*)p;  p += (size_t)RD * 4;
    float* Kp = (float*)p;  p += (size_t)RD * 4;
    float* Vp = (float*)p;  p += (size_t)RD * 4;
    float* Y  = (float*)p;  p += (size_t)RD * 4;
    float* Bt = (float*)p;  p += (size_t)32768 * 4;
    unsigned short* xh  = (unsigned short*)p;  p += (size_t)RD * 2;   // reused as Yh
    unsigned short* xl  = (unsigned short*)p;  p += (size_t)RD * 2;   // reused as Yl
    unsigned short* Wsh = (unsigned short*)p;  p += (size_t)WSZ * 2;
    unsigned short* Wsl = (unsigned short*)p;  p += (size_t)WSZ * 2;
    const size_t need_fast = (size_t)RD * 16 + 131072 + (size_t)RD * 4 + (size_t)WSZ * 4;
    const bool fast = ws_size >= need_fast;

    // Wk/Wv splits parked in Y (dead until scan writes it)
    unsigned short* Wkh = (unsigned short*)Y;
    unsigned short* Wkl = Wkh + WSZ;
    unsigned short* Wvh = Wkl + WSZ;
    unsigned short* Wvl = Wvh + WSZ;

    (void)hipFuncSetAttribute(reinterpret_cast<const void*>(scan_chunked),
                              hipFuncAttributeMaxDynamicSharedMemorySize, SMEM_SCAN);

    if (fast) {
        dim3 ggrid(D_MODEL / 64, ROWS / 128);       // (16,16) = 256 blocks
        dim3 qgrid(D_MODEL / 64, ROWS / 128, 3);    // 768 blocks = 3/CU
        split_kernel<<<RD / 4 / 256, 256, 0, stream>>>(x, xh, xl, RD / 4);
        split3_kernel<<<3 * WSZ / 4 / 256, 256, 0, stream>>>(Wq, Wk, Wv,
                                                             Wsh, Wsl, Wkh, Wkl, Wvh, Wvl);
        gemm_qkv<<<qgrid, 256, 0, stream>>>(xh, xl, Wsh, Wsl, Wkh, Wkl, Wvh, Wvl,
                                            Q, Kp, Vp);
        beta_kernel<<<ROWS / 4, 256, 0, stream>>>(x, Wb, Bt);
        norm_qk<<<2 * ROWS * NHEAD / 4, 256, 0, stream>>>(Q, Kp);
        scan_chunked<<<BATCH * NHEAD, 512, SMEM_SCAN, stream>>>(Q, Kp, Vp, Bt, Y);
        rmsnorm_kernel<1><<<ROWS, 256, 0, stream>>>(Y, rms_w, xh, xl);
        split_kernel<<<WSZ / 4 / 256, 256, 0, stream>>>(Wo, Wsh, Wsl, WSZ / 4);
        gemm_bf16s<0><<<ggrid, 256, 0, stream>>>(xh, xl, Wsh, Wsl, out, ROWS, D_MODEL, D_MODEL);
    } else {
        dim3 ggrid(D_MODEL / 128, ROWS / 128);  // (8,16)
        gemm_mfma<1><<<ggrid, 256, 0, stream>>>(x, Wq, Q, ROWS, D_MODEL, D_MODEL);
        gemm_mfma<1><<<ggrid, 256, 0, stream>>>(x, Wk, Kp, ROWS, D_MODEL, D_MODEL);
        gemm_mfma<1><<<ggrid, 256, 0, stream>>>(x, Wv, Vp, ROWS, D_MODEL, D_MODEL);
        beta_kernel<<<ROWS / 4, 256, 0, stream>>>(x, Wb, Bt);
        norm_qk<<<2 * ROWS * NHEAD / 4, 256, 0, stream>>>(Q, Kp);
        scan_chunked<<<BATCH * NHEAD, 512, SMEM_SCAN, stream>>>(Q, Kp, Vp, Bt, Y);
        rmsnorm_kernel<0><<<ROWS, 256, 0, stream>>>(Y, rms_w, nullptr, nullptr);
        gemm_mfma<0><<<ggrid, 256, 0, stream>>>(Y, Wo, out, ROWS, D_MODEL, D_MODEL);
    }
}

// Round 10
// 443.253 us; speedup vs baseline: 2.4329x; 1.0775x over previous
//
#include <hip/hip_runtime.h>
#include <math.h>

#define D_MODEL 1024
#define NHEAD 16
#define HEAD_DIM 64
#define BATCH 2
#define SEQ 1024
#define ROWS (BATCH * SEQ)        // 2048
#define RD (ROWS * D_MODEL)       // 2097152
#define WSZ (D_MODEL * D_MODEL)   // 1048576
#define CHUNK 64
#define NCHUNK (SEQ / CHUNK)      // 16

typedef __attribute__((ext_vector_type(8))) short bf16x8;
typedef __attribute__((ext_vector_type(8))) unsigned short ushort8;
typedef __attribute__((ext_vector_type(4))) unsigned short us4;
typedef __attribute__((ext_vector_type(4))) float f32x4;
typedef __attribute__((ext_vector_type(4))) unsigned int uint4v;
typedef unsigned short ushort;

// ---------------------------------------------------------------------------
// helpers
// ---------------------------------------------------------------------------
__device__ __forceinline__ void load_lds_16u(const unsigned short* g, unsigned short* l) {
    __builtin_amdgcn_global_load_lds((const __attribute__((address_space(1))) void*)g,
                                     (__attribute__((address_space(3))) void*)l, 16, 0, 0);
}
// fp32 -> bf16 RNE, and back
__device__ __forceinline__ unsigned short f2bf(float x) {
    unsigned int u = __float_as_uint(x);
    unsigned int r = (u + 0x7FFFu + ((u >> 16) & 1u)) >> 16;
    return (unsigned short)r;
}
__device__ __forceinline__ float bf2f(unsigned short h) {
    return __uint_as_float(((unsigned int)h) << 16);
}
// uniform-lane broadcast (SALU path, not LDS)
__device__ __forceinline__ float lane_bcast(float v, int lane) {
    return __uint_as_float(__builtin_amdgcn_readlane(__float_as_uint(v), lane));
}
// fragment-order index (SUBST=512 validated; 520 pad regressed 24% — do not pad)
#define SUBST 512
#define FBUF (8 * SUBST * 2)   // 8192 bytes per 64x64 operand buffer
__device__ __forceinline__ int fidx(int r, int k) {
    return ((r >> 4) * 2 + (k >> 5)) * SUBST + ((((k & 31) >> 3) << 4) + (r & 15)) * 8 + (k & 7);
}

// ---------------------------------------------------------------------------
// split: fp32 -> (hi, lo) bf16 buffers. n4 = n/4 float4 groups.
// ---------------------------------------------------------------------------
__global__ __launch_bounds__(256) void split_kernel(const float* __restrict__ X,
                                                    unsigned short* __restrict__ H,
                                                    unsigned short* __restrict__ L,
                                                    int n4) {
    int i = blockIdx.x * 256 + threadIdx.x;
    if (i >= n4) return;
    float4 v = ((const float4*)X)[i];
    us4 h, l;
    h.x = f2bf(v.x); l.x = f2bf(v.x - bf2f(h.x));
    h.y = f2bf(v.y); l.y = f2bf(v.y - bf2f(h.y));
    h.z = f2bf(v.z); l.z = f2bf(v.z - bf2f(h.z));
    h.w = f2bf(v.w); l.w = f2bf(v.w - bf2f(h.w));
    ((us4*)H)[i] = h;
    ((us4*)L)[i] = l;
}

// fused 3-way weight split (one launch for Wq, Wk, Wv)
__global__ __launch_bounds__(256) void split3_kernel(const float* __restrict__ W0,
                                                     const float* __restrict__ W1,
                                                     const float* __restrict__ W2,
                                                     unsigned short* __restrict__ H0,
                                                     unsigned short* __restrict__ L0,
                                                     unsigned short* __restrict__ H1,
                                                     unsigned short* __restrict__ L1,
                                                     unsigned short* __restrict__ H2,
                                                     unsigned short* __restrict__ L2) {
    const int n4 = WSZ / 4;
    int i = blockIdx.x * 256 + threadIdx.x;
    const int which = i / n4;
    const int j = i - which * n4;
    const float* X = (which == 0) ? W0 : (which == 1) ? W1 : W2;
    unsigned short* H = (which == 0) ? H0 : (which == 1) ? H1 : H2;
    unsigned short* L = (which == 0) ? L0 : (which == 1) ? L1 : L2;
    float4 v = ((const float4*)X)[j];
    us4 h, l;
    h.x = f2bf(v.x); l.x = f2bf(v.x - bf2f(h.x));
    h.y = f2bf(v.y); l.y = f2bf(v.y - bf2f(h.y));
    h.z = f2bf(v.z); l.z = f2bf(v.z - bf2f(h.z));
    h.w = f2bf(v.w); l.w = f2bf(v.w - bf2f(h.w));
    ((us4*)H)[j] = h;
    ((us4*)L)[j] = l;
}

// ---------------------------------------------------------------------------
// GEMM core on pre-split inputs (R4-validated structure).
// ---------------------------------------------------------------------------
template <int ACT>
__device__ __forceinline__ void gemm_core(const unsigned short* __restrict__ Ah,
                                          const unsigned short* __restrict__ Al,
                                          const unsigned short* __restrict__ Bh,
                                          const unsigned short* __restrict__ Bl,
                                          float* __restrict__ C,
                                          int M, int N, int K,
                                          unsigned short* LA0, unsigned short* LA1,
                                          unsigned short* LB0, unsigned short* LB1) {
    const int t = threadIdx.x;
    const int wave = t >> 6, lane = t & 63;
    const int wm = wave >> 1, wn = wave & 1;
    const int m16 = lane & 15, kg = lane >> 4;
    const int row0 = blockIdx.y * 128, col0 = blockIdx.x * 64;

    f32x4 acc[4][2];
#pragma unroll
    for (int i = 0; i < 4; ++i)
#pragma unroll
        for (int j = 0; j < 2; ++j) acc[i][j] = (f32x4){0.f, 0.f, 0.f, 0.f};

    for (int k0 = 0; k0 < K; k0 += 32) {
#pragma unroll
        for (int ci = 0; ci < 6; ++ci) {
            const int c = wave * 6 + ci;
            const unsigned short* src;
            unsigned short* dst;
            int g16, rbase;
            if (c < 8)       { src = Ah; dst = &LA0[c * 512];        g16 = c;      rbase = row0; }
            else if (c < 16) { src = Al; dst = &LA1[(c - 8) * 512];  g16 = c - 8;  rbase = row0; }
            else if (c < 20) { src = Bh; dst = &LB0[(c - 16) * 512]; g16 = c - 16; rbase = col0; }
            else             { src = Bl; dst = &LB1[(c - 20) * 512]; g16 = c - 20; rbase = col0; }
            const unsigned short* gp = src + (size_t)(rbase + g16 * 16 + m16) * K + k0 + kg * 8;
            load_lds_16u(gp, dst);
        }
        __syncthreads();

        bf16x8 fah[4], fal[4], fbh[2], fbl[2];
#pragma unroll
        for (int mt = 0; mt < 4; ++mt) {
            const int off = (wm * 4 + mt) * 512 + lane * 8;
            fah[mt] = *(const bf16x8*)&LA0[off];
            fal[mt] = *(const bf16x8*)&LA1[off];
        }
#pragma unroll
        for (int nt = 0; nt < 2; ++nt) {
            const int off = (wn * 2 + nt) * 512 + lane * 8;
            fbh[nt] = *(const bf16x8*)&LB0[off];
            fbl[nt] = *(const bf16x8*)&LB1[off];
        }
#pragma unroll
        for (int mt = 0; mt < 4; ++mt)
#pragma unroll
            for (int nt = 0; nt < 2; ++nt) {
                acc[mt][nt] = __builtin_amdgcn_mfma_f32_16x16x32_bf16(fal[mt], fbh[nt], acc[mt][nt], 0, 0, 0);
                acc[mt][nt] = __builtin_amdgcn_mfma_f32_16x16x32_bf16(fah[mt], fbl[nt], acc[mt][nt], 0, 0, 0);
                acc[mt][nt] = __builtin_amdgcn_mfma_f32_16x16x32_bf16(fah[mt], fbh[nt], acc[mt][nt], 0, 0, 0);
            }
        __syncthreads();
    }

#pragma unroll
    for (int mt = 0; mt < 4; ++mt)
#pragma unroll
        for (int nt = 0; nt < 2; ++nt) {
            const int rowb = row0 + wm * 64 + mt * 16 + kg * 4;
            const int col  = col0 + wn * 32 + nt * 16 + m16;
#pragma unroll
            for (int rg = 0; rg < 4; ++rg) {
                float v = acc[mt][nt][rg];
                if (ACT == 1) v = v / (1.f + expf(-v));
                C[(size_t)(rowb + rg) * N + col] = v;
            }
        }
}

template <int ACT>
__global__ __launch_bounds__(256) void gemm_bf16s(const unsigned short* __restrict__ Ah,
                                                  const unsigned short* __restrict__ Al,
                                                  const unsigned short* __restrict__ Bh,
                                                  const unsigned short* __restrict__ Bl,
                                                  float* __restrict__ C,
                                                  int M, int N, int K) {
    __shared__ unsigned short LA[2][8 * 512];
    __shared__ unsigned short LB[2][4 * 512];
    gemm_core<ACT>(Ah, Al, Bh, Bl, C, M, N, K, LA[0], LA[1], LB[0], LB[1]);
}

// fused QKV GEMM: blockIdx.z selects weight/output; 768 blocks = 3/CU
__global__ __launch_bounds__(256) void gemm_qkv(const unsigned short* __restrict__ Ah,
                                                const unsigned short* __restrict__ Al,
                                                const unsigned short* __restrict__ Bqh,
                                                const unsigned short* __restrict__ Bql,
                                                const unsigned short* __restrict__ Bkh,
                                                const unsigned short* __restrict__ Bkl,
                                                const unsigned short* __restrict__ Bvh,
                                                const unsigned short* __restrict__ Bvl,
                                                float* __restrict__ Cq,
                                                float* __restrict__ Ck,
                                                float* __restrict__ Cv) {
    __shared__ unsigned short LA[2][8 * 512];
    __shared__ unsigned short LB[2][4 * 512];
    const int z = blockIdx.z;
    const unsigned short* Bh = (z == 0) ? Bqh : (z == 1) ? Bkh : Bvh;
    const unsigned short* Bl = (z == 0) ? Bql : (z == 1) ? Bkl : Bvl;
    float* C = (z == 0) ? Cq : (z == 1) ? Ck : Cv;
    gemm_core<1>(Ah, Al, Bh, Bl, C, ROWS, D_MODEL, D_MODEL, LA[0], LA[1], LB[0], LB[1]);
}

// ---------------------------------------------------------------------------
// Fallback GEMM (inline split) — only if ws_size too small.
// ---------------------------------------------------------------------------
#define LDST 40
template <int ACT>
__global__ __launch_bounds__(256) void gemm_mfma(const float* __restrict__ A,
                                                 const float* __restrict__ B,
                                                 float* __restrict__ C,
                                                 int M, int N, int K) {
    __shared__ unsigned short Ahi[128 * LDST], Alo[128 * LDST];
    __shared__ unsigned short Bhi[128 * LDST], Blo[128 * LDST];

    const int t = threadIdx.x;
    const int wave = t >> 6, lane = t & 63;
    const int wm = wave >> 1, wn = wave & 1;
    const int row0 = blockIdx.y * 128, col0 = blockIdx.x * 128;
    const int sr = t >> 1;
    const int sh = t & 1;
    const int m16 = lane & 15, kg = lane >> 4;

    f32x4 acc[4][4];
#pragma unroll
    for (int i = 0; i < 4; ++i)
#pragma unroll
        for (int j = 0; j < 4; ++j) acc[i][j] = (f32x4){0.f, 0.f, 0.f, 0.f};

    const float* ga = A + (size_t)(row0 + sr) * K + sh * 16;
    const float* gb = B + (size_t)(col0 + sr) * K + sh * 16;
    const int sbase = sr * LDST + sh * 16;

    for (int k0 = 0; k0 < K; k0 += 32) {
        float af[16], bf[16];
#pragma unroll
        for (int i = 0; i < 4; ++i) {
            float4 a4 = *(const float4*)(ga + k0 + i * 4);
            float4 b4 = *(const float4*)(gb + k0 + i * 4);
            af[i * 4 + 0] = a4.x; af[i * 4 + 1] = a4.y; af[i * 4 + 2] = a4.z; af[i * 4 + 3] = a4.w;
            bf[i * 4 + 0] = b4.x; bf[i * 4 + 1] = b4.y; bf[i * 4 + 2] = b4.z; bf[i * 4 + 3] = b4.w;
        }
        ushort8 ah0, ah1, al0, al1, bh0, bh1, bl0, bl1;
#pragma unroll
        for (int j = 0; j < 8; ++j) {
            unsigned short h = f2bf(af[j]);       ah0[j] = h; al0[j] = f2bf(af[j] - bf2f(h));
            h = f2bf(af[j + 8]);                  ah1[j] = h; al1[j] = f2bf(af[j + 8] - bf2f(h));
            h = f2bf(bf[j]);                      bh0[j] = h; bl0[j] = f2bf(bf[j] - bf2f(h));
            h = f2bf(bf[j + 8]);                  bh1[j] = h; bl1[j] = f2bf(bf[j + 8] - bf2f(h));
        }
        *(ushort8*)&Ahi[sbase] = ah0;  *(ushort8*)&Ahi[sbase + 8] = ah1;
        *(ushort8*)&Alo[sbase] = al0;  *(ushort8*)&Alo[sbase + 8] = al1;
        *(ushort8*)&Bhi[sbase] = bh0;  *(ushort8*)&Bhi[sbase + 8] = bh1;
        *(ushort8*)&Blo[sbase] = bl0;  *(ushort8*)&Blo[sbase + 8] = bl1;
        __syncthreads();

        bf16x8 fah[4], fal[4], fbh[4], fbl[4];
#pragma unroll
        for (int i = 0; i < 4; ++i) {
            const int ar = (wm * 64 + i * 16 + m16) * LDST + kg * 8;
            const int br = (wn * 64 + i * 16 + m16) * LDST + kg * 8;
            fah[i] = *(const bf16x8*)&Ahi[ar];
            fal[i] = *(const bf16x8*)&Alo[ar];
            fbh[i] = *(const bf16x8*)&Bhi[br];
            fbl[i] = *(const bf16x8*)&Blo[br];
        }
#pragma unroll
        for (int i = 0; i < 4; ++i)
#pragma unroll
            for (int j = 0; j < 4; ++j) {
                acc[i][j] = __builtin_amdgcn_mfma_f32_16x16x32_bf16(fal[i], fbh[j], acc[i][j], 0, 0, 0);
                acc[i][j] = __builtin_amdgcn_mfma_f32_16x16x32_bf16(fah[i], fbl[j], acc[i][j], 0, 0, 0);
                acc[i][j] = __builtin_amdgcn_mfma_f32_16x16x32_bf16(fah[i], fbh[j], acc[i][j], 0, 0, 0);
            }
        __syncthreads();
    }

#pragma unroll
    for (int i = 0; i < 4; ++i)
#pragma unroll
        for (int j = 0; j < 4; ++j) {
            const int col = col0 + wn * 64 + j * 16 + m16;
            const int rowb = row0 + wm * 64 + i * 16 + kg * 4;
#pragma unroll
            for (int rg = 0; rg < 4; ++rg) {
                float v = acc[i][j][rg];
                if (ACT == 1) v = v / (1.f + expf(-v));
                C[(size_t)(rowb + rg) * N + col] = v;
            }
        }
}

// ---------------------------------------------------------------------------
// beta = 2*sigmoid(x @ Wb^T)  : (ROWS, NHEAD). One wave per row.
// ---------------------------------------------------------------------------
__global__ __launch_bounds__(256) void beta_kernel(const float* __restrict__ x,
                                                   const float* __restrict__ Wb,
                                                   float* __restrict__ beta) {
    const int wave = blockIdx.x * 4 + (threadIdx.x >> 6);
    const int lane = threadIdx.x & 63;
    const float* xr = x + (size_t)wave * D_MODEL;
    float xv[16];
#pragma unroll
    for (int j = 0; j < 16; ++j) xv[j] = xr[lane + 64 * j];
    for (int n = 0; n < NHEAD; ++n) {
        const float* wr = Wb + (size_t)n * D_MODEL;
        float s = 0.f;
#pragma unroll
        for (int j = 0; j < 16; ++j) s += xv[j] * wr[lane + 64 * j];
#pragma unroll
        for (int off = 32; off; off >>= 1) s += __shfl_xor(s, off);
        if (lane == 0) beta[(size_t)wave * NHEAD + n] = 2.f / (1.f + expf(-s));
    }
}

// ---------------------------------------------------------------------------
// L2-normalize q and k per (row, head) over HEAD_DIM=64.
// ---------------------------------------------------------------------------
__global__ __launch_bounds__(256) void norm_qk(float* __restrict__ Q,
                                               float* __restrict__ Kp) {
    const int TOT = ROWS * NHEAD;
    int wave = blockIdx.x * 4 + (threadIdx.x >> 6);
    const int lane = threadIdx.x & 63;
    float* T = (wave < TOT) ? Q : Kp;
    int w = (wave < TOT) ? wave : wave - TOT;
    float* p = T + (size_t)(w >> 4) * D_MODEL + (size_t)(w & 15) * HEAD_DIM;
    float v = p[lane];
    float ss = v * v;
#pragma unroll
    for (int off = 32; off; off >>= 1) ss += __shfl_xor(ss, off);
    p[lane] = v / (sqrtf(ss) + 1e-6f);
}

// ---------------------------------------------------------------------------
// Chunked delta-rule scan v5: 512 threads, wave-0-exclusive solve with ZERO
// internal barriers (wave-local LDS RAW needs only lgkmcnt, auto-inserted).
// Barriers: 6/chunk (was 12). C032 stride 65 (conflict-free solve reads;
// V32 staging keeps 68 for float4 alignment — time-disjoint union).
// ---------------------------------------------------------------------------
#define SMEM_SCAN 153088

__global__ __launch_bounds__(512, 1) void scan_chunked(const float* __restrict__ Qg,
                                                       const float* __restrict__ Kg,
                                                       const float* __restrict__ Vg,
                                                       const float* __restrict__ Btg,
                                                       float* __restrict__ Yg) {
    extern __shared__ char smem[];
    ushort* Mh_  = (ushort*)(smem + 0 * FBUF);
    ushort* Ml_  = (ushort*)(smem + 1 * FBUF);
    ushort* MTh_ = (ushort*)(smem + 2 * FBUF);
    ushort* MTl_ = (ushort*)(smem + 3 * FBUF);
    ushort* KTh_ = (ushort*)(smem + 4 * FBUF);
    ushort* KTl_ = (ushort*)(smem + 5 * FBUF);
    ushort* V0h_ = (ushort*)(smem + 6 * FBUF);
    ushort* V0l_ = (ushort*)(smem + 7 * FBUF);
    ushort* Gh_  = (ushort*)(smem + 8 * FBUF);
    ushort* Gl_  = (ushort*)(smem + 9 * FBUF);
    ushort* Kh_  = (ushort*)(smem + 10 * FBUF);  // union1: K / DT
    ushort* Kl_  = (ushort*)(smem + 11 * FBUF);
    ushort* DTh_ = Kh_;
    ushort* DTl_ = Kl_;
    ushort* Qh_  = (ushort*)(smem + 12 * FBUF);  // union2: Q / W (adjacent hi,lo)
    ushort* Ql_  = (ushort*)(smem + 13 * FBUF);
    ushort* Wh_  = Qh_;
    ushort* Wl_  = Ql_;
    float*  V32  = (float*)(smem + 14 * FBUF);             // 64x68 fp32 staging
    float*  C032 = V32;                                    // reused at stride 65
    ushort* Ah_  = (ushort*)(smem + 14 * FBUF + 17408);
    ushort* Al_  = (ushort*)(smem + 15 * FBUF + 17408);
    float*  N32  = (float*)(smem + 16 * FBUF + 17408);     // 64x17 fp32
    float*  bv   = (float*)(smem + 16 * FBUF + 17408 + 4352);

    const int b = blockIdx.x >> 4;
    const int n = blockIdx.x & 15;
    const int t = threadIdx.x;
    const int wave = t >> 6, lane = t & 63;
    const int wm = wave >> 1, wn = wave & 1;      // 4x2 wave grid
    const int m16 = lane & 15, kg = lane >> 4;
    const int bS = b * SEQ;
    const int nOff = n * HEAD_DIM;
    const int r = t >> 3, g = t & 7;   // staging: row r (0..63), col-octet g (0..7)

    // fp32 register state: row = wm*16 + kg*4 + rg, col = wn*32 + j*16 + m16
    f32x4 Macc[2], MTacc[2];
#pragma unroll
    for (int j = 0; j < 2; ++j) {
        Macc[j] = (f32x4){0.f, 0.f, 0.f, 0.f};
        MTacc[j] = (f32x4){0.f, 0.f, 0.f, 0.f};
    }

    // product: wave's 16-row band x 32-col half, K=64, split operands, D = X*Y^T
    auto prod_band = [&](const ushort* Ah, const ushort* Al,
                         const ushort* Bh, const ushort* Bl, f32x4 acc[2]) {
        const int lo8 = lane * 8;
#pragma unroll
        for (int half = 0; half < 2; ++half) {
            bf16x8 ah = *(const bf16x8*)&Ah[(wm * 2 + half) * SUBST + lo8];
            bf16x8 al = *(const bf16x8*)&Al[(wm * 2 + half) * SUBST + lo8];
#pragma unroll
            for (int j = 0; j < 2; ++j) {
                const int jg = wn * 2 + j;
                bf16x8 bh = *(const bf16x8*)&Bh[(jg * 2 + half) * SUBST + lo8];
                bf16x8 bl = *(const bf16x8*)&Bl[(jg * 2 + half) * SUBST + lo8];
                acc[j] = __builtin_amdgcn_mfma_f32_16x16x32_bf16(al, bh, acc[j], 0, 0, 0);
                acc[j] = __builtin_amdgcn_mfma_f32_16x16x32_bf16(ah, bl, acc[j], 0, 0, 0);
                acc[j] = __builtin_amdgcn_mfma_f32_16x16x32_bf16(ah, bh, acc[j], 0, 0, 0);
            }
        }
    };

    for (int c = 0; c < NCHUNK; ++c) {
        const int s0 = c * CHUNK;

        // ---- stage K (+transpose), Q, V, beta; 8 elems/thread ----
        {
            const float* gK = Kg + (size_t)(bS + s0 + r) * D_MODEL + nOff + g * 8;
            const float* gQ = Qg + (size_t)(bS + s0 + r) * D_MODEL + nOff + g * 8;
            const float* gV = Vg + (size_t)(bS + s0 + r) * D_MODEL + nOff + g * 8;
            float kf[8], qf[8];
            ushort khv[8], klv[8];
            float4 kv0 = ((const float4*)gK)[0], kv1 = ((const float4*)gK)[1];
            float4 qv0 = ((const float4*)gQ)[0], qv1 = ((const float4*)gQ)[1];
            float4 vv0 = ((const float4*)gV)[0], vv1 = ((const float4*)gV)[1];
            kf[0] = kv0.x; kf[1] = kv0.y; kf[2] = kv0.z; kf[3] = kv0.w;
            kf[4] = kv1.x; kf[5] = kv1.y; kf[6] = kv1.z; kf[7] = kv1.w;
            qf[0] = qv0.x; qf[1] = qv0.y; qf[2] = qv0.z; qf[3] = qv0.w;
            qf[4] = qv1.x; qf[5] = qv1.y; qf[6] = qv1.z; qf[7] = qv1.w;
            *(float4*)&V32[r * 68 + g * 8] = vv0;
            *(float4*)&V32[r * 68 + g * 8 + 4] = vv1;
            ushort8 kh8, kl8, qh8, ql8;
#pragma unroll
            for (int e = 0; e < 8; ++e) {
                ushort h = f2bf(kf[e]);
                ushort l = f2bf(kf[e] - bf2f(h));
                khv[e] = h; klv[e] = l;
                kh8[e] = h; kl8[e] = l;
                h = f2bf(qf[e]); l = f2bf(qf[e] - bf2f(h));
                qh8[e] = h; ql8[e] = l;
            }
            const int o0 = fidx(r, g * 8);
            *(ushort8*)&Kh_[o0] = kh8;
            *(ushort8*)&Kl_[o0] = kl8;
            *(ushort8*)&Qh_[o0] = qh8;
            *(ushort8*)&Ql_[o0] = ql8;
#pragma unroll
            for (int e = 0; e < 8; ++e) {
                const int ib = fidx(g * 8 + e, r);
                KTh_[ib] = khv[e]; KTl_[ib] = klv[e];
            }
            if (t < 64) bv[t] = Btg[(size_t)(bS + s0 + t) * NHEAD + n];
        }
        __syncthreads();   // B1

        f32x4 yacc[2], V0acc[2];
        {
            // ---- P_R: V0 = V - K*M0^T (register result + split-bf16 operand copy) ----
            if (c > 0) {
#pragma unroll
                for (int j = 0; j < 2; ++j) V0acc[j] = (f32x4){0.f, 0.f, 0.f, 0.f};
                prod_band(Kh_, Kl_, Mh_, Ml_, V0acc);
#pragma unroll
                for (int j = 0; j < 2; ++j)
#pragma unroll
                    for (int rg = 0; rg < 4; ++rg) {
                        const int row = wm * 16 + kg * 4 + rg, col = wn * 32 + j * 16 + m16;
                        V0acc[j][rg] = V32[row * 68 + col] - V0acc[j][rg];
                    }
            } else {
#pragma unroll
                for (int j = 0; j < 2; ++j)
#pragma unroll
                    for (int rg = 0; rg < 4; ++rg) {
                        const int row = wm * 16 + kg * 4 + rg, col = wn * 32 + j * 16 + m16;
                        V0acc[j][rg] = V32[row * 68 + col];
                    }
            }
#pragma unroll
            for (int j = 0; j < 2; ++j)
#pragma unroll
                for (int rg = 0; rg < 4; ++rg) {
                    const int row = wm * 16 + kg * 4 + rg, col = wn * 32 + j * 16 + m16;
                    float v0 = V0acc[j][rg];
                    ushort h = f2bf(v0);
                    const int ii = fidx(row, col);
                    V0h_[ii] = h; V0l_[ii] = f2bf(v0 - bf2f(h));
                }
            // ---- P_YM: yacc = Q*M0 (via MT) ----
#pragma unroll
            for (int j = 0; j < 2; ++j) yacc[j] = (f32x4){0.f, 0.f, 0.f, 0.f};
            if (c > 0) prod_band(Qh_, Ql_, MTh_, MTl_, yacc);
            // ---- P_A: A = K K^T -> Asp ----
            f32x4 acc[2];
#pragma unroll
            for (int j = 0; j < 2; ++j) acc[j] = (f32x4){0.f, 0.f, 0.f, 0.f};
            prod_band(Kh_, Kl_, Kh_, Kl_, acc);
#pragma unroll
            for (int j = 0; j < 2; ++j)
#pragma unroll
                for (int rg = 0; rg < 4; ++rg) {
                    const int row = wm * 16 + kg * 4 + rg, col = wn * 32 + j * 16 + m16;
                    float av = acc[j][rg];
                    ushort h = f2bf(av);
                    const int ii = fidx(row, col);
                    Ah_[ii] = h; Al_[ii] = f2bf(av - bf2f(h));
                }
            // ---- P_QK: G = tril_(Q K^T) -> Gsp ----
#pragma unroll
            for (int j = 0; j < 2; ++j) acc[j] = (f32x4){0.f, 0.f, 0.f, 0.f};
            prod_band(Qh_, Ql_, Kh_, Kl_, acc);
#pragma unroll
            for (int j = 0; j < 2; ++j)
#pragma unroll
                for (int rg = 0; rg < 4; ++rg) {
                    const int row = wm * 16 + kg * 4 + rg, col = wn * 32 + j * 16 + m16;
                    float gv = (row > col) ? acc[j][rg] : 0.f;
                    ushort h = f2bf(gv);
                    const int ii = fidx(row, col);
                    Gh_[ii] = h; Gl_[ii] = f2bf(gv - bf2f(h));
                }
        }
        __syncthreads();   // B2 (V32 dead -> C032 writable; Q dead -> W writable)

        {
            // ---- P_C0: C0 = K * V0^T -> fp32 (stride 65: conflict-free solve reads) ----
            f32x4 acc[2];
#pragma unroll
            for (int j = 0; j < 2; ++j) acc[j] = (f32x4){0.f, 0.f, 0.f, 0.f};
            prod_band(Kh_, Kl_, V0h_, V0l_, acc);
#pragma unroll
            for (int j = 0; j < 2; ++j)
#pragma unroll
                for (int rg = 0; rg < 4; ++rg) {
                    const int row = wm * 16 + kg * 4 + rg, col = wn * 32 + j * 16 + m16;
                    C032[row * 65 + col] = acc[j][rg];
                }
            // zero W region (Wh_,Wl_ adjacent): must be 0, not stale, every chunk
            for (int i = t; i < 2 * FBUF / 16; i += 512)
                ((uint4v*)Wh_)[i] = (uint4v){0u, 0u, 0u, 0u};
        }
        __syncthreads();   // B3 (C032 + zeroed W visible)

        // ---- blocked solve: WAVE 0 ONLY, zero internal barriers ----
        // Wave-local LDS RAW (W publish -> N-product read) needs only lgkmcnt,
        // which the compiler inserts. Waves 1-7 wait at B4.
        if (wave == 0) {
#pragma unroll
            for (int J = 0; J < 4; ++J) {
                float Nreg[16];
                if (J > 0) {
                    // N[t, s in J] = A * W_J^T for all 4 row-bands (wave-local)
#pragma unroll
                    for (int band = 0; band < 4; ++band) {
                        f32x4 acc1 = (f32x4){0.f, 0.f, 0.f, 0.f};
                        const int lo8 = lane * 8;
#pragma unroll
                        for (int half = 0; half < 2; ++half) {
                            bf16x8 ah = *(const bf16x8*)&Ah_[(band * 2 + half) * SUBST + lo8];
                            bf16x8 al = *(const bf16x8*)&Al_[(band * 2 + half) * SUBST + lo8];
                            bf16x8 bh = *(const bf16x8*)&Wh_[(J * 2 + half) * SUBST + lo8];
                            bf16x8 bl = *(const bf16x8*)&Wl_[(J * 2 + half) * SUBST + lo8];
                            acc1 = __builtin_amdgcn_mfma_f32_16x16x32_bf16(al, bh, acc1, 0, 0, 0);
                            acc1 = __builtin_amdgcn_mfma_f32_16x16x32_bf16(ah, bl, acc1, 0, 0, 0);
                            acc1 = __builtin_amdgcn_mfma_f32_16x16x32_bf16(ah, bh, acc1, 0, 0, 0);
                        }
#pragma unroll
                        for (int rg = 0; rg < 4; ++rg)
                            N32[(band * 16 + kg * 4 + rg) * 17 + m16] = acc1[rg];
                    }
#pragma unroll
                    for (int j = 0; j < 16; ++j) Nreg[j] = N32[lane * 17 + j];
                }

                float Areg[16], CNreg[16];
                {
                    bf16x8 a0 = *(const bf16x8*)&Ah_[fidx(lane, 16 * J)];
                    bf16x8 a1 = *(const bf16x8*)&Ah_[fidx(lane, 16 * J + 8)];
                    bf16x8 b0 = *(const bf16x8*)&Al_[fidx(lane, 16 * J)];
                    bf16x8 b1 = *(const bf16x8*)&Al_[fidx(lane, 16 * J + 8)];
#pragma unroll
                    for (int e = 0; e < 8; ++e) {
                        Areg[e]     = bf2f((ushort)a0[e]) + bf2f((ushort)b0[e]);
                        Areg[e + 8] = bf2f((ushort)a1[e]) + bf2f((ushort)b1[e]);
                    }
#pragma unroll
                    for (int j = 0; j < 16; ++j) CNreg[j] = C032[lane * 65 + 16 * J + j];
                    if (J > 0) {
#pragma unroll
                        for (int j = 0; j < 16; ++j) CNreg[j] += Nreg[j];
                    }
                }
                float bvreg = bv[16 * J + m16];

                // 16 serial steps; even/odd partial sums halve the FMA chain depth
                float wreg[16];
#pragma unroll
                for (int j = 0; j < 16; ++j) {
                    float sA = CNreg[j], sB = 0.f;
#pragma unroll
                    for (int jj = 0; jj < 16; ++jj) {
                        if (jj < j) {
                            float pr = Areg[jj] * lane_bcast(wreg[jj], 16 * J + j);
                            if (jj & 1) sB += pr; else sA += pr;
                        }
                    }
                    float sum = sA + sB;
                    float beta_s = lane_bcast(bvreg, j);
                    wreg[j] = (lane > 16 * J + j) ? (-beta_s * sum) : 0.f;
                }

                // publish W columns J (octet stores)
                {
                    ushort8 h8[2], l8[2];
#pragma unroll
                    for (int e = 0; e < 16; ++e) {
                        ushort h = f2bf(wreg[e]);
                        h8[e >> 3][e & 7] = h;
                        l8[e >> 3][e & 7] = f2bf(wreg[e] - bf2f(h));
                    }
                    const int o0 = fidx(lane, 16 * J), o1 = fidx(lane, 16 * J + 8);
                    *(ushort8*)&Wh_[o0] = h8[0]; *(ushort8*)&Wh_[o1] = h8[1];
                    *(ushort8*)&Wl_[o0] = l8[0]; *(ushort8*)&Wl_[o1] = l8[1];
                }
            }
        }
        __syncthreads();   // B4 (full W visible to all waves)

        {
            // ---- P_Delta: Delta = V0(reg) + W * K ; write DT = (beta Delta)^T ----
            f32x4 acc[2];
#pragma unroll
            for (int j = 0; j < 2; ++j) acc[j] = V0acc[j];
            prod_band(Wh_, Wl_, KTh_, KTl_, acc);
#pragma unroll
            for (int j = 0; j < 2; ++j)
#pragma unroll
                for (int rg = 0; rg < 4; ++rg) {
                    const int row = wm * 16 + kg * 4 + rg, col = wn * 32 + j * 16 + m16;
                    float dv = acc[j][rg] * bv[row];     // beta_s * delta_s[d]
                    ushort h = f2bf(dv);
                    const int ii = fidx(col, row);       // DT[d][s]
                    DTh_[ii] = h; DTl_[ii] = f2bf(dv - bf2f(h));
                }
        }
        __syncthreads();   // B5 (DT ready)

        {
            // ---- P_Y2: Y = yacc + G * DT^T -> global ----
            prod_band(Gh_, Gl_, DTh_, DTl_, yacc);
#pragma unroll
            for (int j = 0; j < 2; ++j)
#pragma unroll
                for (int rg = 0; rg < 4; ++rg) {
                    const int row = wm * 16 + kg * 4 + rg, col = wn * 32 + j * 16 + m16;
                    Yg[(size_t)(bS + s0 + row) * D_MODEL + nOff + col] = yacc[j][rg];
                }
            // ---- P_M / P_MT into fp32 registers ----
            prod_band(KTh_, KTl_, DTh_, DTl_, Macc);
            prod_band(DTh_, DTl_, KTh_, KTl_, MTacc);
            // state operand copies: M/MT buffers last read before B2 — safe to
            // write here without an extra barrier (B6 orders vs next chunk)
            if (c < NCHUNK - 1) {
#pragma unroll
                for (int j = 0; j < 2; ++j)
#pragma unroll
                    for (int rg = 0; rg < 4; ++rg) {
                        const int row = wm * 16 + kg * 4 + rg, col = wn * 32 + j * 16 + m16;
                        const int ii = fidx(row, col);
                        float mv = Macc[j][rg];
                        ushort h = f2bf(mv);
                        Mh_[ii] = h; Ml_[ii] = f2bf(mv - bf2f(h));
                        mv = MTacc[j][rg];
                        h = f2bf(mv);
                        MTh_[ii] = h; MTl_[ii] = f2bf(mv - bf2f(h));
                    }
            }
        }
        __syncthreads();   // B6 (state + unions settled for next chunk)
    }
}

// ---------------------------------------------------------------------------
// RMSNorm. SPLIT=1: write (hi,lo) bf16 for final GEMM. SPLIT=0: fp32 in place.
// ---------------------------------------------------------------------------
template <int SPLIT>
__global__ __launch_bounds__(256) void rmsnorm_kernel(float* __restrict__ Y,
                                                      const float* __restrict__ w,
                                                      unsigned short* __restrict__ H,
                                                      unsigned short* __restrict__ L) {
    __shared__ float red[4];
    float* y = Y + (size_t)blockIdx.x * D_MODEL;
    const int t = threadIdx.x;
    const int wv = t >> 6, ln = t & 63;
    float4 v = ((float4*)y)[t];
    float ss = v.x * v.x + v.y * v.y + v.z * v.z + v.w * v.w;
#pragma unroll
    for (int off = 32; off; off >>= 1) ss += __shfl_xor(ss, off);
    if (ln == 0) red[wv] = ss;
    __syncthreads();
    float tot = red[0] + red[1] + red[2] + red[3];
    float inv = 1.f / sqrtf(tot * (1.f / D_MODEL) + 1e-6f);
    const float4 wv4 = ((const float4*)w)[t];
    v.x *= inv * wv4.x; v.y *= inv * wv4.y;
    v.z *= inv * wv4.z; v.w *= inv * wv4.w;
    if (SPLIT) {
        us4 h, l;
        h.x = f2bf(v.x); l.x = f2bf(v.x - bf2f(h.x));
        h.y = f2bf(v.y); l.y = f2bf(v.y - bf2f(h.y));
        h.z = f2bf(v.z); l.z = f2bf(v.z - bf2f(h.z));
        h.w = f2bf(v.w); l.w = f2bf(v.w - bf2f(h.w));
        size_t i = (size_t)blockIdx.x * 256 + t;
        ((us4*)H)[i] = h;
        ((us4*)L)[i] = l;
    } else {
        ((float4*)y)[t] = v;
    }
}

// ---------------------------------------------------------------------------
extern "C" void kernel_launch(void* const* d_in, const int* in_sizes, int n_in,
                              void* d_out, int out_size, void* d_ws, size_t ws_size,
                              hipStream_t stream) {
    const float* x     = (const float*)d_in[0];
    const float* Wq    = (const float*)d_in[1];
    const float* Wk    = (const float*)d_in[2];
    const float* Wv    = (const float*)d_in[3];
    const float* Wb    = (const float*)d_in[4];
    const float* Wo    = (const float*)d_in[5];
    const float* rms_w = (const float*)d_in[6];
    float* out = (float*)d_out;

    char* p = (char*)d_ws;
    float* Q  = (float*)p;  p += (size_t)RD * 4;
    float* Kp = (float*)p;  p += (size_t)RD * 4;
    float* Vp = (float*)p;  p += (size_t)RD * 4;
    float* Y  = (float*)p;  p += (size_t)RD * 4;
    float* Bt = (float*)p;  p += (size_t)32768 * 4;
    unsigned short* xh  = (unsigned short*)p;  p += (size_t)RD * 2;   // reused as Yh
    unsigned short* xl  = (unsigned short*)p;  p += (size_t)RD * 2;   // reused as Yl
    unsigned short* Wsh = (unsigned short*)p;  p += (size_t)WSZ * 2;
    unsigned short* Wsl = (unsigned short*)p;  p += (size_t)WSZ * 2;
    const size_t need_fast = (size_t)RD * 16 + 131072 + (size_t)RD * 4 + (size_t)WSZ * 4;
    const bool fast = ws_size >= need_fast;

    // Wk/Wv splits parked in Y (dead until scan writes it)
    unsigned short* Wkh = (unsigned short*)Y;
    unsigned short* Wkl = Wkh + WSZ;
    unsigned short* Wvh = Wkl + WSZ;
    unsigned short* Wvl = Wvh + WSZ;

    (void)hipFuncSetAttribute(reinterpret_cast<const void*>(scan_chunked),
                              hipFuncAttributeMaxDynamicSharedMemorySize, SMEM_SCAN);

    if (fast) {
        dim3 ggrid(D_MODEL / 64, ROWS / 128);       // (16,16) = 256 blocks
        dim3 qgrid(D_MODEL / 64, ROWS / 128, 3);    // 768 blocks = 3/CU
        split_kernel<<<RD / 4 / 256, 256, 0, stream>>>(x, xh, xl, RD / 4);
        split3_kernel<<<3 * WSZ / 4 / 256, 256, 0, stream>>>(Wq, Wk, Wv,
                                                             Wsh, Wsl, Wkh, Wkl, Wvh, Wvl);
        gemm_qkv<<<qgrid, 256, 0, stream>>>(xh, xl, Wsh, Wsl, Wkh, Wkl, Wvh, Wvl,
                                            Q, Kp, Vp);
        beta_kernel<<<ROWS / 4, 256, 0, stream>>>(x, Wb, Bt);
        norm_qk<<<2 * ROWS * NHEAD / 4, 256, 0, stream>>>(Q, Kp);
        scan_chunked<<<BATCH * NHEAD, 512, SMEM_SCAN, stream>>>(Q, Kp, Vp, Bt, Y);
        rmsnorm_kernel<1><<<ROWS, 256, 0, stream>>>(Y, rms_w, xh, xl);
        split_kernel<<<WSZ / 4 / 256, 256, 0, stream>>>(Wo, Wsh, Wsl, WSZ / 4);
        gemm_bf16s<0><<<ggrid, 256, 0, stream>>>(xh, xl, Wsh, Wsl, out, ROWS, D_MODEL, D_MODEL);
    } else {
        dim3 ggrid(D_MODEL / 128, ROWS / 128);  // (8,16)
        gemm_mfma<1><<<ggrid, 256, 0, stream>>>(x, Wq, Q, ROWS, D_MODEL, D_MODEL);
        gemm_mfma<1><<<ggrid, 256, 0, stream>>>(x, Wk, Kp, ROWS, D_MODEL, D_MODEL);
        gemm_mfma<1><<<ggrid, 256, 0, stream>>>(x, Wv, Vp, ROWS, D_MODEL, D_MODEL);
        beta_kernel<<<ROWS / 4, 256, 0, stream>>>(x, Wb, Bt);
        norm_qk<<<2 * ROWS * NHEAD / 4, 256, 0, stream>>>(Q, Kp);
        scan_chunked<<<BATCH * NHEAD, 512, SMEM_SCAN, stream>>>(Q, Kp, Vp, Bt, Y);
        rmsnorm_kernel<0><<<ROWS, 256, 0, stream>>>(Y, rms_w, nullptr, nullptr);
        gemm_mfma<0><<<ggrid, 256, 0, stream>>>(Y, Wo, out, ROWS, D_MODEL, D_MODEL);
    }
}